// Round 16
// baseline (903.504 us; speedup 1.0000x reference)
//
#include <hip/hip_runtime.h>
#include <math.h>

typedef __attribute__((ext_vector_type(8))) short s8;
typedef __attribute__((ext_vector_type(8))) unsigned short us8;
typedef __attribute__((ext_vector_type(4))) float f4;
typedef __attribute__((ext_vector_type(4))) unsigned short us4;
typedef __attribute__((ext_vector_type(4))) unsigned int u32x4;

#define DEVI __device__ __forceinline__

static const int NPIX = 65536;   // 256*256

DEVI float b2f(unsigned short u) {
    unsigned int v = ((unsigned int)u) << 16;
    float f; __builtin_memcpy(&f, &v, 4); return f;
}
DEVI unsigned short f2b(float f) {
    unsigned int u; __builtin_memcpy(&u, &f, 4);
    unsigned int r = (u + 0x7FFFu + ((u >> 16) & 1u)) >> 16;
    return (unsigned short)r;
}
DEVI float geluf(float x) { return 0.5f * x * (1.0f + erff(x * 0.70710678118f)); }
DEVI float gelu_t(float x) {
    float z = 1.595769122f * (x + 0.044715f * x * x * x);
    return x * __builtin_amdgcn_rcpf(1.0f + __expf(-z));
}
DEVI float rfl(float v) {
    int i; __builtin_memcpy(&i, &v, 4);
    i = __builtin_amdgcn_readfirstlane(i);
    float o; __builtin_memcpy(&o, &i, 4); return o;
}

DEVI void gload_lds16(const unsigned short* g, unsigned short* l) {
    __builtin_amdgcn_global_load_lds(
        (const __attribute__((address_space(1))) unsigned int*)g,
        (__attribute__((address_space(3))) unsigned int*)l,
        16, 0, 0);
}

// wave-local sync: wait own memory ops, block compiler reordering (no s_barrier)
DEVI void wave_sync() {
    asm volatile("s_waitcnt vmcnt(0) lgkmcnt(0)" ::: "memory");
    __builtin_amdgcn_wave_barrier();
}

// ---------------------------------------------------------------------------
// LayerNorm + transpose: x f32 [b][192][px] -> xnt bf16 [b*px][192]
// ---------------------------------------------------------------------------
__global__ __launch_bounds__(256) void lnt_k(const float* __restrict__ X,
                                             const float* __restrict__ gw,
                                             const float* __restrict__ gb,
                                             unsigned short* __restrict__ Out)
{
    const int i = blockIdx.x * 256 + threadIdx.x;
    const int b = i >> 16, px = i & 65535;
    const float* xp = X + (size_t)b * 192 * NPIX + px;

    unsigned int pk[96];
    float sum = 0.f, ssq = 0.f;
    #pragma unroll
    for (int c = 0; c < 192; c++) {
        float v = xp[(size_t)c * NPIX];
        sum += v; ssq += v * v;
        unsigned int h = f2b(v);
        if (c & 1) pk[c >> 1] |= h << 16;
        else       pk[c >> 1] = h;
    }
    float mu = sum * (1.0f / 192.0f);
    float var = ssq * (1.0f / 192.0f) - mu * mu;
    float rs = rsqrtf(var + 1e-5f);

    #pragma unroll
    for (int c2 = 0; c2 < 96; c2++) {
        int c = c2 * 2;
        float lo = b2f((unsigned short)(pk[c2] & 0xFFFF));
        float hi = b2f((unsigned short)(pk[c2] >> 16));
        lo = (lo - mu) * rs * gw[c] + gb[c];
        hi = (hi - mu) * rs * gw[c + 1] + gb[c + 1];
        pk[c2] = (unsigned int)f2b(lo) | ((unsigned int)f2b(hi) << 16);
    }
    u32x4* dst = (u32x4*)(Out + (size_t)i * 192);
    #pragma unroll
    for (int j = 0; j < 6; j++) {
        u32x4 v = { pk[4 * j], pk[4 * j + 1], pk[4 * j + 2], pk[4 * j + 3] };
        dst[j] = v;
    }
}

// ---------------------------------------------------------------------------
// Pipelined staged GEMM.
// MODE 2: out f32  [b][192][px], bias + f32 resid    (w2, small-ws)
// MODE 3: qkv: cn==0 -> exp(q) -> qT[gp][192]; cn==1 -> exp(k); cn==2 -> v
// MODE 4: out f32  [b][192][px], bias + bf16 resid   (w2, big-ws)
// ---------------------------------------------------------------------------
template<int MODE, int NCHUNK, int UNITS, int NTILE>
__global__ __launch_bounds__(256) void gemm3_k(
    const unsigned short* __restrict__ X, const unsigned short* __restrict__ Wb,
    const float* __restrict__ bias, const void* __restrict__ resid,
    void* __restrict__ Out, int OCTOT, unsigned short* __restrict__ qT)
{
    constexpr int KTOT = UNITS * 192;
    __shared__ unsigned short tile[2][64 * 192];

    const int tid = threadIdx.x;
    const int wave = tid >> 6, lane = tid & 63;
    const int lr = lane & 15, lg = lane >> 4;
    const int xr = lr & 7;

    auto stage = [&](int s, int buf) {
        const int t = s / UNITS, u = s - t * UNITS;
        const int gp0s = (blockIdx.x * NTILE + t) * 64;
        const unsigned short* Xb = X + (size_t)gp0s * KTOT + u * 192;
        #pragma unroll
        for (int j = 0; j < 6; j++) {
            int ci = (wave * 6 + j) * 64 + lane;
            int row = ci / 24;
            int c = ci - row * 24;
            int csw = (c & ~7) | ((c ^ row) & 7);
            gload_lds16(Xb + (size_t)row * KTOT + csw * 8, &tile[buf][ci * 8]);
        }
    };

    stage(0, 0);

    for (int t = 0; t < NTILE; t++) {
        const int gp0 = (blockIdx.x * NTILE + t) * 64;
        const int b = gp0 >> 16;
        const int pxb = gp0 & 65535;

        if constexpr (UNITS == 1) {
            __syncthreads();
            if (t + 1 < NTILE) stage(t + 1, (t + 1) & 1);
            const unsigned short* tb = tile[t & 1];

            #pragma unroll
            for (int cn = 0; cn < NCHUNK; cn++) {
                const int ocb = cn * 192 + wave * 48;
                const unsigned short* wrow = Wb + (size_t)(ocb + lr) * KTOT + lg * 8;
                const bool swapped = (MODE == 3 && cn == 0);

                s8 wf[3][6];
                #pragma unroll
                for (int ot = 0; ot < 3; ot++)
                    #pragma unroll
                    for (int kk = 0; kk < 6; kk++)
                        wf[ot][kk] = *(const s8*)(wrow + (size_t)ot * 16 * KTOT + kk * 32);

                f4 acc[4][3];
                #pragma unroll
                for (int i = 0; i < 4; i++)
                    #pragma unroll
                    for (int j = 0; j < 3; j++) acc[i][j] = (f4)0.0f;

                #pragma unroll
                for (int kk = 0; kk < 6; kk++) {
                    const int kc = kk * 4 + lg;
                    const int kcs = (kc & ~7) | ((kc ^ xr) & 7);
                    s8 a[4];
                    #pragma unroll
                    for (int pt = 0; pt < 4; pt++)
                        a[pt] = *(const s8*)&tb[((pt * 16 + lr) * 24 + kcs) * 8];
                    #pragma unroll
                    for (int ot = 0; ot < 3; ot++)
                        #pragma unroll
                        for (int pt = 0; pt < 4; pt++)
                            acc[pt][ot] = swapped
                                ? __builtin_amdgcn_mfma_f32_16x16x32_bf16(wf[ot][kk], a[pt], acc[pt][ot], 0, 0, 0)
                                : __builtin_amdgcn_mfma_f32_16x16x32_bf16(a[pt], wf[ot][kk], acc[pt][ot], 0, 0, 0);
                }

                if (MODE == 3 && cn == 0) {
                    #pragma unroll
                    for (int pt = 0; pt < 4; pt++) {
                        const int gp = gp0 + pt * 16 + lr;
                        unsigned short* orow = qT + (size_t)gp * 192 + wave * 48 + lg * 4;
                        #pragma unroll
                        for (int ot = 0; ot < 3; ot++) {
                            f4 bi4 = *(const f4*)&bias[wave * 48 + ot * 16 + lg * 4];
                            us4 o;
                            #pragma unroll
                            for (int r = 0; r < 4; r++) o[r] = f2b(__expf(acc[pt][ot][r] + bi4[r]));
                            *(us4*)(orow + ot * 16) = o;
                        }
                    }
                } else if (MODE == 3) {
                    #pragma unroll
                    for (int ot = 0; ot < 3; ot++) {
                        const int oc = ocb + ot * 16 + lr;
                        const float bi = bias[oc];
                        const size_t rowoff = ((size_t)b * 384 + (oc - 192)) * NPIX + pxb + lg * 4;
                        #pragma unroll
                        for (int pt = 0; pt < 4; pt++) {
                            us4 o;
                            #pragma unroll
                            for (int r = 0; r < 4; r++) {
                                float v = acc[pt][ot][r] + bi;
                                if (cn == 1) v = __expf(v);
                                o[r] = f2b(v);
                            }
                            *(us4*)((unsigned short*)Out + rowoff + pt * 16) = o;
                        }
                    }
                }
            }
        } else {
            // UNITS == 2, NCHUNK == 1 (w2)
            const int ocb = wave * 48;
            const unsigned short* wrow = Wb + (size_t)(ocb + lr) * KTOT + lg * 8;

            f4 acc[4][3];
            #pragma unroll
            for (int i = 0; i < 4; i++)
                #pragma unroll
                for (int j = 0; j < 3; j++) acc[i][j] = (f4)0.0f;

            #pragma unroll
            for (int u = 0; u < 2; u++) {
                const int s = t * 2 + u;
                __syncthreads();
                if (s + 1 < NTILE * 2) stage(s + 1, (s + 1) & 1);
                const unsigned short* tb = tile[s & 1];

                s8 wf[3][6];
                #pragma unroll
                for (int ot = 0; ot < 3; ot++)
                    #pragma unroll
                    for (int kk = 0; kk < 6; kk++)
                        wf[ot][kk] = *(const s8*)(wrow + (size_t)ot * 16 * KTOT + u * 192 + kk * 32);

                #pragma unroll
                for (int kk = 0; kk < 6; kk++) {
                    const int kc = kk * 4 + lg;
                    const int kcs = (kc & ~7) | ((kc ^ xr) & 7);
                    s8 a[4];
                    #pragma unroll
                    for (int pt = 0; pt < 4; pt++)
                        a[pt] = *(const s8*)&tb[((pt * 16 + lr) * 24 + kcs) * 8];
                    #pragma unroll
                    for (int ot = 0; ot < 3; ot++)
                        #pragma unroll
                        for (int pt = 0; pt < 4; pt++)
                            acc[pt][ot] = __builtin_amdgcn_mfma_f32_16x16x32_bf16(a[pt], wf[ot][kk], acc[pt][ot], 0, 0, 0);
                }
            }

            #pragma unroll
            for (int ot = 0; ot < 3; ot++) {
                const int oc = ocb + ot * 16 + lr;
                const float bi = bias[oc];
                const size_t rowoff = ((size_t)b * 192 + oc) * NPIX + pxb + lg * 4;
                #pragma unroll
                for (int pt = 0; pt < 4; pt++) {
                    if (MODE == 2) {
                        f4 rv = *(const f4*)((const float*)resid + rowoff + pt * 16);
                        f4 o;
                        #pragma unroll
                        for (int r = 0; r < 4; r++) o[r] = acc[pt][ot][r] + bi + rv[r];
                        *(f4*)((float*)Out + rowoff + pt * 16) = o;
                    } else {  // MODE 4
                        us4 rv = *(const us4*)((const unsigned short*)resid + rowoff + pt * 16);
                        f4 o;
                        #pragma unroll
                        for (int r = 0; r < 4; r++) o[r] = acc[pt][ot][r] + bi + b2f(rv[r]);
                        *(f4*)((float*)Out + rowoff + pt * 16) = o;
                    }
                }
            }
        }
    }
}

__global__ void zero_k(float* __restrict__ p, int n)
{
    int i = blockIdx.x * 256 + threadIdx.x;
    if (i < n) p[i] = 0.f;
}

__global__ void cvt_k(const float* __restrict__ src, unsigned short* __restrict__ dst, int n)
{
    int i = blockIdx.x * 256 + threadIdx.x;
    if (i < n) dst[i] = f2b(src[i]);
}

// ---------------------------------------------------------------------------
// context (exp-free) + denominator row d=24 via all-ones v fragment.
// ---------------------------------------------------------------------------
__global__ __launch_bounds__(256) void context_k(const unsigned short* __restrict__ kv,
                                                 float* __restrict__ ctxT)
{
    __shared__ float red[4][64][16];
    int bid = blockIdx.x;
    int bh = bid >> 4, cgrp = bid & 15;
    int b = bh >> 3, h = bh & 7;
    int tid = threadIdx.x;
    int wave = tid >> 6, lane = tid & 63, lr = lane & 15, lg = lane >> 4;
    int chunk = cgrp * 4 + wave;
    size_t nbase = (size_t)chunk * 1024 + lg * 8;

    int c0 = h * 24 + lr;
    int c1 = h * 24 + 16 + lr;
    bool val1 = lr < 8;

    const unsigned short* k0p = kv + ((size_t)b * 384 + c0) * NPIX + nbase;
    const unsigned short* k1p = kv + ((size_t)b * 384 + (c1 > 191 ? 191 : c1)) * NPIX + nbase;
    const unsigned short* v0p = kv + ((size_t)b * 384 + 192 + h * 24 + lr) * NPIX + nbase;
    const unsigned short* v1p = kv + ((size_t)b * 384 + 192 + ((h * 24 + 16 + lr > 191) ? 191 : h * 24 + 16 + lr)) * NPIX + nbase;

    const short one_bf = (short)0x3F80;
    s8 ones8 = { one_bf, one_bf, one_bf, one_bf, one_bf, one_bf, one_bf, one_bf };
    s8 zero8 = (s8)0;

    f4 acc[2][2];
    #pragma unroll
    for (int i = 0; i < 2; i++) for (int j = 0; j < 2; j++) acc[i][j] = (f4)0.0f;

    for (int s = 0; s < 32; s++) {
        int off = s * 32;
        s8 p0 = *(const s8*)(k0p + off);
        s8 p1 = *(const s8*)(k1p + off);
        s8 vr0 = *(const s8*)(v0p + off);
        s8 vr1 = *(const s8*)(v1p + off);
        if (!val1) p1 = zero8;
        if (lr == 8) vr1 = ones8;
        acc[0][0] = __builtin_amdgcn_mfma_f32_16x16x32_bf16(p0, vr0, acc[0][0], 0, 0, 0);
        acc[0][1] = __builtin_amdgcn_mfma_f32_16x16x32_bf16(p0, vr1, acc[0][1], 0, 0, 0);
        acc[1][0] = __builtin_amdgcn_mfma_f32_16x16x32_bf16(p1, vr0, acc[1][0], 0, 0, 0);
        acc[1][1] = __builtin_amdgcn_mfma_f32_16x16x32_bf16(p1, vr1, acc[1][1], 0, 0, 0);
    }
    #pragma unroll
    for (int mt = 0; mt < 2; mt++)
        #pragma unroll
        for (int ct = 0; ct < 2; ct++)
            #pragma unroll
            for (int r = 0; r < 4; r++)
                red[wave][lane][mt * 8 + ct * 4 + r] = acc[mt][ct][r];
    __syncthreads();

    if (wave == 0) {
        float* base = ctxT + (size_t)(b * 8 + h) * 1024;
        #pragma unroll
        for (int j = 0; j < 16; j++) {
            float sum = red[0][lane][j] + red[1][lane][j] + red[2][lane][j] + red[3][lane][j];
            int mt = j >> 3, ct = (j >> 2) & 1, r = j & 3;
            int c = mt * 16 + lg * 4 + r;
            int d = ct * 16 + lr;
            atomicAdd(base + d * 32 + c, sum);
        }
    }
}

__global__ void ctxnorm_k(float* __restrict__ ctxT)
{
    int i = blockIdx.x * 256 + threadIdx.x;
    if (i >= 1024) return;
    int bh = i >> 5, c = i & 31;
    float* base = ctxT + (size_t)bh * 1024;
    float den = base[24 * 32 + c];
    float r = den > 0.f ? 1.0f / den : 0.0f;
    #pragma unroll
    for (int d = 0; d < 24; d++) base[d * 32 + c] *= r;
}

// ---------------------------------------------------------------------------
// fused qctx+w1 (LN partials deferred to cut VGPR pressure)
// ---------------------------------------------------------------------------
template<bool BIGWS>
__global__ __launch_bounds__(256) void qctx_proj_k(
    const unsigned short* __restrict__ qT, const float* __restrict__ ctxT,
    const unsigned short* __restrict__ outWb, const float* __restrict__ outBias,
    const float* __restrict__ xres, float* __restrict__ Out,
    unsigned short* __restrict__ x2b,
    const float* __restrict__ ln2g, const float* __restrict__ ln2b,
    const unsigned short* __restrict__ w1b, const float* __restrict__ b1,
    unsigned short* __restrict__ h1t)
{
    __shared__ unsigned short outp[64][200];
    __shared__ float lnS[4][64], lnQ[4][64];

    int tid = threadIdx.x, bid = blockIdx.x;
    int b = bid >> 10, n0 = (bid & 1023) * 64;
    int wave = tid >> 6, lane = tid & 63, lr = lane & 15, lg = lane >> 4;
    const size_t bpx = (size_t)b << 16;

    #pragma unroll
    for (int hh = 0; hh < 2; hh++) {
        int h = wave * 2 + hh;
        s8 cf[2];
        #pragma unroll
        for (int mt = 0; mt < 2; mt++) {
            const float* cp = ctxT + ((size_t)(b * 8 + h) * 32 + mt * 16 + lr) * 32 + lg * 8;
            s8 a;
            #pragma unroll
            for (int j = 0; j < 8; j++) a[j] = (short)f2b(cp[j]);
            cf[mt] = a;
        }
        #pragma unroll
        for (int nt = 0; nt < 4; nt++) {
            int n = nt * 16 + lr;
            s8 bfq = (s8)0;
            float sown = 0.f;
            if (lg < 3) {
                bfq = *(const s8*)(qT + (bpx + n0 + n) * 192 + h * 24 + lg * 8);
                #pragma unroll
                for (int j = 0; j < 8; j++) sown += b2f((unsigned short)bfq[j]);
            }
            float den = sown;
            den += __shfl_xor(den, 16);
            den += __shfl_xor(den, 32);
            f4 z = (f4)0.0f;
            f4 d0 = __builtin_amdgcn_mfma_f32_16x16x32_bf16(cf[0], bfq, z, 0, 0, 0);
            f4 d1 = __builtin_amdgcn_mfma_f32_16x16x32_bf16(cf[1], bfq, z, 0, 0, 0);
            float sinv = 1.0f / den;
            us4 w0;
            #pragma unroll
            for (int r = 0; r < 4; r++) w0[r] = f2b(d0[r] * sinv);
            *(us4*)&outp[n][h * 24 + lg * 4] = w0;
            if (lg < 2) {
                us4 w1;
                #pragma unroll
                for (int r = 0; r < 4; r++) w1[r] = f2b(d1[r] * sinv);
                *(us4*)&outp[n][h * 24 + 16 + lg * 4] = w1;
            }
        }
    }
    __syncthreads();

    f4 acc[4][3];
    #pragma unroll
    for (int i = 0; i < 4; i++) for (int j = 0; j < 3; j++) acc[i][j] = (f4)0.0f;
    #pragma unroll
    for (int k0 = 0; k0 < 192; k0 += 32) {
        s8 bf[4];
        #pragma unroll
        for (int pt = 0; pt < 4; pt++)
            bf[pt] = *(const s8*)&outp[pt * 16 + lr][k0 + lg * 8];
        #pragma unroll
        for (int ot = 0; ot < 3; ot++) {
            s8 af = *(const s8*)&outWb[(size_t)(wave * 48 + ot * 16 + lr) * 192 + k0 + lg * 8];
            #pragma unroll
            for (int pt = 0; pt < 4; pt++)
                acc[pt][ot] = __builtin_amdgcn_mfma_f32_16x16x32_bf16(bf[pt], af, acc[pt][ot], 0, 0, 0);
        }
    }

    // epilogue: x2 = proj + bias + x; store; LN partials computed AFTER loop
    #pragma unroll
    for (int ot = 0; ot < 3; ot++) {
        const int oc = wave * 48 + ot * 16 + lr;
        const float bi = outBias[oc];
        const size_t rowbase = ((size_t)b * 192 + oc) * NPIX + n0 + lg * 4;
        #pragma unroll
        for (int pt = 0; pt < 4; pt++) {
            f4 rv = *(const f4*)(xres + rowbase + pt * 16);
            f4 v;
            #pragma unroll
            for (int r = 0; r < 4; r++) v[r] = acc[pt][ot][r] + bi + rv[r];
            acc[pt][ot] = v;
            if (BIGWS) {
                us4 o;
                #pragma unroll
                for (int r = 0; r < 4; r++) o[r] = f2b(v[r]);
                *(us4*)(x2b + rowbase + pt * 16) = o;
            } else {
                *(f4*)(Out + rowbase + pt * 16) = v;
            }
        }
    }
    // deferred LN partials from acc
    #pragma unroll
    for (int pt = 0; pt < 4; pt++)
        #pragma unroll
        for (int r = 0; r < 4; r++) {
            float s = acc[pt][0][r] + acc[pt][1][r] + acc[pt][2][r];
            float q = acc[pt][0][r] * acc[pt][0][r]
                    + acc[pt][1][r] * acc[pt][1][r]
                    + acc[pt][2][r] * acc[pt][2][r];
            s += __shfl_xor(s, 1); s += __shfl_xor(s, 2);
            s += __shfl_xor(s, 4); s += __shfl_xor(s, 8);
            q += __shfl_xor(q, 1); q += __shfl_xor(q, 2);
            q += __shfl_xor(q, 4); q += __shfl_xor(q, 8);
            if (lr == 0) {
                lnS[wave][pt * 16 + lg * 4 + r] = s;
                lnQ[wave][pt * 16 + lg * 4 + r] = q;
            }
        }
    __syncthreads();

    // LN2 apply -> xn into outp
    float lgv[3], lbv[3];
    #pragma unroll
    for (int ot = 0; ot < 3; ot++) {
        int oc = wave * 48 + ot * 16 + lr;
        lgv[ot] = ln2g[oc]; lbv[ot] = ln2b[oc];
    }
    #pragma unroll
    for (int pt = 0; pt < 4; pt++) {
        float mu4[4], rs4[4];
        #pragma unroll
        for (int r = 0; r < 4; r++) {
            int px = pt * 16 + lg * 4 + r;
            float S = lnS[0][px] + lnS[1][px] + lnS[2][px] + lnS[3][px];
            float Qq = lnQ[0][px] + lnQ[1][px] + lnQ[2][px] + lnQ[3][px];
            float mu = S * (1.0f / 192.0f);
            float var = Qq * (1.0f / 192.0f) - mu * mu;
            mu4[r] = mu; rs4[r] = rsqrtf(var + 1e-5f);
        }
        #pragma unroll
        for (int ot = 0; ot < 3; ot++) {
            int oc = wave * 48 + ot * 16 + lr;
            #pragma unroll
            for (int r = 0; r < 4; r++) {
                int px = pt * 16 + lg * 4 + r;
                float xn = (acc[pt][ot][r] - mu4[r]) * rs4[r] * lgv[ot] + lbv[ot];
                outp[px][oc] = f2b(xn);
            }
        }
    }
    __syncthreads();

    // w1 GEMM in place -> h1t[px][384]+gelu
    #pragma unroll
    for (int cn = 0; cn < 2; cn++) {
        const int ocb = cn * 192 + wave * 48;
        const unsigned short* wrow = w1b + (size_t)(ocb + lr) * 192 + lg * 8;

        s8 wf[3][6];
        #pragma unroll
        for (int ot = 0; ot < 3; ot++)
            #pragma unroll
            for (int kk = 0; kk < 6; kk++)
                wf[ot][kk] = *(const s8*)(wrow + (size_t)ot * 16 * 192 + kk * 32);

        f4 acc2[4][3];
        #pragma unroll
        for (int i = 0; i < 4; i++)
            #pragma unroll
            for (int j = 0; j < 3; j++) acc2[i][j] = (f4)0.0f;

        #pragma unroll
        for (int kk = 0; kk < 6; kk++) {
            s8 bf[4];
            #pragma unroll
            for (int pt = 0; pt < 4; pt++)
                bf[pt] = *(const s8*)&outp[pt * 16 + lr][kk * 32 + lg * 8];
            #pragma unroll
            for (int ot = 0; ot < 3; ot++)
                #pragma unroll
                for (int pt = 0; pt < 4; pt++)
                    acc2[pt][ot] = __builtin_amdgcn_mfma_f32_16x16x32_bf16(wf[ot][kk], bf[pt], acc2[pt][ot], 0, 0, 0);
        }

        #pragma unroll
        for (int pt = 0; pt < 4; pt++) {
            const int gp = n0 + pt * 16 + lr;
            unsigned short* orow = h1t + (bpx + gp) * 384 + ocb + lg * 4;
            #pragma unroll
            for (int ot = 0; ot < 3; ot++) {
                f4 bi4 = *(const f4*)&b1[ocb + ot * 16 + lg * 4];
                us4 o;
                #pragma unroll
                for (int r = 0; r < 4; r++) o[r] = f2b(geluf(acc2[pt][ot][r] + bi4[r]));
                *(us4*)(orow + ot * 16) = o;
            }
        }
    }
}

// ---------------------------------------------------------------------------
// depthwise 3x3 + gelu on [px][384]; ring LDS is WAVE-PRIVATE (per cg), so
// no __syncthreads: per-wave waitcnt + wave_barrier only.
// ---------------------------------------------------------------------------
__global__ __launch_bounds__(256) void dwconv_t2_k(
    const unsigned short* __restrict__ h1t, const float* __restrict__ w,
    const float* __restrict__ bias, unsigned short* __restrict__ h2t)
{
    __shared__ unsigned short ring[4 * 4 * 66 * 8];
    const int bz = blockIdx.z;
    const int b = bz / 12, cb = (bz % 12) * 32;
    const int y0 = blockIdx.y * 16, x0 = blockIdx.x * 64;
    const int tid = threadIdx.x;
    const int x = tid & 63, cg = tid >> 6;
    const int c0 = cb + cg * 8;
    const size_t bbase = (size_t)b << 16;

    float wr[9][8], bi[8];
    #pragma unroll
    for (int i = 0; i < 8; i++) {
        #pragma unroll
        for (int j = 0; j < 9; j++) wr[j][i] = rfl(w[(c0 + i) * 9 + j]);
        bi[i] = rfl(bias[c0 + i]);
    }

    const us8 zz = {0, 0, 0, 0, 0, 0, 0, 0};

    auto stage_row = [&](int gy, int s) {
        unsigned short* ldsrow = &ring[((s * 4 + cg) * 66) * 8];
        if (gy >= 0 && gy <= 255) {
            us8 ev = zz;
            if (x == 0 && x0 > 0)
                ev = *(const us8*)(h1t + (bbase + gy * 256 + x0 - 1) * 384 + c0);
            if (x == 63 && x0 + 64 < 256)
                ev = *(const us8*)(h1t + (bbase + gy * 256 + x0 + 64) * 384 + c0);
            gload_lds16(h1t + (bbase + gy * 256 + x0 + x) * 384 + c0,
                        ldsrow + (1 + x) * 8);
            if (x == 0)  *(us8*)&ldsrow[0]      = ev;
            if (x == 63) *(us8*)&ldsrow[65 * 8] = ev;
        } else {
            *(us8*)&ldsrow[(1 + x) * 8] = zz;
            if (x == 0)  *(us8*)&ldsrow[0]      = zz;
            if (x == 63) *(us8*)&ldsrow[65 * 8] = zz;
        }
    };

    stage_row(y0 - 1, 0);
    stage_row(y0,     1);
    stage_row(y0 + 1, 2);
    wave_sync();

    #pragma unroll
    for (int y = 0; y < 16; y++) {
        if (y < 15) stage_row(y0 + y + 2, (y + 3) & 3);

        float a[8];
        #pragma unroll
        for (int i = 0; i < 8; i++) a[i] = bi[i];
        #pragma unroll
        for (int t = 0; t < 3; t++) {
            const int s = (y + t) & 3;
            const unsigned short* rp = &ring[((s * 4 + cg) * 66 + x) * 8];
            us8 L = *(const us8*)(rp);
            us8 C = *(const us8*)(rp + 8);
            us8 R = *(const us8*)(rp + 16);
            #pragma unroll
            for (int i = 0; i < 8; i++) {
                a[i] += wr[t * 3 + 0][i] * b2f(L[i]);
                a[i] += wr[t * 3 + 1][i] * b2f(C[i]);
                a[i] += wr[t * 3 + 2][i] * b2f(R[i]);
            }
        }
        us8 ov;
        #pragma unroll
        for (int i = 0; i < 8; i++) ov[i] = f2b(gelu_t(a[i]));
        *(us8*)(h2t + (bbase + (y0 + y) * 256 + x0 + x) * 384 + c0) = ov;

        wave_sync();   // wait this iter's stage before next iter reads it
    }
}

// ---------------------------------------------------------------------------
extern "C" void kernel_launch(void* const* d_in, const int* in_sizes, int n_in,
                              void* d_out, int out_size, void* d_ws, size_t ws_size,
                              hipStream_t stream)
{
    const float* x    = (const float*)d_in[0];
    const float* ln1g = (const float*)d_in[1];
    const float* ln1b = (const float*)d_in[2];
    const float* qkvw = (const float*)d_in[3];
    const float* qkvb = (const float*)d_in[4];
    const float* outw = (const float*)d_in[5];
    const float* outb = (const float*)d_in[6];
    const float* ln2g = (const float*)d_in[7];
    const float* ln2b = (const float*)d_in[8];
    const float* w1   = (const float*)d_in[9];
    const float* b1   = (const float*)d_in[10];
    const float* dww  = (const float*)d_in[11];
    const float* dwb  = (const float*)d_in[12];
    const float* w2   = (const float*)d_in[13];
    const float* b2   = (const float*)d_in[14];
    float* out = (float*)d_out;

    char* ws = (char*)d_ws;
    unsigned short* kv  = (unsigned short*)ws;
    unsigned short* h1t = (unsigned short*)ws;
    unsigned short* h2t = (unsigned short*)(ws + (size_t)201326592);
    unsigned short* qT  = (unsigned short*)(ws + (size_t)201326592);
    unsigned short* xnt = (unsigned short*)(ws + (size_t)301989888);
    size_t off = (size_t)402653184;
    float* koff = (float*)(ws + off); off += 4096;
    float* ctxT = (float*)(ws + off); off += 131072;
    unsigned short* qkvwb = (unsigned short*)(ws + off); off += 221184;
    unsigned short* outwb = (unsigned short*)(ws + off); off += 73728 * 2;
    unsigned short* w1b   = (unsigned short*)(ws + off); off += 147456;
    unsigned short* w2b   = (unsigned short*)(ws + off); off += 147456;
    off = (off + 255) & ~(size_t)255;
    unsigned short* x2b = (unsigned short*)(ws + off);
    const bool bigws = ws_size >= off + (size_t)100663296;
    (void)koff;

    cvt_k<<<(110592 + 255) / 256, 256, 0, stream>>>(qkvw, qkvwb, 110592);
    cvt_k<<<(36864 + 255) / 256, 256, 0, stream>>>(outw, outwb, 36864);
    cvt_k<<<(73728 + 255) / 256, 256, 0, stream>>>(w1, w1b, 73728);
    cvt_k<<<(73728 + 255) / 256, 256, 0, stream>>>(w2, w2b, 73728);

    // 1) LN1 + transpose -> xnt
    lnt_k<<<1024, 256, 0, stream>>>(x, ln1g, ln1b, xnt);

    // 2) qkv GEMM: exp(q) -> qT, exp(k)/v -> kv
    gemm3_k<3, 3, 1, 4><<<1024, 256, 0, stream>>>(xnt, qkvwb, qkvb, nullptr, kv, 384, qT);

    // 3) context accumulation + denominator
    zero_k<<<128, 256, 0, stream>>>(ctxT, 32768);
    context_k<<<512, 256, 0, stream>>>(kv, ctxT);

    // 4) normalize ctx
    ctxnorm_k<<<4, 256, 0, stream>>>(ctxT);

    // 5) qctx fused (+LN2 +w1+gelu -> h1t)
    if (bigws)
        qctx_proj_k<true><<<4096, 256, 0, stream>>>(qT, ctxT, outwb, outb, x, out,
                                                    x2b, ln2g, ln2b, w1b, b1, h1t);
    else
        qctx_proj_k<false><<<4096, 256, 0, stream>>>(qT, ctxT, outwb, outb, x, out,
                                                     x2b, ln2g, ln2b, w1b, b1, h1t);

    // 6) depthwise 3x3 + gelu -> h2t
    dwconv_t2_k<<<dim3(4, 16, 48), 256, 0, stream>>>(h1t, dww, dwb, h2t);

    // 7) w2 GEMM + bias + x2 residual -> d_out f32
    if (bigws)
        gemm3_k<4, 1, 2, 4><<<1024, 256, 0, stream>>>(h2t, w2b, b2, x2b, out, 192, nullptr);
    else
        gemm3_k<2, 1, 2, 4><<<1024, 256, 0, stream>>>(h2t, w2b, b2, out, out, 192, nullptr);
}

// Round 17
// 858.010 us; speedup vs baseline: 1.0530x; 1.0530x over previous
//
#include <hip/hip_runtime.h>
#include <math.h>

typedef __attribute__((ext_vector_type(8))) short s8;
typedef __attribute__((ext_vector_type(8))) unsigned short us8;
typedef __attribute__((ext_vector_type(4))) float f4;
typedef __attribute__((ext_vector_type(4))) unsigned short us4;
typedef __attribute__((ext_vector_type(4))) unsigned int u32x4;

#define DEVI __device__ __forceinline__

static const int NPIX = 65536;   // 256*256

DEVI float b2f(unsigned short u) {
    unsigned int v = ((unsigned int)u) << 16;
    float f; __builtin_memcpy(&f, &v, 4); return f;
}
DEVI unsigned short f2b(float f) {
    unsigned int u; __builtin_memcpy(&u, &f, 4);
    unsigned int r = (u + 0x7FFFu + ((u >> 16) & 1u)) >> 16;
    return (unsigned short)r;
}
DEVI float geluf(float x) { return 0.5f * x * (1.0f + erff(x * 0.70710678118f)); }
DEVI float gelu_t(float x) {
    float z = 1.595769122f * (x + 0.044715f * x * x * x);
    return x * __builtin_amdgcn_rcpf(1.0f + __expf(-z));
}
DEVI float rfl(float v) {
    int i; __builtin_memcpy(&i, &v, 4);
    i = __builtin_amdgcn_readfirstlane(i);
    float o; __builtin_memcpy(&o, &i, 4); return o;
}

DEVI void gload_lds16(const unsigned short* g, unsigned short* l) {
    __builtin_amdgcn_global_load_lds(
        (const __attribute__((address_space(1))) unsigned int*)g,
        (__attribute__((address_space(3))) unsigned int*)l,
        16, 0, 0);
}

// ---------------------------------------------------------------------------
// LayerNorm + transpose: x f32 [b][192][px] -> xnt bf16 [b*px][192]
// ---------------------------------------------------------------------------
__global__ __launch_bounds__(256) void lnt_k(const float* __restrict__ X,
                                             const float* __restrict__ gw,
                                             const float* __restrict__ gb,
                                             unsigned short* __restrict__ Out)
{
    const int i = blockIdx.x * 256 + threadIdx.x;
    const int b = i >> 16, px = i & 65535;
    const float* xp = X + (size_t)b * 192 * NPIX + px;

    unsigned int pk[96];
    float sum = 0.f, ssq = 0.f;
    #pragma unroll
    for (int c = 0; c < 192; c++) {
        float v = xp[(size_t)c * NPIX];
        sum += v; ssq += v * v;
        unsigned int h = f2b(v);
        if (c & 1) pk[c >> 1] |= h << 16;
        else       pk[c >> 1] = h;
    }
    float mu = sum * (1.0f / 192.0f);
    float var = ssq * (1.0f / 192.0f) - mu * mu;
    float rs = rsqrtf(var + 1e-5f);

    #pragma unroll
    for (int c2 = 0; c2 < 96; c2++) {
        int c = c2 * 2;
        float lo = b2f((unsigned short)(pk[c2] & 0xFFFF));
        float hi = b2f((unsigned short)(pk[c2] >> 16));
        lo = (lo - mu) * rs * gw[c] + gb[c];
        hi = (hi - mu) * rs * gw[c + 1] + gb[c + 1];
        pk[c2] = (unsigned int)f2b(lo) | ((unsigned int)f2b(hi) << 16);
    }
    u32x4* dst = (u32x4*)(Out + (size_t)i * 192);
    #pragma unroll
    for (int j = 0; j < 6; j++) {
        u32x4 v = { pk[4 * j], pk[4 * j + 1], pk[4 * j + 2], pk[4 * j + 3] };
        dst[j] = v;
    }
}

// ---------------------------------------------------------------------------
// Pipelined staged GEMM.
// MODE 2: out f32  [b][192][px], bias + f32 resid    (w2, small-ws)
// MODE 3: qkv: cn==0 -> exp(q) -> qT[gp][192]; cn==1 -> exp(k); cn==2 -> v
// MODE 4: out f32  [b][192][px], bias + bf16 resid   (w2, big-ws)
// ---------------------------------------------------------------------------
template<int MODE, int NCHUNK, int UNITS, int NTILE>
__global__ __launch_bounds__(256) void gemm3_k(
    const unsigned short* __restrict__ X, const unsigned short* __restrict__ Wb,
    const float* __restrict__ bias, const void* __restrict__ resid,
    void* __restrict__ Out, int OCTOT, unsigned short* __restrict__ qT)
{
    constexpr int KTOT = UNITS * 192;
    __shared__ unsigned short tile[2][64 * 192];

    const int tid = threadIdx.x;
    const int wave = tid >> 6, lane = tid & 63;
    const int lr = lane & 15, lg = lane >> 4;
    const int xr = lr & 7;

    auto stage = [&](int s, int buf) {
        const int t = s / UNITS, u = s - t * UNITS;
        const int gp0s = (blockIdx.x * NTILE + t) * 64;
        const unsigned short* Xb = X + (size_t)gp0s * KTOT + u * 192;
        #pragma unroll
        for (int j = 0; j < 6; j++) {
            int ci = (wave * 6 + j) * 64 + lane;
            int row = ci / 24;
            int c = ci - row * 24;
            int csw = (c & ~7) | ((c ^ row) & 7);
            gload_lds16(Xb + (size_t)row * KTOT + csw * 8, &tile[buf][ci * 8]);
        }
    };

    stage(0, 0);

    for (int t = 0; t < NTILE; t++) {
        const int gp0 = (blockIdx.x * NTILE + t) * 64;
        const int b = gp0 >> 16;
        const int pxb = gp0 & 65535;

        if constexpr (UNITS == 1) {
            __syncthreads();
            if (t + 1 < NTILE) stage(t + 1, (t + 1) & 1);
            const unsigned short* tb = tile[t & 1];

            #pragma unroll
            for (int cn = 0; cn < NCHUNK; cn++) {
                const int ocb = cn * 192 + wave * 48;
                const unsigned short* wrow = Wb + (size_t)(ocb + lr) * KTOT + lg * 8;
                const bool swapped = (MODE == 3 && cn == 0);

                s8 wf[3][6];
                #pragma unroll
                for (int ot = 0; ot < 3; ot++)
                    #pragma unroll
                    for (int kk = 0; kk < 6; kk++)
                        wf[ot][kk] = *(const s8*)(wrow + (size_t)ot * 16 * KTOT + kk * 32);

                f4 acc[4][3];
                #pragma unroll
                for (int i = 0; i < 4; i++)
                    #pragma unroll
                    for (int j = 0; j < 3; j++) acc[i][j] = (f4)0.0f;

                #pragma unroll
                for (int kk = 0; kk < 6; kk++) {
                    const int kc = kk * 4 + lg;
                    const int kcs = (kc & ~7) | ((kc ^ xr) & 7);
                    s8 a[4];
                    #pragma unroll
                    for (int pt = 0; pt < 4; pt++)
                        a[pt] = *(const s8*)&tb[((pt * 16 + lr) * 24 + kcs) * 8];
                    #pragma unroll
                    for (int ot = 0; ot < 3; ot++)
                        #pragma unroll
                        for (int pt = 0; pt < 4; pt++)
                            acc[pt][ot] = swapped
                                ? __builtin_amdgcn_mfma_f32_16x16x32_bf16(wf[ot][kk], a[pt], acc[pt][ot], 0, 0, 0)
                                : __builtin_amdgcn_mfma_f32_16x16x32_bf16(a[pt], wf[ot][kk], acc[pt][ot], 0, 0, 0);
                }

                if (MODE == 3 && cn == 0) {
                    #pragma unroll
                    for (int pt = 0; pt < 4; pt++) {
                        const int gp = gp0 + pt * 16 + lr;
                        unsigned short* orow = qT + (size_t)gp * 192 + wave * 48 + lg * 4;
                        #pragma unroll
                        for (int ot = 0; ot < 3; ot++) {
                            f4 bi4 = *(const f4*)&bias[wave * 48 + ot * 16 + lg * 4];
                            us4 o;
                            #pragma unroll
                            for (int r = 0; r < 4; r++) o[r] = f2b(__expf(acc[pt][ot][r] + bi4[r]));
                            *(us4*)(orow + ot * 16) = o;
                        }
                    }
                } else if (MODE == 3) {
                    #pragma unroll
                    for (int ot = 0; ot < 3; ot++) {
                        const int oc = ocb + ot * 16 + lr;
                        const float bi = bias[oc];
                        const size_t rowoff = ((size_t)b * 384 + (oc - 192)) * NPIX + pxb + lg * 4;
                        #pragma unroll
                        for (int pt = 0; pt < 4; pt++) {
                            us4 o;
                            #pragma unroll
                            for (int r = 0; r < 4; r++) {
                                float v = acc[pt][ot][r] + bi;
                                if (cn == 1) v = __expf(v);
                                o[r] = f2b(v);
                            }
                            *(us4*)((unsigned short*)Out + rowoff + pt * 16) = o;
                        }
                    }
                }
            }
        } else {
            // UNITS == 2, NCHUNK == 1 (w2)
            const int ocb = wave * 48;
            const unsigned short* wrow = Wb + (size_t)(ocb + lr) * KTOT + lg * 8;

            f4 acc[4][3];
            #pragma unroll
            for (int i = 0; i < 4; i++)
                #pragma unroll
                for (int j = 0; j < 3; j++) acc[i][j] = (f4)0.0f;

            #pragma unroll
            for (int u = 0; u < 2; u++) {
                const int s = t * 2 + u;
                __syncthreads();
                if (s + 1 < NTILE * 2) stage(s + 1, (s + 1) & 1);
                const unsigned short* tb = tile[s & 1];

                s8 wf[3][6];
                #pragma unroll
                for (int ot = 0; ot < 3; ot++)
                    #pragma unroll
                    for (int kk = 0; kk < 6; kk++)
                        wf[ot][kk] = *(const s8*)(wrow + (size_t)ot * 16 * KTOT + u * 192 + kk * 32);

                #pragma unroll
                for (int kk = 0; kk < 6; kk++) {
                    const int kc = kk * 4 + lg;
                    const int kcs = (kc & ~7) | ((kc ^ xr) & 7);
                    s8 a[4];
                    #pragma unroll
                    for (int pt = 0; pt < 4; pt++)
                        a[pt] = *(const s8*)&tb[((pt * 16 + lr) * 24 + kcs) * 8];
                    #pragma unroll
                    for (int ot = 0; ot < 3; ot++)
                        #pragma unroll
                        for (int pt = 0; pt < 4; pt++)
                            acc[pt][ot] = __builtin_amdgcn_mfma_f32_16x16x32_bf16(a[pt], wf[ot][kk], acc[pt][ot], 0, 0, 0);
                }
            }

            #pragma unroll
            for (int ot = 0; ot < 3; ot++) {
                const int oc = ocb + ot * 16 + lr;
                const float bi = bias[oc];
                const size_t rowoff = ((size_t)b * 192 + oc) * NPIX + pxb + lg * 4;
                #pragma unroll
                for (int pt = 0; pt < 4; pt++) {
                    if (MODE == 2) {
                        f4 rv = *(const f4*)((const float*)resid + rowoff + pt * 16);
                        f4 o;
                        #pragma unroll
                        for (int r = 0; r < 4; r++) o[r] = acc[pt][ot][r] + bi + rv[r];
                        *(f4*)((float*)Out + rowoff + pt * 16) = o;
                    } else {  // MODE 4
                        us4 rv = *(const us4*)((const unsigned short*)resid + rowoff + pt * 16);
                        f4 o;
                        #pragma unroll
                        for (int r = 0; r < 4; r++) o[r] = acc[pt][ot][r] + bi + b2f(rv[r]);
                        *(f4*)((float*)Out + rowoff + pt * 16) = o;
                    }
                }
            }
        }
    }
}

__global__ void zero_k(float* __restrict__ p, int n)
{
    int i = blockIdx.x * 256 + threadIdx.x;
    if (i < n) p[i] = 0.f;
}

__global__ void cvt_k(const float* __restrict__ src, unsigned short* __restrict__ dst, int n)
{
    int i = blockIdx.x * 256 + threadIdx.x;
    if (i < n) dst[i] = f2b(src[i]);
}

// ---------------------------------------------------------------------------
// context (exp-free) + denominator row d=24 via all-ones v fragment.
// ---------------------------------------------------------------------------
__global__ __launch_bounds__(256) void context_k(const unsigned short* __restrict__ kv,
                                                 float* __restrict__ ctxT)
{
    __shared__ float red[4][64][16];
    int bid = blockIdx.x;
    int bh = bid >> 4, cgrp = bid & 15;
    int b = bh >> 3, h = bh & 7;
    int tid = threadIdx.x;
    int wave = tid >> 6, lane = tid & 63, lr = lane & 15, lg = lane >> 4;
    int chunk = cgrp * 4 + wave;
    size_t nbase = (size_t)chunk * 1024 + lg * 8;

    int c0 = h * 24 + lr;
    int c1 = h * 24 + 16 + lr;
    bool val1 = lr < 8;

    const unsigned short* k0p = kv + ((size_t)b * 384 + c0) * NPIX + nbase;
    const unsigned short* k1p = kv + ((size_t)b * 384 + (c1 > 191 ? 191 : c1)) * NPIX + nbase;
    const unsigned short* v0p = kv + ((size_t)b * 384 + 192 + h * 24 + lr) * NPIX + nbase;
    const unsigned short* v1p = kv + ((size_t)b * 384 + 192 + ((h * 24 + 16 + lr > 191) ? 191 : h * 24 + 16 + lr)) * NPIX + nbase;

    const short one_bf = (short)0x3F80;
    s8 ones8 = { one_bf, one_bf, one_bf, one_bf, one_bf, one_bf, one_bf, one_bf };
    s8 zero8 = (s8)0;

    f4 acc[2][2];
    #pragma unroll
    for (int i = 0; i < 2; i++) for (int j = 0; j < 2; j++) acc[i][j] = (f4)0.0f;

    for (int s = 0; s < 32; s++) {
        int off = s * 32;
        s8 p0 = *(const s8*)(k0p + off);
        s8 p1 = *(const s8*)(k1p + off);
        s8 vr0 = *(const s8*)(v0p + off);
        s8 vr1 = *(const s8*)(v1p + off);
        if (!val1) p1 = zero8;
        if (lr == 8) vr1 = ones8;
        acc[0][0] = __builtin_amdgcn_mfma_f32_16x16x32_bf16(p0, vr0, acc[0][0], 0, 0, 0);
        acc[0][1] = __builtin_amdgcn_mfma_f32_16x16x32_bf16(p0, vr1, acc[0][1], 0, 0, 0);
        acc[1][0] = __builtin_amdgcn_mfma_f32_16x16x32_bf16(p1, vr0, acc[1][0], 0, 0, 0);
        acc[1][1] = __builtin_amdgcn_mfma_f32_16x16x32_bf16(p1, vr1, acc[1][1], 0, 0, 0);
    }
    #pragma unroll
    for (int mt = 0; mt < 2; mt++)
        #pragma unroll
        for (int ct = 0; ct < 2; ct++)
            #pragma unroll
            for (int r = 0; r < 4; r++)
                red[wave][lane][mt * 8 + ct * 4 + r] = acc[mt][ct][r];
    __syncthreads();

    if (wave == 0) {
        float* base = ctxT + (size_t)(b * 8 + h) * 1024;
        #pragma unroll
        for (int j = 0; j < 16; j++) {
            float sum = red[0][lane][j] + red[1][lane][j] + red[2][lane][j] + red[3][lane][j];
            int mt = j >> 3, ct = (j >> 2) & 1, r = j & 3;
            int c = mt * 16 + lg * 4 + r;
            int d = ct * 16 + lr;
            atomicAdd(base + d * 32 + c, sum);
        }
    }
}

__global__ void ctxnorm_k(float* __restrict__ ctxT)
{
    int i = blockIdx.x * 256 + threadIdx.x;
    if (i >= 1024) return;
    int bh = i >> 5, c = i & 31;
    float* base = ctxT + (size_t)bh * 1024;
    float den = base[24 * 32 + c];
    float r = den > 0.f ? 1.0f / den : 0.0f;
    #pragma unroll
    for (int d = 0; d < 24; d++) base[d * 32 + c] *= r;
}

// ---------------------------------------------------------------------------
// fused qctx+w1 (R15 form: in-loop LN partials)
// ---------------------------------------------------------------------------
template<bool BIGWS>
__global__ __launch_bounds__(256) void qctx_proj_k(
    const unsigned short* __restrict__ qT, const float* __restrict__ ctxT,
    const unsigned short* __restrict__ outWb, const float* __restrict__ outBias,
    const float* __restrict__ xres, float* __restrict__ Out,
    unsigned short* __restrict__ x2b,
    const float* __restrict__ ln2g, const float* __restrict__ ln2b,
    const unsigned short* __restrict__ w1b, const float* __restrict__ b1,
    unsigned short* __restrict__ h1t)
{
    __shared__ unsigned short outp[64][200];
    __shared__ float lnS[4][64], lnQ[4][64];

    int tid = threadIdx.x, bid = blockIdx.x;
    int b = bid >> 10, n0 = (bid & 1023) * 64;
    int wave = tid >> 6, lane = tid & 63, lr = lane & 15, lg = lane >> 4;
    const size_t bpx = (size_t)b << 16;

    #pragma unroll
    for (int hh = 0; hh < 2; hh++) {
        int h = wave * 2 + hh;
        s8 cf[2];
        #pragma unroll
        for (int mt = 0; mt < 2; mt++) {
            const float* cp = ctxT + ((size_t)(b * 8 + h) * 32 + mt * 16 + lr) * 32 + lg * 8;
            s8 a;
            #pragma unroll
            for (int j = 0; j < 8; j++) a[j] = (short)f2b(cp[j]);
            cf[mt] = a;
        }
        #pragma unroll
        for (int nt = 0; nt < 4; nt++) {
            int n = nt * 16 + lr;
            s8 bfq = (s8)0;
            float sown = 0.f;
            if (lg < 3) {
                bfq = *(const s8*)(qT + (bpx + n0 + n) * 192 + h * 24 + lg * 8);
                #pragma unroll
                for (int j = 0; j < 8; j++) sown += b2f((unsigned short)bfq[j]);
            }
            float den = sown;
            den += __shfl_xor(den, 16);
            den += __shfl_xor(den, 32);
            f4 z = (f4)0.0f;
            f4 d0 = __builtin_amdgcn_mfma_f32_16x16x32_bf16(cf[0], bfq, z, 0, 0, 0);
            f4 d1 = __builtin_amdgcn_mfma_f32_16x16x32_bf16(cf[1], bfq, z, 0, 0, 0);
            float sinv = 1.0f / den;
            us4 w0;
            #pragma unroll
            for (int r = 0; r < 4; r++) w0[r] = f2b(d0[r] * sinv);
            *(us4*)&outp[n][h * 24 + lg * 4] = w0;
            if (lg < 2) {
                us4 w1;
                #pragma unroll
                for (int r = 0; r < 4; r++) w1[r] = f2b(d1[r] * sinv);
                *(us4*)&outp[n][h * 24 + 16 + lg * 4] = w1;
            }
        }
    }
    __syncthreads();

    f4 acc[4][3];
    #pragma unroll
    for (int i = 0; i < 4; i++) for (int j = 0; j < 3; j++) acc[i][j] = (f4)0.0f;
    #pragma unroll
    for (int k0 = 0; k0 < 192; k0 += 32) {
        s8 bf[4];
        #pragma unroll
        for (int pt = 0; pt < 4; pt++)
            bf[pt] = *(const s8*)&outp[pt * 16 + lr][k0 + lg * 8];
        #pragma unroll
        for (int ot = 0; ot < 3; ot++) {
            s8 af = *(const s8*)&outWb[(size_t)(wave * 48 + ot * 16 + lr) * 192 + k0 + lg * 8];
            #pragma unroll
            for (int pt = 0; pt < 4; pt++)
                acc[pt][ot] = __builtin_amdgcn_mfma_f32_16x16x32_bf16(bf[pt], af, acc[pt][ot], 0, 0, 0);
        }
    }

    float sP[4][4], qP[4][4];
    #pragma unroll
    for (int pt = 0; pt < 4; pt++)
        #pragma unroll
        for (int r = 0; r < 4; r++) { sP[pt][r] = 0.f; qP[pt][r] = 0.f; }

    #pragma unroll
    for (int ot = 0; ot < 3; ot++) {
        const int oc = wave * 48 + ot * 16 + lr;
        const float bi = outBias[oc];
        const size_t rowbase = ((size_t)b * 192 + oc) * NPIX + n0 + lg * 4;
        #pragma unroll
        for (int pt = 0; pt < 4; pt++) {
            f4 rv = *(const f4*)(xres + rowbase + pt * 16);
            f4 v;
            #pragma unroll
            for (int r = 0; r < 4; r++) {
                v[r] = acc[pt][ot][r] + bi + rv[r];
                sP[pt][r] += v[r]; qP[pt][r] += v[r] * v[r];
            }
            acc[pt][ot] = v;
            if (BIGWS) {
                us4 o;
                #pragma unroll
                for (int r = 0; r < 4; r++) o[r] = f2b(v[r]);
                *(us4*)(x2b + rowbase + pt * 16) = o;
            } else {
                *(f4*)(Out + rowbase + pt * 16) = v;
            }
        }
    }
    #pragma unroll
    for (int pt = 0; pt < 4; pt++)
        #pragma unroll
        for (int r = 0; r < 4; r++) {
            float s = sP[pt][r], q = qP[pt][r];
            s += __shfl_xor(s, 1); s += __shfl_xor(s, 2);
            s += __shfl_xor(s, 4); s += __shfl_xor(s, 8);
            q += __shfl_xor(q, 1); q += __shfl_xor(q, 2);
            q += __shfl_xor(q, 4); q += __shfl_xor(q, 8);
            sP[pt][r] = s; qP[pt][r] = q;
        }
    if (lr == 0) {
        #pragma unroll
        for (int pt = 0; pt < 4; pt++)
            #pragma unroll
            for (int r = 0; r < 4; r++) {
                lnS[wave][pt * 16 + lg * 4 + r] = sP[pt][r];
                lnQ[wave][pt * 16 + lg * 4 + r] = qP[pt][r];
            }
    }
    __syncthreads();

    // LN2 apply -> xn into outp
    float lgv[3], lbv[3];
    #pragma unroll
    for (int ot = 0; ot < 3; ot++) {
        int oc = wave * 48 + ot * 16 + lr;
        lgv[ot] = ln2g[oc]; lbv[ot] = ln2b[oc];
    }
    #pragma unroll
    for (int pt = 0; pt < 4; pt++) {
        float mu4[4], rs4[4];
        #pragma unroll
        for (int r = 0; r < 4; r++) {
            int px = pt * 16 + lg * 4 + r;
            float S = lnS[0][px] + lnS[1][px] + lnS[2][px] + lnS[3][px];
            float Qq = lnQ[0][px] + lnQ[1][px] + lnQ[2][px] + lnQ[3][px];
            float mu = S * (1.0f / 192.0f);
            float var = Qq * (1.0f / 192.0f) - mu * mu;
            mu4[r] = mu; rs4[r] = rsqrtf(var + 1e-5f);
        }
        #pragma unroll
        for (int ot = 0; ot < 3; ot++) {
            int oc = wave * 48 + ot * 16 + lr;
            #pragma unroll
            for (int r = 0; r < 4; r++) {
                int px = pt * 16 + lg * 4 + r;
                float xn = (acc[pt][ot][r] - mu4[r]) * rs4[r] * lgv[ot] + lbv[ot];
                outp[px][oc] = f2b(xn);
            }
        }
    }
    __syncthreads();

    // w1 GEMM in place -> h1t[px][384]+gelu
    #pragma unroll
    for (int cn = 0; cn < 2; cn++) {
        const int ocb = cn * 192 + wave * 48;
        const unsigned short* wrow = w1b + (size_t)(ocb + lr) * 192 + lg * 8;

        s8 wf[3][6];
        #pragma unroll
        for (int ot = 0; ot < 3; ot++)
            #pragma unroll
            for (int kk = 0; kk < 6; kk++)
                wf[ot][kk] = *(const s8*)(wrow + (size_t)ot * 16 * 192 + kk * 32);

        f4 acc2[4][3];
        #pragma unroll
        for (int i = 0; i < 4; i++)
            #pragma unroll
            for (int j = 0; j < 3; j++) acc2[i][j] = (f4)0.0f;

        #pragma unroll
        for (int kk = 0; kk < 6; kk++) {
            s8 bf[4];
            #pragma unroll
            for (int pt = 0; pt < 4; pt++)
                bf[pt] = *(const s8*)&outp[pt * 16 + lr][kk * 32 + lg * 8];
            #pragma unroll
            for (int ot = 0; ot < 3; ot++)
                #pragma unroll
                for (int pt = 0; pt < 4; pt++)
                    acc2[pt][ot] = __builtin_amdgcn_mfma_f32_16x16x32_bf16(wf[ot][kk], bf[pt], acc2[pt][ot], 0, 0, 0);
        }

        #pragma unroll
        for (int pt = 0; pt < 4; pt++) {
            const int gp = n0 + pt * 16 + lr;
            unsigned short* orow = h1t + (bpx + gp) * 384 + ocb + lg * 4;
            #pragma unroll
            for (int ot = 0; ot < 3; ot++) {
                f4 bi4 = *(const f4*)&b1[ocb + ot * 16 + lg * 4];
                us4 o;
                #pragma unroll
                for (int r = 0; r < 4; r++) o[r] = f2b(geluf(acc2[pt][ot][r] + bi4[r]));
                *(us4*)(orow + ot * 16) = o;
            }
        }
    }
}

// ---------------------------------------------------------------------------
// depthwise 3x3 + gelu on [px][384], row-streamed LDS ring; 16 rows/block.
// ---------------------------------------------------------------------------
__global__ __launch_bounds__(256) void dwconv_t2_k(
    const unsigned short* __restrict__ h1t, const float* __restrict__ w,
    const float* __restrict__ bias, unsigned short* __restrict__ h2t)
{
    __shared__ unsigned short ring[4 * 4 * 66 * 8];
    const int bz = blockIdx.z;
    const int b = bz / 12, cb = (bz % 12) * 32;
    const int y0 = blockIdx.y * 16, x0 = blockIdx.x * 64;
    const int tid = threadIdx.x;
    const int x = tid & 63, cg = tid >> 6;
    const int c0 = cb + cg * 8;
    const size_t bbase = (size_t)b << 16;

    float wr[9][8], bi[8];
    #pragma unroll
    for (int i = 0; i < 8; i++) {
        #pragma unroll
        for (int j = 0; j < 9; j++) wr[j][i] = rfl(w[(c0 + i) * 9 + j]);
        bi[i] = rfl(bias[c0 + i]);
    }

    const us8 zz = {0, 0, 0, 0, 0, 0, 0, 0};

    auto stage_row = [&](int gy, int s) {
        unsigned short* ldsrow = &ring[((s * 4 + cg) * 66) * 8];
        if (gy >= 0 && gy <= 255) {
            us8 ev = zz;
            if (x == 0 && x0 > 0)
                ev = *(const us8*)(h1t + (bbase + gy * 256 + x0 - 1) * 384 + c0);
            if (x == 63 && x0 + 64 < 256)
                ev = *(const us8*)(h1t + (bbase + gy * 256 + x0 + 64) * 384 + c0);
            gload_lds16(h1t + (bbase + gy * 256 + x0 + x) * 384 + c0,
                        ldsrow + (1 + x) * 8);
            if (x == 0)  *(us8*)&ldsrow[0]      = ev;
            if (x == 63) *(us8*)&ldsrow[65 * 8] = ev;
        } else {
            *(us8*)&ldsrow[(1 + x) * 8] = zz;
            if (x == 0)  *(us8*)&ldsrow[0]      = zz;
            if (x == 63) *(us8*)&ldsrow[65 * 8] = zz;
        }
    };

    stage_row(y0 - 1, 0);
    stage_row(y0,     1);
    stage_row(y0 + 1, 2);
    __syncthreads();

    #pragma unroll
    for (int y = 0; y < 16; y++) {
        if (y < 15) stage_row(y0 + y + 2, (y + 3) & 3);

        float a[8];
        #pragma unroll
        for (int i = 0; i < 8; i++) a[i] = bi[i];
        #pragma unroll
        for (int t = 0; t < 3; t++) {
            const int s = (y + t) & 3;
            const unsigned short* rp = &ring[((s * 4 + cg) * 66 + x) * 8];
            us8 L = *(const us8*)(rp);
            us8 C = *(const us8*)(rp + 8);
            us8 R = *(const us8*)(rp + 16);
            #pragma unroll
            for (int i = 0; i < 8; i++) {
                a[i] += wr[t * 3 + 0][i] * b2f(L[i]);
                a[i] += wr[t * 3 + 1][i] * b2f(C[i]);
                a[i] += wr[t * 3 + 2][i] * b2f(R[i]);
            }
        }
        us8 ov;
        #pragma unroll
        for (int i = 0; i < 8; i++) ov[i] = f2b(gelu_t(a[i]));
        *(us8*)(h2t + (bbase + (y0 + y) * 256 + x0 + x) * 384 + c0) = ov;

        __syncthreads();
    }
}

// ---------------------------------------------------------------------------
extern "C" void kernel_launch(void* const* d_in, const int* in_sizes, int n_in,
                              void* d_out, int out_size, void* d_ws, size_t ws_size,
                              hipStream_t stream)
{
    const float* x    = (const float*)d_in[0];
    const float* ln1g = (const float*)d_in[1];
    const float* ln1b = (const float*)d_in[2];
    const float* qkvw = (const float*)d_in[3];
    const float* qkvb = (const float*)d_in[4];
    const float* outw = (const float*)d_in[5];
    const float* outb = (const float*)d_in[6];
    const float* ln2g = (const float*)d_in[7];
    const float* ln2b = (const float*)d_in[8];
    const float* w1   = (const float*)d_in[9];
    const float* b1   = (const float*)d_in[10];
    const float* dww  = (const float*)d_in[11];
    const float* dwb  = (const float*)d_in[12];
    const float* w2   = (const float*)d_in[13];
    const float* b2   = (const float*)d_in[14];
    float* out = (float*)d_out;

    char* ws = (char*)d_ws;
    unsigned short* kv  = (unsigned short*)ws;
    unsigned short* h1t = (unsigned short*)ws;
    unsigned short* h2t = (unsigned short*)(ws + (size_t)201326592);
    unsigned short* qT  = (unsigned short*)(ws + (size_t)201326592);
    unsigned short* xnt = (unsigned short*)(ws + (size_t)301989888);
    size_t off = (size_t)402653184;
    float* koff = (float*)(ws + off); off += 4096;
    float* ctxT = (float*)(ws + off); off += 131072;
    unsigned short* qkvwb = (unsigned short*)(ws + off); off += 221184;
    unsigned short* outwb = (unsigned short*)(ws + off); off += 73728 * 2;
    unsigned short* w1b   = (unsigned short*)(ws + off); off += 147456;
    unsigned short* w2b   = (unsigned short*)(ws + off); off += 147456;
    off = (off + 255) & ~(size_t)255;
    unsigned short* x2b = (unsigned short*)(ws + off);
    const bool bigws = ws_size >= off + (size_t)100663296;
    (void)koff;

    cvt_k<<<(110592 + 255) / 256, 256, 0, stream>>>(qkvw, qkvwb, 110592);
    cvt_k<<<(36864 + 255) / 256, 256, 0, stream>>>(outw, outwb, 36864);
    cvt_k<<<(73728 + 255) / 256, 256, 0, stream>>>(w1, w1b, 73728);
    cvt_k<<<(73728 + 255) / 256, 256, 0, stream>>>(w2, w2b, 73728);

    // 1) LN1 + transpose -> xnt
    lnt_k<<<1024, 256, 0, stream>>>(x, ln1g, ln1b, xnt);

    // 2) qkv GEMM: exp(q) -> qT, exp(k)/v -> kv
    gemm3_k<3, 3, 1, 4><<<1024, 256, 0, stream>>>(xnt, qkvwb, qkvb, nullptr, kv, 384, qT);

    // 3) context accumulation + denominator
    zero_k<<<128, 256, 0, stream>>>(ctxT, 32768);
    context_k<<<512, 256, 0, stream>>>(kv, ctxT);

    // 4) normalize ctx
    ctxnorm_k<<<4, 256, 0, stream>>>(ctxT);

    // 5) qctx fused (+LN2 +w1+gelu -> h1t)
    if (bigws)
        qctx_proj_k<true><<<4096, 256, 0, stream>>>(qT, ctxT, outwb, outb, x, out,
                                                    x2b, ln2g, ln2b, w1b, b1, h1t);
    else
        qctx_proj_k<false><<<4096, 256, 0, stream>>>(qT, ctxT, outwb, outb, x, out,
                                                     x2b, ln2g, ln2b, w1b, b1, h1t);

    // 6) depthwise 3x3 + gelu -> h2t
    dwconv_t2_k<<<dim3(4, 16, 48), 256, 0, stream>>>(h1t, dww, dwb, h2t);

    // 7) w2 GEMM + bias + x2 residual -> d_out f32
    if (bigws)
        gemm3_k<4, 1, 2, 4><<<1024, 256, 0, stream>>>(h2t, w2b, b2, x2b, out, 192, nullptr);
    else
        gemm3_k<2, 1, 2, 4><<<1024, 256, 0, stream>>>(h2t, w2b, b2, out, out, 192, nullptr);
}

// Round 18
// 854.360 us; speedup vs baseline: 1.0575x; 1.0043x over previous
//
#include <hip/hip_runtime.h>
#include <math.h>

typedef __attribute__((ext_vector_type(8))) short s8;
typedef __attribute__((ext_vector_type(8))) unsigned short us8;
typedef __attribute__((ext_vector_type(4))) float f4;
typedef __attribute__((ext_vector_type(4))) unsigned short us4;
typedef __attribute__((ext_vector_type(4))) unsigned int u32x4;

#define DEVI __device__ __forceinline__

static const int NPIX = 65536;   // 256*256

DEVI float b2f(unsigned short u) {
    unsigned int v = ((unsigned int)u) << 16;
    float f; __builtin_memcpy(&f, &v, 4); return f;
}
DEVI unsigned short f2b(float f) {
    unsigned int u; __builtin_memcpy(&u, &f, 4);
    unsigned int r = (u + 0x7FFFu + ((u >> 16) & 1u)) >> 16;
    return (unsigned short)r;
}
DEVI float geluf(float x) { return 0.5f * x * (1.0f + erff(x * 0.70710678118f)); }
DEVI float gelu_t(float x) {
    float z = 1.595769122f * (x + 0.044715f * x * x * x);
    return x * __builtin_amdgcn_rcpf(1.0f + __expf(-z));
}
DEVI float rfl(float v) {
    int i; __builtin_memcpy(&i, &v, 4);
    i = __builtin_amdgcn_readfirstlane(i);
    float o; __builtin_memcpy(&o, &i, 4); return o;
}

DEVI void gload_lds16(const unsigned short* g, unsigned short* l) {
    __builtin_amdgcn_global_load_lds(
        (const __attribute__((address_space(1))) unsigned int*)g,
        (__attribute__((address_space(3))) unsigned int*)l,
        16, 0, 0);
}

// ---------------------------------------------------------------------------
// LayerNorm + transpose: x f32 [b][192][px] -> xnt bf16 [b*px][192]
// ---------------------------------------------------------------------------
__global__ __launch_bounds__(256) void lnt_k(const float* __restrict__ X,
                                             const float* __restrict__ gw,
                                             const float* __restrict__ gb,
                                             unsigned short* __restrict__ Out)
{
    const int i = blockIdx.x * 256 + threadIdx.x;
    const int b = i >> 16, px = i & 65535;
    const float* xp = X + (size_t)b * 192 * NPIX + px;

    unsigned int pk[96];
    float sum = 0.f, ssq = 0.f;
    #pragma unroll
    for (int c = 0; c < 192; c++) {
        float v = xp[(size_t)c * NPIX];
        sum += v; ssq += v * v;
        unsigned int h = f2b(v);
        if (c & 1) pk[c >> 1] |= h << 16;
        else       pk[c >> 1] = h;
    }
    float mu = sum * (1.0f / 192.0f);
    float var = ssq * (1.0f / 192.0f) - mu * mu;
    float rs = rsqrtf(var + 1e-5f);

    #pragma unroll
    for (int c2 = 0; c2 < 96; c2++) {
        int c = c2 * 2;
        float lo = b2f((unsigned short)(pk[c2] & 0xFFFF));
        float hi = b2f((unsigned short)(pk[c2] >> 16));
        lo = (lo - mu) * rs * gw[c] + gb[c];
        hi = (hi - mu) * rs * gw[c + 1] + gb[c + 1];
        pk[c2] = (unsigned int)f2b(lo) | ((unsigned int)f2b(hi) << 16);
    }
    u32x4* dst = (u32x4*)(Out + (size_t)i * 192);
    #pragma unroll
    for (int j = 0; j < 6; j++) {
        u32x4 v = { pk[4 * j], pk[4 * j + 1], pk[4 * j + 2], pk[4 * j + 3] };
        dst[j] = v;
    }
}

// ---------------------------------------------------------------------------
// Pipelined staged GEMM.
// MODE 2: out f32  [b][192][px], bias + f32 resid    (w2, small-ws)
// MODE 3: qkv: cn==0 -> exp(q) -> qT[gp][192]; cn==1 -> exp(k); cn==2 -> v
// MODE 4: out f32  [b][192][px], bias + bf16 resid   (w2, big-ws)
// ---------------------------------------------------------------------------
template<int MODE, int NCHUNK, int UNITS, int NTILE>
__global__ __launch_bounds__(256) void gemm3_k(
    const unsigned short* __restrict__ X, const unsigned short* __restrict__ Wb,
    const float* __restrict__ bias, const void* __restrict__ resid,
    void* __restrict__ Out, int OCTOT, unsigned short* __restrict__ qT)
{
    constexpr int KTOT = UNITS * 192;
    __shared__ unsigned short tile[2][64 * 192];

    const int tid = threadIdx.x;
    const int wave = tid >> 6, lane = tid & 63;
    const int lr = lane & 15, lg = lane >> 4;
    const int xr = lr & 7;

    auto stage = [&](int s, int buf) {
        const int t = s / UNITS, u = s - t * UNITS;
        const int gp0s = (blockIdx.x * NTILE + t) * 64;
        const unsigned short* Xb = X + (size_t)gp0s * KTOT + u * 192;
        #pragma unroll
        for (int j = 0; j < 6; j++) {
            int ci = (wave * 6 + j) * 64 + lane;
            int row = ci / 24;
            int c = ci - row * 24;
            int csw = (c & ~7) | ((c ^ row) & 7);
            gload_lds16(Xb + (size_t)row * KTOT + csw * 8, &tile[buf][ci * 8]);
        }
    };

    stage(0, 0);

    for (int t = 0; t < NTILE; t++) {
        const int gp0 = (blockIdx.x * NTILE + t) * 64;
        const int b = gp0 >> 16;
        const int pxb = gp0 & 65535;

        if constexpr (UNITS == 1) {
            __syncthreads();
            if (t + 1 < NTILE) stage(t + 1, (t + 1) & 1);
            const unsigned short* tb = tile[t & 1];

            #pragma unroll
            for (int cn = 0; cn < NCHUNK; cn++) {
                const int ocb = cn * 192 + wave * 48;
                const unsigned short* wrow = Wb + (size_t)(ocb + lr) * KTOT + lg * 8;
                const bool swapped = (MODE == 3 && cn == 0);

                s8 wf[3][6];
                #pragma unroll
                for (int ot = 0; ot < 3; ot++)
                    #pragma unroll
                    for (int kk = 0; kk < 6; kk++)
                        wf[ot][kk] = *(const s8*)(wrow + (size_t)ot * 16 * KTOT + kk * 32);

                f4 acc[4][3];
                #pragma unroll
                for (int i = 0; i < 4; i++)
                    #pragma unroll
                    for (int j = 0; j < 3; j++) acc[i][j] = (f4)0.0f;

                #pragma unroll
                for (int kk = 0; kk < 6; kk++) {
                    const int kc = kk * 4 + lg;
                    const int kcs = (kc & ~7) | ((kc ^ xr) & 7);
                    s8 a[4];
                    #pragma unroll
                    for (int pt = 0; pt < 4; pt++)
                        a[pt] = *(const s8*)&tb[((pt * 16 + lr) * 24 + kcs) * 8];
                    #pragma unroll
                    for (int ot = 0; ot < 3; ot++)
                        #pragma unroll
                        for (int pt = 0; pt < 4; pt++)
                            acc[pt][ot] = swapped
                                ? __builtin_amdgcn_mfma_f32_16x16x32_bf16(wf[ot][kk], a[pt], acc[pt][ot], 0, 0, 0)
                                : __builtin_amdgcn_mfma_f32_16x16x32_bf16(a[pt], wf[ot][kk], acc[pt][ot], 0, 0, 0);
                }

                if (MODE == 3 && cn == 0) {
                    #pragma unroll
                    for (int pt = 0; pt < 4; pt++) {
                        const int gp = gp0 + pt * 16 + lr;
                        unsigned short* orow = qT + (size_t)gp * 192 + wave * 48 + lg * 4;
                        #pragma unroll
                        for (int ot = 0; ot < 3; ot++) {
                            f4 bi4 = *(const f4*)&bias[wave * 48 + ot * 16 + lg * 4];
                            us4 o;
                            #pragma unroll
                            for (int r = 0; r < 4; r++) o[r] = f2b(__expf(acc[pt][ot][r] + bi4[r]));
                            *(us4*)(orow + ot * 16) = o;
                        }
                    }
                } else if (MODE == 3) {
                    #pragma unroll
                    for (int ot = 0; ot < 3; ot++) {
                        const int oc = ocb + ot * 16 + lr;
                        const float bi = bias[oc];
                        const size_t rowoff = ((size_t)b * 384 + (oc - 192)) * NPIX + pxb + lg * 4;
                        #pragma unroll
                        for (int pt = 0; pt < 4; pt++) {
                            us4 o;
                            #pragma unroll
                            for (int r = 0; r < 4; r++) {
                                float v = acc[pt][ot][r] + bi;
                                if (cn == 1) v = __expf(v);
                                o[r] = f2b(v);
                            }
                            *(us4*)((unsigned short*)Out + rowoff + pt * 16) = o;
                        }
                    }
                }
            }
        } else {
            // UNITS == 2, NCHUNK == 1 (w2)
            const int ocb = wave * 48;
            const unsigned short* wrow = Wb + (size_t)(ocb + lr) * KTOT + lg * 8;

            f4 acc[4][3];
            #pragma unroll
            for (int i = 0; i < 4; i++)
                #pragma unroll
                for (int j = 0; j < 3; j++) acc[i][j] = (f4)0.0f;

            #pragma unroll
            for (int u = 0; u < 2; u++) {
                const int s = t * 2 + u;
                __syncthreads();
                if (s + 1 < NTILE * 2) stage(s + 1, (s + 1) & 1);
                const unsigned short* tb = tile[s & 1];

                s8 wf[3][6];
                #pragma unroll
                for (int ot = 0; ot < 3; ot++)
                    #pragma unroll
                    for (int kk = 0; kk < 6; kk++)
                        wf[ot][kk] = *(const s8*)(wrow + (size_t)ot * 16 * KTOT + u * 192 + kk * 32);

                #pragma unroll
                for (int kk = 0; kk < 6; kk++) {
                    const int kc = kk * 4 + lg;
                    const int kcs = (kc & ~7) | ((kc ^ xr) & 7);
                    s8 a[4];
                    #pragma unroll
                    for (int pt = 0; pt < 4; pt++)
                        a[pt] = *(const s8*)&tb[((pt * 16 + lr) * 24 + kcs) * 8];
                    #pragma unroll
                    for (int ot = 0; ot < 3; ot++)
                        #pragma unroll
                        for (int pt = 0; pt < 4; pt++)
                            acc[pt][ot] = __builtin_amdgcn_mfma_f32_16x16x32_bf16(a[pt], wf[ot][kk], acc[pt][ot], 0, 0, 0);
                }
            }

            #pragma unroll
            for (int ot = 0; ot < 3; ot++) {
                const int oc = ocb + ot * 16 + lr;
                const float bi = bias[oc];
                const size_t rowoff = ((size_t)b * 192 + oc) * NPIX + pxb + lg * 4;
                #pragma unroll
                for (int pt = 0; pt < 4; pt++) {
                    if (MODE == 2) {
                        f4 rv = *(const f4*)((const float*)resid + rowoff + pt * 16);
                        f4 o;
                        #pragma unroll
                        for (int r = 0; r < 4; r++) o[r] = acc[pt][ot][r] + bi + rv[r];
                        *(f4*)((float*)Out + rowoff + pt * 16) = o;
                    } else {  // MODE 4
                        us4 rv = *(const us4*)((const unsigned short*)resid + rowoff + pt * 16);
                        f4 o;
                        #pragma unroll
                        for (int r = 0; r < 4; r++) o[r] = acc[pt][ot][r] + bi + b2f(rv[r]);
                        *(f4*)((float*)Out + rowoff + pt * 16) = o;
                    }
                }
            }
        }
    }
}

__global__ void zero_k(float* __restrict__ p, int n)
{
    int i = blockIdx.x * 256 + threadIdx.x;
    if (i < n) p[i] = 0.f;
}

__global__ void cvt_k(const float* __restrict__ src, unsigned short* __restrict__ dst, int n)
{
    int i = blockIdx.x * 256 + threadIdx.x;
    if (i < n) dst[i] = f2b(src[i]);
}

// ---------------------------------------------------------------------------
// context (exp-free) + denominator row d=24 via all-ones v fragment.
// ---------------------------------------------------------------------------
__global__ __launch_bounds__(256) void context_k(const unsigned short* __restrict__ kv,
                                                 float* __restrict__ ctxT)
{
    __shared__ float red[4][64][16];
    int bid = blockIdx.x;
    int bh = bid >> 4, cgrp = bid & 15;
    int b = bh >> 3, h = bh & 7;
    int tid = threadIdx.x;
    int wave = tid >> 6, lane = tid & 63, lr = lane & 15, lg = lane >> 4;
    int chunk = cgrp * 4 + wave;
    size_t nbase = (size_t)chunk * 1024 + lg * 8;

    int c0 = h * 24 + lr;
    int c1 = h * 24 + 16 + lr;
    bool val1 = lr < 8;

    const unsigned short* k0p = kv + ((size_t)b * 384 + c0) * NPIX + nbase;
    const unsigned short* k1p = kv + ((size_t)b * 384 + (c1 > 191 ? 191 : c1)) * NPIX + nbase;
    const unsigned short* v0p = kv + ((size_t)b * 384 + 192 + h * 24 + lr) * NPIX + nbase;
    const unsigned short* v1p = kv + ((size_t)b * 384 + 192 + ((h * 24 + 16 + lr > 191) ? 191 : h * 24 + 16 + lr)) * NPIX + nbase;

    const short one_bf = (short)0x3F80;
    s8 ones8 = { one_bf, one_bf, one_bf, one_bf, one_bf, one_bf, one_bf, one_bf };
    s8 zero8 = (s8)0;

    f4 acc[2][2];
    #pragma unroll
    for (int i = 0; i < 2; i++) for (int j = 0; j < 2; j++) acc[i][j] = (f4)0.0f;

    for (int s = 0; s < 32; s++) {
        int off = s * 32;
        s8 p0 = *(const s8*)(k0p + off);
        s8 p1 = *(const s8*)(k1p + off);
        s8 vr0 = *(const s8*)(v0p + off);
        s8 vr1 = *(const s8*)(v1p + off);
        if (!val1) p1 = zero8;
        if (lr == 8) vr1 = ones8;
        acc[0][0] = __builtin_amdgcn_mfma_f32_16x16x32_bf16(p0, vr0, acc[0][0], 0, 0, 0);
        acc[0][1] = __builtin_amdgcn_mfma_f32_16x16x32_bf16(p0, vr1, acc[0][1], 0, 0, 0);
        acc[1][0] = __builtin_amdgcn_mfma_f32_16x16x32_bf16(p1, vr0, acc[1][0], 0, 0, 0);
        acc[1][1] = __builtin_amdgcn_mfma_f32_16x16x32_bf16(p1, vr1, acc[1][1], 0, 0, 0);
    }
    #pragma unroll
    for (int mt = 0; mt < 2; mt++)
        #pragma unroll
        for (int ct = 0; ct < 2; ct++)
            #pragma unroll
            for (int r = 0; r < 4; r++)
                red[wave][lane][mt * 8 + ct * 4 + r] = acc[mt][ct][r];
    __syncthreads();

    if (wave == 0) {
        float* base = ctxT + (size_t)(b * 8 + h) * 1024;
        #pragma unroll
        for (int j = 0; j < 16; j++) {
            float sum = red[0][lane][j] + red[1][lane][j] + red[2][lane][j] + red[3][lane][j];
            int mt = j >> 3, ct = (j >> 2) & 1, r = j & 3;
            int c = mt * 16 + lg * 4 + r;
            int d = ct * 16 + lr;
            atomicAdd(base + d * 32 + c, sum);
        }
    }
}

// ---------------------------------------------------------------------------
// normalize ctx rows 0..23 by denominator; also emit bf16 copy ctxb[bh][32][32]
// (rows 24..31 zeroed) for vectorized fragment loads in qctx.
// ---------------------------------------------------------------------------
__global__ void ctxnorm_k(float* __restrict__ ctxT, unsigned short* __restrict__ ctxb)
{
    int i = blockIdx.x * 256 + threadIdx.x;
    if (i >= 1024) return;
    int bh = i >> 5, c = i & 31;
    float* base = ctxT + (size_t)bh * 1024;
    unsigned short* bb = ctxb + (size_t)bh * 1024;
    float den = base[24 * 32 + c];
    float r = den > 0.f ? 1.0f / den : 0.0f;
    #pragma unroll
    for (int d = 0; d < 24; d++) {
        float v = base[d * 32 + c] * r;
        bb[d * 32 + c] = f2b(v);
    }
    #pragma unroll
    for (int d = 24; d < 32; d++) bb[d * 32 + c] = 0;
}

// ---------------------------------------------------------------------------
// fused qctx+w1 (ctx fragments loaded as bf16 16B vectors from ctxb)
// ---------------------------------------------------------------------------
template<bool BIGWS>
__global__ __launch_bounds__(256) void qctx_proj_k(
    const unsigned short* __restrict__ qT, const unsigned short* __restrict__ ctxb,
    const unsigned short* __restrict__ outWb, const float* __restrict__ outBias,
    const float* __restrict__ xres, float* __restrict__ Out,
    unsigned short* __restrict__ x2b,
    const float* __restrict__ ln2g, const float* __restrict__ ln2b,
    const unsigned short* __restrict__ w1b, const float* __restrict__ b1,
    unsigned short* __restrict__ h1t)
{
    __shared__ unsigned short outp[64][200];
    __shared__ float lnS[4][64], lnQ[4][64];

    int tid = threadIdx.x, bid = blockIdx.x;
    int b = bid >> 10, n0 = (bid & 1023) * 64;
    int wave = tid >> 6, lane = tid & 63, lr = lane & 15, lg = lane >> 4;
    const size_t bpx = (size_t)b << 16;

    #pragma unroll
    for (int hh = 0; hh < 2; hh++) {
        int h = wave * 2 + hh;
        const unsigned short* cb = ctxb + (size_t)(b * 8 + h) * 1024;
        s8 cf[2];
        #pragma unroll
        for (int mt = 0; mt < 2; mt++)
            cf[mt] = *(const s8*)(cb + (mt * 16 + lr) * 32 + lg * 8);
        #pragma unroll
        for (int nt = 0; nt < 4; nt++) {
            int n = nt * 16 + lr;
            s8 bfq = (s8)0;
            float sown = 0.f;
            if (lg < 3) {
                bfq = *(const s8*)(qT + (bpx + n0 + n) * 192 + h * 24 + lg * 8);
                #pragma unroll
                for (int j = 0; j < 8; j++) sown += b2f((unsigned short)bfq[j]);
            }
            float den = sown;
            den += __shfl_xor(den, 16);
            den += __shfl_xor(den, 32);
            f4 z = (f4)0.0f;
            f4 d0 = __builtin_amdgcn_mfma_f32_16x16x32_bf16(cf[0], bfq, z, 0, 0, 0);
            f4 d1 = __builtin_amdgcn_mfma_f32_16x16x32_bf16(cf[1], bfq, z, 0, 0, 0);
            float sinv = 1.0f / den;
            us4 w0;
            #pragma unroll
            for (int r = 0; r < 4; r++) w0[r] = f2b(d0[r] * sinv);
            *(us4*)&outp[n][h * 24 + lg * 4] = w0;
            if (lg < 2) {
                us4 w1;
                #pragma unroll
                for (int r = 0; r < 4; r++) w1[r] = f2b(d1[r] * sinv);
                *(us4*)&outp[n][h * 24 + 16 + lg * 4] = w1;
            }
        }
    }
    __syncthreads();

    f4 acc[4][3];
    #pragma unroll
    for (int i = 0; i < 4; i++) for (int j = 0; j < 3; j++) acc[i][j] = (f4)0.0f;
    #pragma unroll
    for (int k0 = 0; k0 < 192; k0 += 32) {
        s8 bf[4];
        #pragma unroll
        for (int pt = 0; pt < 4; pt++)
            bf[pt] = *(const s8*)&outp[pt * 16 + lr][k0 + lg * 8];
        #pragma unroll
        for (int ot = 0; ot < 3; ot++) {
            s8 af = *(const s8*)&outWb[(size_t)(wave * 48 + ot * 16 + lr) * 192 + k0 + lg * 8];
            #pragma unroll
            for (int pt = 0; pt < 4; pt++)
                acc[pt][ot] = __builtin_amdgcn_mfma_f32_16x16x32_bf16(bf[pt], af, acc[pt][ot], 0, 0, 0);
        }
    }

    float sP[4][4], qP[4][4];
    #pragma unroll
    for (int pt = 0; pt < 4; pt++)
        #pragma unroll
        for (int r = 0; r < 4; r++) { sP[pt][r] = 0.f; qP[pt][r] = 0.f; }

    #pragma unroll
    for (int ot = 0; ot < 3; ot++) {
        const int oc = wave * 48 + ot * 16 + lr;
        const float bi = outBias[oc];
        const size_t rowbase = ((size_t)b * 192 + oc) * NPIX + n0 + lg * 4;
        #pragma unroll
        for (int pt = 0; pt < 4; pt++) {
            f4 rv = *(const f4*)(xres + rowbase + pt * 16);
            f4 v;
            #pragma unroll
            for (int r = 0; r < 4; r++) {
                v[r] = acc[pt][ot][r] + bi + rv[r];
                sP[pt][r] += v[r]; qP[pt][r] += v[r] * v[r];
            }
            acc[pt][ot] = v;
            if (BIGWS) {
                us4 o;
                #pragma unroll
                for (int r = 0; r < 4; r++) o[r] = f2b(v[r]);
                *(us4*)(x2b + rowbase + pt * 16) = o;
            } else {
                *(f4*)(Out + rowbase + pt * 16) = v;
            }
        }
    }
    #pragma unroll
    for (int pt = 0; pt < 4; pt++)
        #pragma unroll
        for (int r = 0; r < 4; r++) {
            float s = sP[pt][r], q = qP[pt][r];
            s += __shfl_xor(s, 1); s += __shfl_xor(s, 2);
            s += __shfl_xor(s, 4); s += __shfl_xor(s, 8);
            q += __shfl_xor(q, 1); q += __shfl_xor(q, 2);
            q += __shfl_xor(q, 4); q += __shfl_xor(q, 8);
            sP[pt][r] = s; qP[pt][r] = q;
        }
    if (lr == 0) {
        #pragma unroll
        for (int pt = 0; pt < 4; pt++)
            #pragma unroll
            for (int r = 0; r < 4; r++) {
                lnS[wave][pt * 16 + lg * 4 + r] = sP[pt][r];
                lnQ[wave][pt * 16 + lg * 4 + r] = qP[pt][r];
            }
    }
    __syncthreads();

    // LN2 apply -> xn into outp
    float lgv[3], lbv[3];
    #pragma unroll
    for (int ot = 0; ot < 3; ot++) {
        int oc = wave * 48 + ot * 16 + lr;
        lgv[ot] = ln2g[oc]; lbv[ot] = ln2b[oc];
    }
    #pragma unroll
    for (int pt = 0; pt < 4; pt++) {
        float mu4[4], rs4[4];
        #pragma unroll
        for (int r = 0; r < 4; r++) {
            int px = pt * 16 + lg * 4 + r;
            float S = lnS[0][px] + lnS[1][px] + lnS[2][px] + lnS[3][px];
            float Qq = lnQ[0][px] + lnQ[1][px] + lnQ[2][px] + lnQ[3][px];
            float mu = S * (1.0f / 192.0f);
            float var = Qq * (1.0f / 192.0f) - mu * mu;
            mu4[r] = mu; rs4[r] = rsqrtf(var + 1e-5f);
        }
        #pragma unroll
        for (int ot = 0; ot < 3; ot++) {
            int oc = wave * 48 + ot * 16 + lr;
            #pragma unroll
            for (int r = 0; r < 4; r++) {
                int px = pt * 16 + lg * 4 + r;
                float xn = (acc[pt][ot][r] - mu4[r]) * rs4[r] * lgv[ot] + lbv[ot];
                outp[px][oc] = f2b(xn);
            }
        }
    }
    __syncthreads();

    // w1 GEMM in place -> h1t[px][384]+gelu
    #pragma unroll
    for (int cn = 0; cn < 2; cn++) {
        const int ocb = cn * 192 + wave * 48;
        const unsigned short* wrow = w1b + (size_t)(ocb + lr) * 192 + lg * 8;

        s8 wf[3][6];
        #pragma unroll
        for (int ot = 0; ot < 3; ot++)
            #pragma unroll
            for (int kk = 0; kk < 6; kk++)
                wf[ot][kk] = *(const s8*)(wrow + (size_t)ot * 16 * 192 + kk * 32);

        f4 acc2[4][3];
        #pragma unroll
        for (int i = 0; i < 4; i++)
            #pragma unroll
            for (int j = 0; j < 3; j++) acc2[i][j] = (f4)0.0f;

        #pragma unroll
        for (int kk = 0; kk < 6; kk++) {
            s8 bf[4];
            #pragma unroll
            for (int pt = 0; pt < 4; pt++)
                bf[pt] = *(const s8*)&outp[pt * 16 + lr][kk * 32 + lg * 8];
            #pragma unroll
            for (int ot = 0; ot < 3; ot++)
                #pragma unroll
                for (int pt = 0; pt < 4; pt++)
                    acc2[pt][ot] = __builtin_amdgcn_mfma_f32_16x16x32_bf16(wf[ot][kk], bf[pt], acc2[pt][ot], 0, 0, 0);
        }

        #pragma unroll
        for (int pt = 0; pt < 4; pt++) {
            const int gp = n0 + pt * 16 + lr;
            unsigned short* orow = h1t + (bpx + gp) * 384 + ocb + lg * 4;
            #pragma unroll
            for (int ot = 0; ot < 3; ot++) {
                f4 bi4 = *(const f4*)&b1[ocb + ot * 16 + lg * 4];
                us4 o;
                #pragma unroll
                for (int r = 0; r < 4; r++) o[r] = f2b(geluf(acc2[pt][ot][r] + bi4[r]));
                *(us4*)(orow + ot * 16) = o;
            }
        }
    }
}

// ---------------------------------------------------------------------------
// depthwise 3x3 + gelu on [px][384], row-streamed LDS ring; 16 rows/block.
// ---------------------------------------------------------------------------
__global__ __launch_bounds__(256) void dwconv_t2_k(
    const unsigned short* __restrict__ h1t, const float* __restrict__ w,
    const float* __restrict__ bias, unsigned short* __restrict__ h2t)
{
    __shared__ unsigned short ring[4 * 4 * 66 * 8];
    const int bz = blockIdx.z;
    const int b = bz / 12, cb = (bz % 12) * 32;
    const int y0 = blockIdx.y * 16, x0 = blockIdx.x * 64;
    const int tid = threadIdx.x;
    const int x = tid & 63, cg = tid >> 6;
    const int c0 = cb + cg * 8;
    const size_t bbase = (size_t)b << 16;

    float wr[9][8], bi[8];
    #pragma unroll
    for (int i = 0; i < 8; i++) {
        #pragma unroll
        for (int j = 0; j < 9; j++) wr[j][i] = rfl(w[(c0 + i) * 9 + j]);
        bi[i] = rfl(bias[c0 + i]);
    }

    const us8 zz = {0, 0, 0, 0, 0, 0, 0, 0};

    auto stage_row = [&](int gy, int s) {
        unsigned short* ldsrow = &ring[((s * 4 + cg) * 66) * 8];
        if (gy >= 0 && gy <= 255) {
            us8 ev = zz;
            if (x == 0 && x0 > 0)
                ev = *(const us8*)(h1t + (bbase + gy * 256 + x0 - 1) * 384 + c0);
            if (x == 63 && x0 + 64 < 256)
                ev = *(const us8*)(h1t + (bbase + gy * 256 + x0 + 64) * 384 + c0);
            gload_lds16(h1t + (bbase + gy * 256 + x0 + x) * 384 + c0,
                        ldsrow + (1 + x) * 8);
            if (x == 0)  *(us8*)&ldsrow[0]      = ev;
            if (x == 63) *(us8*)&ldsrow[65 * 8] = ev;
        } else {
            *(us8*)&ldsrow[(1 + x) * 8] = zz;
            if (x == 0)  *(us8*)&ldsrow[0]      = zz;
            if (x == 63) *(us8*)&ldsrow[65 * 8] = zz;
        }
    };

    stage_row(y0 - 1, 0);
    stage_row(y0,     1);
    stage_row(y0 + 1, 2);
    __syncthreads();

    #pragma unroll
    for (int y = 0; y < 16; y++) {
        if (y < 15) stage_row(y0 + y + 2, (y + 3) & 3);

        float a[8];
        #pragma unroll
        for (int i = 0; i < 8; i++) a[i] = bi[i];
        #pragma unroll
        for (int t = 0; t < 3; t++) {
            const int s = (y + t) & 3;
            const unsigned short* rp = &ring[((s * 4 + cg) * 66 + x) * 8];
            us8 L = *(const us8*)(rp);
            us8 C = *(const us8*)(rp + 8);
            us8 R = *(const us8*)(rp + 16);
            #pragma unroll
            for (int i = 0; i < 8; i++) {
                a[i] += wr[t * 3 + 0][i] * b2f(L[i]);
                a[i] += wr[t * 3 + 1][i] * b2f(C[i]);
                a[i] += wr[t * 3 + 2][i] * b2f(R[i]);
            }
        }
        us8 ov;
        #pragma unroll
        for (int i = 0; i < 8; i++) ov[i] = f2b(gelu_t(a[i]));
        *(us8*)(h2t + (bbase + (y0 + y) * 256 + x0 + x) * 384 + c0) = ov;

        __syncthreads();
    }
}

// ---------------------------------------------------------------------------
extern "C" void kernel_launch(void* const* d_in, const int* in_sizes, int n_in,
                              void* d_out, int out_size, void* d_ws, size_t ws_size,
                              hipStream_t stream)
{
    const float* x    = (const float*)d_in[0];
    const float* ln1g = (const float*)d_in[1];
    const float* ln1b = (const float*)d_in[2];
    const float* qkvw = (const float*)d_in[3];
    const float* qkvb = (const float*)d_in[4];
    const float* outw = (const float*)d_in[5];
    const float* outb = (const float*)d_in[6];
    const float* ln2g = (const float*)d_in[7];
    const float* ln2b = (const float*)d_in[8];
    const float* w1   = (const float*)d_in[9];
    const float* b1   = (const float*)d_in[10];
    const float* dww  = (const float*)d_in[11];
    const float* dwb  = (const float*)d_in[12];
    const float* w2   = (const float*)d_in[13];
    const float* b2   = (const float*)d_in[14];
    float* out = (float*)d_out;

    char* ws = (char*)d_ws;
    unsigned short* kv  = (unsigned short*)ws;
    unsigned short* h1t = (unsigned short*)ws;
    unsigned short* h2t = (unsigned short*)(ws + (size_t)201326592);
    unsigned short* qT  = (unsigned short*)(ws + (size_t)201326592);
    unsigned short* xnt = (unsigned short*)(ws + (size_t)301989888);
    size_t off = (size_t)402653184;
    float* koff = (float*)(ws + off); off += 4096;
    float* ctxT = (float*)(ws + off); off += 131072;
    unsigned short* ctxb = (unsigned short*)(ws + off); off += 65536;
    unsigned short* qkvwb = (unsigned short*)(ws + off); off += 221184;
    unsigned short* outwb = (unsigned short*)(ws + off); off += 73728 * 2;
    unsigned short* w1b   = (unsigned short*)(ws + off); off += 147456;
    unsigned short* w2b   = (unsigned short*)(ws + off); off += 147456;
    off = (off + 255) & ~(size_t)255;
    unsigned short* x2b = (unsigned short*)(ws + off);
    const bool bigws = ws_size >= off + (size_t)100663296;
    (void)koff;

    cvt_k<<<(110592 + 255) / 256, 256, 0, stream>>>(qkvw, qkvwb, 110592);
    cvt_k<<<(36864 + 255) / 256, 256, 0, stream>>>(outw, outwb, 36864);
    cvt_k<<<(73728 + 255) / 256, 256, 0, stream>>>(w1, w1b, 73728);
    cvt_k<<<(73728 + 255) / 256, 256, 0, stream>>>(w2, w2b, 73728);

    // 1) LN1 + transpose -> xnt
    lnt_k<<<1024, 256, 0, stream>>>(x, ln1g, ln1b, xnt);

    // 2) qkv GEMM: exp(q) -> qT, exp(k)/v -> kv
    gemm3_k<3, 3, 1, 4><<<1024, 256, 0, stream>>>(xnt, qkvwb, qkvb, nullptr, kv, 384, qT);

    // 3) context accumulation + denominator
    zero_k<<<128, 256, 0, stream>>>(ctxT, 32768);
    context_k<<<512, 256, 0, stream>>>(kv, ctxT);

    // 4) normalize ctx -> also bf16 copy ctxb
    ctxnorm_k<<<4, 256, 0, stream>>>(ctxT, ctxb);

    // 5) qctx fused (+LN2 +w1+gelu -> h1t), ctx frags from ctxb (16B loads)
    if (bigws)
        qctx_proj_k<true><<<4096, 256, 0, stream>>>(qT, ctxb, outwb, outb, x, out,
                                                    x2b, ln2g, ln2b, w1b, b1, h1t);
    else
        qctx_proj_k<false><<<4096, 256, 0, stream>>>(qT, ctxb, outwb, outb, x, out,
                                                     x2b, ln2g, ln2b, w1b, b1, h1t);

    // 6) depthwise 3x3 + gelu -> h2t
    dwconv_t2_k<<<dim3(4, 16, 48), 256, 0, stream>>>(h1t, dww, dwb, h2t);

    // 7) w2 GEMM + bias + x2 residual -> d_out f32
    if (bigws)
        gemm3_k<4, 1, 2, 4><<<1024, 256, 0, stream>>>(h2t, w2b, b2, x2b, out, 192, nullptr);
    else
        gemm3_k<2, 1, 2, 4><<<1024, 256, 0, stream>>>(h2t, w2b, b2, out, out, 192, nullptr);
}

// Round 19
// 838.957 us; speedup vs baseline: 1.0769x; 1.0184x over previous
//
#include <hip/hip_runtime.h>
#include <math.h>

typedef __attribute__((ext_vector_type(8))) short s8;
typedef __attribute__((ext_vector_type(8))) unsigned short us8;
typedef __attribute__((ext_vector_type(4))) float f4;
typedef __attribute__((ext_vector_type(4))) unsigned short us4;
typedef __attribute__((ext_vector_type(4))) unsigned int u32x4;

#define DEVI __device__ __forceinline__

static const int NPIX = 65536;   // 256*256

DEVI float b2f(unsigned short u) {
    unsigned int v = ((unsigned int)u) << 16;
    float f; __builtin_memcpy(&f, &v, 4); return f;
}
DEVI unsigned short f2b(float f) {
    unsigned int u; __builtin_memcpy(&u, &f, 4);
    unsigned int r = (u + 0x7FFFu + ((u >> 16) & 1u)) >> 16;
    return (unsigned short)r;
}
DEVI float geluf(float x) { return 0.5f * x * (1.0f + erff(x * 0.70710678118f)); }
DEVI float gelu_t(float x) {
    float z = 1.595769122f * (x + 0.044715f * x * x * x);
    return x * __builtin_amdgcn_rcpf(1.0f + __expf(-z));
}
DEVI float rfl(float v) {
    int i; __builtin_memcpy(&i, &v, 4);
    i = __builtin_amdgcn_readfirstlane(i);
    float o; __builtin_memcpy(&o, &i, 4); return o;
}

DEVI void gload_lds16(const unsigned short* g, unsigned short* l) {
    __builtin_amdgcn_global_load_lds(
        (const __attribute__((address_space(1))) unsigned int*)g,
        (__attribute__((address_space(3))) unsigned int*)l,
        16, 0, 0);
}

// ---------------------------------------------------------------------------
// LayerNorm + transpose: x f32 [b][192][px] -> xnt bf16 [b*px][192]
// ---------------------------------------------------------------------------
__global__ __launch_bounds__(256) void lnt_k(const float* __restrict__ X,
                                             const float* __restrict__ gw,
                                             const float* __restrict__ gb,
                                             unsigned short* __restrict__ Out)
{
    const int i = blockIdx.x * 256 + threadIdx.x;
    const int b = i >> 16, px = i & 65535;
    const float* xp = X + (size_t)b * 192 * NPIX + px;

    unsigned int pk[96];
    float sum = 0.f, ssq = 0.f;
    #pragma unroll
    for (int c = 0; c < 192; c++) {
        float v = xp[(size_t)c * NPIX];
        sum += v; ssq += v * v;
        unsigned int h = f2b(v);
        if (c & 1) pk[c >> 1] |= h << 16;
        else       pk[c >> 1] = h;
    }
    float mu = sum * (1.0f / 192.0f);
    float var = ssq * (1.0f / 192.0f) - mu * mu;
    float rs = rsqrtf(var + 1e-5f);

    #pragma unroll
    for (int c2 = 0; c2 < 96; c2++) {
        int c = c2 * 2;
        float lo = b2f((unsigned short)(pk[c2] & 0xFFFF));
        float hi = b2f((unsigned short)(pk[c2] >> 16));
        lo = (lo - mu) * rs * gw[c] + gb[c];
        hi = (hi - mu) * rs * gw[c + 1] + gb[c + 1];
        pk[c2] = (unsigned int)f2b(lo) | ((unsigned int)f2b(hi) << 16);
    }
    u32x4* dst = (u32x4*)(Out + (size_t)i * 192);
    #pragma unroll
    for (int j = 0; j < 6; j++) {
        u32x4 v = { pk[4 * j], pk[4 * j + 1], pk[4 * j + 2], pk[4 * j + 3] };
        dst[j] = v;
    }
}

// ---------------------------------------------------------------------------
// Pipelined staged GEMM.
// MODE 2: out f32  [b][192][px], bias + f32 resid    (w2, small-ws)
// MODE 3: qkv: cn==0 -> exp(q) -> qT[gp][192]; cn==1 -> exp(k); cn==2 -> v
// MODE 4: out f32  [b][192][px], bias + bf16 resid   (w2, big-ws)
// ---------------------------------------------------------------------------
template<int MODE, int NCHUNK, int UNITS, int NTILE>
__global__ __launch_bounds__(256) void gemm3_k(
    const unsigned short* __restrict__ X, const unsigned short* __restrict__ Wb,
    const float* __restrict__ bias, const void* __restrict__ resid,
    void* __restrict__ Out, int OCTOT, unsigned short* __restrict__ qT)
{
    constexpr int KTOT = UNITS * 192;
    __shared__ unsigned short tile[2][64 * 192];

    const int tid = threadIdx.x;
    const int wave = tid >> 6, lane = tid & 63;
    const int lr = lane & 15, lg = lane >> 4;
    const int xr = lr & 7;

    auto stage = [&](int s, int buf) {
        const int t = s / UNITS, u = s - t * UNITS;
        const int gp0s = (blockIdx.x * NTILE + t) * 64;
        const unsigned short* Xb = X + (size_t)gp0s * KTOT + u * 192;
        #pragma unroll
        for (int j = 0; j < 6; j++) {
            int ci = (wave * 6 + j) * 64 + lane;
            int row = ci / 24;
            int c = ci - row * 24;
            int csw = (c & ~7) | ((c ^ row) & 7);
            gload_lds16(Xb + (size_t)row * KTOT + csw * 8, &tile[buf][ci * 8]);
        }
    };

    stage(0, 0);

    for (int t = 0; t < NTILE; t++) {
        const int gp0 = (blockIdx.x * NTILE + t) * 64;
        const int b = gp0 >> 16;
        const int pxb = gp0 & 65535;

        if constexpr (UNITS == 1) {
            __syncthreads();
            if (t + 1 < NTILE) stage(t + 1, (t + 1) & 1);
            const unsigned short* tb = tile[t & 1];

            #pragma unroll
            for (int cn = 0; cn < NCHUNK; cn++) {
                const int ocb = cn * 192 + wave * 48;
                const unsigned short* wrow = Wb + (size_t)(ocb + lr) * KTOT + lg * 8;
                const bool swapped = (MODE == 3 && cn == 0);

                s8 wf[3][6];
                #pragma unroll
                for (int ot = 0; ot < 3; ot++)
                    #pragma unroll
                    for (int kk = 0; kk < 6; kk++)
                        wf[ot][kk] = *(const s8*)(wrow + (size_t)ot * 16 * KTOT + kk * 32);

                f4 acc[4][3];
                #pragma unroll
                for (int i = 0; i < 4; i++)
                    #pragma unroll
                    for (int j = 0; j < 3; j++) acc[i][j] = (f4)0.0f;

                #pragma unroll
                for (int kk = 0; kk < 6; kk++) {
                    const int kc = kk * 4 + lg;
                    const int kcs = (kc & ~7) | ((kc ^ xr) & 7);
                    s8 a[4];
                    #pragma unroll
                    for (int pt = 0; pt < 4; pt++)
                        a[pt] = *(const s8*)&tb[((pt * 16 + lr) * 24 + kcs) * 8];
                    #pragma unroll
                    for (int ot = 0; ot < 3; ot++)
                        #pragma unroll
                        for (int pt = 0; pt < 4; pt++)
                            acc[pt][ot] = swapped
                                ? __builtin_amdgcn_mfma_f32_16x16x32_bf16(wf[ot][kk], a[pt], acc[pt][ot], 0, 0, 0)
                                : __builtin_amdgcn_mfma_f32_16x16x32_bf16(a[pt], wf[ot][kk], acc[pt][ot], 0, 0, 0);
                }

                if (MODE == 3 && cn == 0) {
                    #pragma unroll
                    for (int pt = 0; pt < 4; pt++) {
                        const int gp = gp0 + pt * 16 + lr;
                        unsigned short* orow = qT + (size_t)gp * 192 + wave * 48 + lg * 4;
                        #pragma unroll
                        for (int ot = 0; ot < 3; ot++) {
                            f4 bi4 = *(const f4*)&bias[wave * 48 + ot * 16 + lg * 4];
                            us4 o;
                            #pragma unroll
                            for (int r = 0; r < 4; r++) o[r] = f2b(__expf(acc[pt][ot][r] + bi4[r]));
                            *(us4*)(orow + ot * 16) = o;
                        }
                    }
                } else if (MODE == 3) {
                    #pragma unroll
                    for (int ot = 0; ot < 3; ot++) {
                        const int oc = ocb + ot * 16 + lr;
                        const float bi = bias[oc];
                        const size_t rowoff = ((size_t)b * 384 + (oc - 192)) * NPIX + pxb + lg * 4;
                        #pragma unroll
                        for (int pt = 0; pt < 4; pt++) {
                            us4 o;
                            #pragma unroll
                            for (int r = 0; r < 4; r++) {
                                float v = acc[pt][ot][r] + bi;
                                if (cn == 1) v = __expf(v);
                                o[r] = f2b(v);
                            }
                            *(us4*)((unsigned short*)Out + rowoff + pt * 16) = o;
                        }
                    }
                }
            }
        } else {
            // UNITS == 2, NCHUNK == 1 (w2)
            const int ocb = wave * 48;
            const unsigned short* wrow = Wb + (size_t)(ocb + lr) * KTOT + lg * 8;

            f4 acc[4][3];
            #pragma unroll
            for (int i = 0; i < 4; i++)
                #pragma unroll
                for (int j = 0; j < 3; j++) acc[i][j] = (f4)0.0f;

            #pragma unroll
            for (int u = 0; u < 2; u++) {
                const int s = t * 2 + u;
                __syncthreads();
                if (s + 1 < NTILE * 2) stage(s + 1, (s + 1) & 1);
                const unsigned short* tb = tile[s & 1];

                s8 wf[3][6];
                #pragma unroll
                for (int ot = 0; ot < 3; ot++)
                    #pragma unroll
                    for (int kk = 0; kk < 6; kk++)
                        wf[ot][kk] = *(const s8*)(wrow + (size_t)ot * 16 * KTOT + u * 192 + kk * 32);

                #pragma unroll
                for (int kk = 0; kk < 6; kk++) {
                    const int kc = kk * 4 + lg;
                    const int kcs = (kc & ~7) | ((kc ^ xr) & 7);
                    s8 a[4];
                    #pragma unroll
                    for (int pt = 0; pt < 4; pt++)
                        a[pt] = *(const s8*)&tb[((pt * 16 + lr) * 24 + kcs) * 8];
                    #pragma unroll
                    for (int ot = 0; ot < 3; ot++)
                        #pragma unroll
                        for (int pt = 0; pt < 4; pt++)
                            acc[pt][ot] = __builtin_amdgcn_mfma_f32_16x16x32_bf16(a[pt], wf[ot][kk], acc[pt][ot], 0, 0, 0);
                }
            }

            #pragma unroll
            for (int ot = 0; ot < 3; ot++) {
                const int oc = ocb + ot * 16 + lr;
                const float bi = bias[oc];
                const size_t rowoff = ((size_t)b * 192 + oc) * NPIX + pxb + lg * 4;
                #pragma unroll
                for (int pt = 0; pt < 4; pt++) {
                    if (MODE == 2) {
                        f4 rv = *(const f4*)((const float*)resid + rowoff + pt * 16);
                        f4 o;
                        #pragma unroll
                        for (int r = 0; r < 4; r++) o[r] = acc[pt][ot][r] + bi + rv[r];
                        *(f4*)((float*)Out + rowoff + pt * 16) = o;
                    } else {  // MODE 4
                        us4 rv = *(const us4*)((const unsigned short*)resid + rowoff + pt * 16);
                        f4 o;
                        #pragma unroll
                        for (int r = 0; r < 4; r++) o[r] = acc[pt][ot][r] + bi + b2f(rv[r]);
                        *(f4*)((float*)Out + rowoff + pt * 16) = o;
                    }
                }
            }
        }
    }
}

__global__ void zero_k(float* __restrict__ p, int n)
{
    int i = blockIdx.x * 256 + threadIdx.x;
    if (i < n) p[i] = 0.f;
}

__global__ void cvt_k(const float* __restrict__ src, unsigned short* __restrict__ dst, int n)
{
    int i = blockIdx.x * 256 + threadIdx.x;
    if (i < n) dst[i] = f2b(src[i]);
}

// ---------------------------------------------------------------------------
// context (exp-free) + denominator row d=24 via all-ones v fragment.
// ---------------------------------------------------------------------------
__global__ __launch_bounds__(256) void context_k(const unsigned short* __restrict__ kv,
                                                 float* __restrict__ ctxT)
{
    __shared__ float red[4][64][16];
    int bid = blockIdx.x;
    int bh = bid >> 4, cgrp = bid & 15;
    int b = bh >> 3, h = bh & 7;
    int tid = threadIdx.x;
    int wave = tid >> 6, lane = tid & 63, lr = lane & 15, lg = lane >> 4;
    int chunk = cgrp * 4 + wave;
    size_t nbase = (size_t)chunk * 1024 + lg * 8;

    int c0 = h * 24 + lr;
    int c1 = h * 24 + 16 + lr;
    bool val1 = lr < 8;

    const unsigned short* k0p = kv + ((size_t)b * 384 + c0) * NPIX + nbase;
    const unsigned short* k1p = kv + ((size_t)b * 384 + (c1 > 191 ? 191 : c1)) * NPIX + nbase;
    const unsigned short* v0p = kv + ((size_t)b * 384 + 192 + h * 24 + lr) * NPIX + nbase;
    const unsigned short* v1p = kv + ((size_t)b * 384 + 192 + ((h * 24 + 16 + lr > 191) ? 191 : h * 24 + 16 + lr)) * NPIX + nbase;

    const short one_bf = (short)0x3F80;
    s8 ones8 = { one_bf, one_bf, one_bf, one_bf, one_bf, one_bf, one_bf, one_bf };
    s8 zero8 = (s8)0;

    f4 acc[2][2];
    #pragma unroll
    for (int i = 0; i < 2; i++) for (int j = 0; j < 2; j++) acc[i][j] = (f4)0.0f;

    for (int s = 0; s < 32; s++) {
        int off = s * 32;
        s8 p0 = *(const s8*)(k0p + off);
        s8 p1 = *(const s8*)(k1p + off);
        s8 vr0 = *(const s8*)(v0p + off);
        s8 vr1 = *(const s8*)(v1p + off);
        if (!val1) p1 = zero8;
        if (lr == 8) vr1 = ones8;
        acc[0][0] = __builtin_amdgcn_mfma_f32_16x16x32_bf16(p0, vr0, acc[0][0], 0, 0, 0);
        acc[0][1] = __builtin_amdgcn_mfma_f32_16x16x32_bf16(p0, vr1, acc[0][1], 0, 0, 0);
        acc[1][0] = __builtin_amdgcn_mfma_f32_16x16x32_bf16(p1, vr0, acc[1][0], 0, 0, 0);
        acc[1][1] = __builtin_amdgcn_mfma_f32_16x16x32_bf16(p1, vr1, acc[1][1], 0, 0, 0);
    }
    #pragma unroll
    for (int mt = 0; mt < 2; mt++)
        #pragma unroll
        for (int ct = 0; ct < 2; ct++)
            #pragma unroll
            for (int r = 0; r < 4; r++)
                red[wave][lane][mt * 8 + ct * 4 + r] = acc[mt][ct][r];
    __syncthreads();

    if (wave == 0) {
        float* base = ctxT + (size_t)(b * 8 + h) * 1024;
        #pragma unroll
        for (int j = 0; j < 16; j++) {
            float sum = red[0][lane][j] + red[1][lane][j] + red[2][lane][j] + red[3][lane][j];
            int mt = j >> 3, ct = (j >> 2) & 1, r = j & 3;
            int c = mt * 16 + lg * 4 + r;
            int d = ct * 16 + lr;
            atomicAdd(base + d * 32 + c, sum);
        }
    }
}

// ---------------------------------------------------------------------------
// normalize ctx rows 0..23 by denominator; emit bf16 copy ctxb[bh][32][32]
// ---------------------------------------------------------------------------
__global__ void ctxnorm_k(float* __restrict__ ctxT, unsigned short* __restrict__ ctxb)
{
    int i = blockIdx.x * 256 + threadIdx.x;
    if (i >= 1024) return;
    int bh = i >> 5, c = i & 31;
    float* base = ctxT + (size_t)bh * 1024;
    unsigned short* bb = ctxb + (size_t)bh * 1024;
    float den = base[24 * 32 + c];
    float r = den > 0.f ? 1.0f / den : 0.0f;
    #pragma unroll
    for (int d = 0; d < 24; d++) {
        float v = base[d * 32 + c] * r;
        bb[d * 32 + c] = f2b(v);
    }
    #pragma unroll
    for (int d = 24; d < 32; d++) bb[d * 32 + c] = 0;
}

// ---------------------------------------------------------------------------
// fused qctx+w1 (gelu_t in w1 epilogue, fast rcp for softmax denominator)
// ---------------------------------------------------------------------------
template<bool BIGWS>
__global__ __launch_bounds__(256) void qctx_proj_k(
    const unsigned short* __restrict__ qT, const unsigned short* __restrict__ ctxb,
    const unsigned short* __restrict__ outWb, const float* __restrict__ outBias,
    const float* __restrict__ xres, float* __restrict__ Out,
    unsigned short* __restrict__ x2b,
    const float* __restrict__ ln2g, const float* __restrict__ ln2b,
    const unsigned short* __restrict__ w1b, const float* __restrict__ b1,
    unsigned short* __restrict__ h1t)
{
    __shared__ unsigned short outp[64][200];
    __shared__ float lnS[4][64], lnQ[4][64];

    int tid = threadIdx.x, bid = blockIdx.x;
    int b = bid >> 10, n0 = (bid & 1023) * 64;
    int wave = tid >> 6, lane = tid & 63, lr = lane & 15, lg = lane >> 4;
    const size_t bpx = (size_t)b << 16;

    #pragma unroll
    for (int hh = 0; hh < 2; hh++) {
        int h = wave * 2 + hh;
        const unsigned short* cb = ctxb + (size_t)(b * 8 + h) * 1024;
        s8 cf[2];
        #pragma unroll
        for (int mt = 0; mt < 2; mt++)
            cf[mt] = *(const s8*)(cb + (mt * 16 + lr) * 32 + lg * 8);
        #pragma unroll
        for (int nt = 0; nt < 4; nt++) {
            int n = nt * 16 + lr;
            s8 bfq = (s8)0;
            float sown = 0.f;
            if (lg < 3) {
                bfq = *(const s8*)(qT + (bpx + n0 + n) * 192 + h * 24 + lg * 8);
                #pragma unroll
                for (int j = 0; j < 8; j++) sown += b2f((unsigned short)bfq[j]);
            }
            float den = sown;
            den += __shfl_xor(den, 16);
            den += __shfl_xor(den, 32);
            f4 z = (f4)0.0f;
            f4 d0 = __builtin_amdgcn_mfma_f32_16x16x32_bf16(cf[0], bfq, z, 0, 0, 0);
            f4 d1 = __builtin_amdgcn_mfma_f32_16x16x32_bf16(cf[1], bfq, z, 0, 0, 0);
            float sinv = __builtin_amdgcn_rcpf(den);
            us4 w0;
            #pragma unroll
            for (int r = 0; r < 4; r++) w0[r] = f2b(d0[r] * sinv);
            *(us4*)&outp[n][h * 24 + lg * 4] = w0;
            if (lg < 2) {
                us4 w1;
                #pragma unroll
                for (int r = 0; r < 4; r++) w1[r] = f2b(d1[r] * sinv);
                *(us4*)&outp[n][h * 24 + 16 + lg * 4] = w1;
            }
        }
    }
    __syncthreads();

    f4 acc[4][3];
    #pragma unroll
    for (int i = 0; i < 4; i++) for (int j = 0; j < 3; j++) acc[i][j] = (f4)0.0f;
    #pragma unroll
    for (int k0 = 0; k0 < 192; k0 += 32) {
        s8 bf[4];
        #pragma unroll
        for (int pt = 0; pt < 4; pt++)
            bf[pt] = *(const s8*)&outp[pt * 16 + lr][k0 + lg * 8];
        #pragma unroll
        for (int ot = 0; ot < 3; ot++) {
            s8 af = *(const s8*)&outWb[(size_t)(wave * 48 + ot * 16 + lr) * 192 + k0 + lg * 8];
            #pragma unroll
            for (int pt = 0; pt < 4; pt++)
                acc[pt][ot] = __builtin_amdgcn_mfma_f32_16x16x32_bf16(bf[pt], af, acc[pt][ot], 0, 0, 0);
        }
    }

    float sP[4][4], qP[4][4];
    #pragma unroll
    for (int pt = 0; pt < 4; pt++)
        #pragma unroll
        for (int r = 0; r < 4; r++) { sP[pt][r] = 0.f; qP[pt][r] = 0.f; }

    #pragma unroll
    for (int ot = 0; ot < 3; ot++) {
        const int oc = wave * 48 + ot * 16 + lr;
        const float bi = outBias[oc];
        const size_t rowbase = ((size_t)b * 192 + oc) * NPIX + n0 + lg * 4;
        #pragma unroll
        for (int pt = 0; pt < 4; pt++) {
            f4 rv = *(const f4*)(xres + rowbase + pt * 16);
            f4 v;
            #pragma unroll
            for (int r = 0; r < 4; r++) {
                v[r] = acc[pt][ot][r] + bi + rv[r];
                sP[pt][r] += v[r]; qP[pt][r] += v[r] * v[r];
            }
            acc[pt][ot] = v;
            if (BIGWS) {
                us4 o;
                #pragma unroll
                for (int r = 0; r < 4; r++) o[r] = f2b(v[r]);
                *(us4*)(x2b + rowbase + pt * 16) = o;
            } else {
                *(f4*)(Out + rowbase + pt * 16) = v;
            }
        }
    }
    #pragma unroll
    for (int pt = 0; pt < 4; pt++)
        #pragma unroll
        for (int r = 0; r < 4; r++) {
            float s = sP[pt][r], q = qP[pt][r];
            s += __shfl_xor(s, 1); s += __shfl_xor(s, 2);
            s += __shfl_xor(s, 4); s += __shfl_xor(s, 8);
            q += __shfl_xor(q, 1); q += __shfl_xor(q, 2);
            q += __shfl_xor(q, 4); q += __shfl_xor(q, 8);
            sP[pt][r] = s; qP[pt][r] = q;
        }
    if (lr == 0) {
        #pragma unroll
        for (int pt = 0; pt < 4; pt++)
            #pragma unroll
            for (int r = 0; r < 4; r++) {
                lnS[wave][pt * 16 + lg * 4 + r] = sP[pt][r];
                lnQ[wave][pt * 16 + lg * 4 + r] = qP[pt][r];
            }
    }
    __syncthreads();

    // LN2 apply -> xn into outp
    float lgv[3], lbv[3];
    #pragma unroll
    for (int ot = 0; ot < 3; ot++) {
        int oc = wave * 48 + ot * 16 + lr;
        lgv[ot] = ln2g[oc]; lbv[ot] = ln2b[oc];
    }
    #pragma unroll
    for (int pt = 0; pt < 4; pt++) {
        float mu4[4], rs4[4];
        #pragma unroll
        for (int r = 0; r < 4; r++) {
            int px = pt * 16 + lg * 4 + r;
            float S = lnS[0][px] + lnS[1][px] + lnS[2][px] + lnS[3][px];
            float Qq = lnQ[0][px] + lnQ[1][px] + lnQ[2][px] + lnQ[3][px];
            float mu = S * (1.0f / 192.0f);
            float var = Qq * (1.0f / 192.0f) - mu * mu;
            mu4[r] = mu; rs4[r] = rsqrtf(var + 1e-5f);
        }
        #pragma unroll
        for (int ot = 0; ot < 3; ot++) {
            int oc = wave * 48 + ot * 16 + lr;
            #pragma unroll
            for (int r = 0; r < 4; r++) {
                int px = pt * 16 + lg * 4 + r;
                float xn = (acc[pt][ot][r] - mu4[r]) * rs4[r] * lgv[ot] + lbv[ot];
                outp[px][oc] = f2b(xn);
            }
        }
    }
    __syncthreads();

    // w1 GEMM in place -> h1t[px][384] + gelu_t
    #pragma unroll
    for (int cn = 0; cn < 2; cn++) {
        const int ocb = cn * 192 + wave * 48;
        const unsigned short* wrow = w1b + (size_t)(ocb + lr) * 192 + lg * 8;

        s8 wf[3][6];
        #pragma unroll
        for (int ot = 0; ot < 3; ot++)
            #pragma unroll
            for (int kk = 0; kk < 6; kk++)
                wf[ot][kk] = *(const s8*)(wrow + (size_t)ot * 16 * 192 + kk * 32);

        f4 acc2[4][3];
        #pragma unroll
        for (int i = 0; i < 4; i++)
            #pragma unroll
            for (int j = 0; j < 3; j++) acc2[i][j] = (f4)0.0f;

        #pragma unroll
        for (int kk = 0; kk < 6; kk++) {
            s8 bf[4];
            #pragma unroll
            for (int pt = 0; pt < 4; pt++)
                bf[pt] = *(const s8*)&outp[pt * 16 + lr][kk * 32 + lg * 8];
            #pragma unroll
            for (int ot = 0; ot < 3; ot++)
                #pragma unroll
                for (int pt = 0; pt < 4; pt++)
                    acc2[pt][ot] = __builtin_amdgcn_mfma_f32_16x16x32_bf16(wf[ot][kk], bf[pt], acc2[pt][ot], 0, 0, 0);
        }

        #pragma unroll
        for (int pt = 0; pt < 4; pt++) {
            const int gp = n0 + pt * 16 + lr;
            unsigned short* orow = h1t + (bpx + gp) * 384 + ocb + lg * 4;
            #pragma unroll
            for (int ot = 0; ot < 3; ot++) {
                f4 bi4 = *(const f4*)&b1[ocb + ot * 16 + lg * 4];
                us4 o;
                #pragma unroll
                for (int r = 0; r < 4; r++) o[r] = f2b(gelu_t(acc2[pt][ot][r] + bi4[r]));
                *(us4*)(orow + ot * 16) = o;
            }
        }
    }
}

// ---------------------------------------------------------------------------
// depthwise 3x3 + gelu on [px][384], row-streamed LDS ring; 16 rows/block.
// ---------------------------------------------------------------------------
__global__ __launch_bounds__(256) void dwconv_t2_k(
    const unsigned short* __restrict__ h1t, const float* __restrict__ w,
    const float* __restrict__ bias, unsigned short* __restrict__ h2t)
{
    __shared__ unsigned short ring[4 * 4 * 66 * 8];
    const int bz = blockIdx.z;
    const int b = bz / 12, cb = (bz % 12) * 32;
    const int y0 = blockIdx.y * 16, x0 = blockIdx.x * 64;
    const int tid = threadIdx.x;
    const int x = tid & 63, cg = tid >> 6;
    const int c0 = cb + cg * 8;
    const size_t bbase = (size_t)b << 16;

    float wr[9][8], bi[8];
    #pragma unroll
    for (int i = 0; i < 8; i++) {
        #pragma unroll
        for (int j = 0; j < 9; j++) wr[j][i] = rfl(w[(c0 + i) * 9 + j]);
        bi[i] = rfl(bias[c0 + i]);
    }

    const us8 zz = {0, 0, 0, 0, 0, 0, 0, 0};

    auto stage_row = [&](int gy, int s) {
        unsigned short* ldsrow = &ring[((s * 4 + cg) * 66) * 8];
        if (gy >= 0 && gy <= 255) {
            us8 ev = zz;
            if (x == 0 && x0 > 0)
                ev = *(const us8*)(h1t + (bbase + gy * 256 + x0 - 1) * 384 + c0);
            if (x == 63 && x0 + 64 < 256)
                ev = *(const us8*)(h1t + (bbase + gy * 256 + x0 + 64) * 384 + c0);
            gload_lds16(h1t + (bbase + gy * 256 + x0 + x) * 384 + c0,
                        ldsrow + (1 + x) * 8);
            if (x == 0)  *(us8*)&ldsrow[0]      = ev;
            if (x == 63) *(us8*)&ldsrow[65 * 8] = ev;
        } else {
            *(us8*)&ldsrow[(1 + x) * 8] = zz;
            if (x == 0)  *(us8*)&ldsrow[0]      = zz;
            if (x == 63) *(us8*)&ldsrow[65 * 8] = zz;
        }
    };

    stage_row(y0 - 1, 0);
    stage_row(y0,     1);
    stage_row(y0 + 1, 2);
    __syncthreads();

    #pragma unroll
    for (int y = 0; y < 16; y++) {
        if (y < 15) stage_row(y0 + y + 2, (y + 3) & 3);

        float a[8];
        #pragma unroll
        for (int i = 0; i < 8; i++) a[i] = bi[i];
        #pragma unroll
        for (int t = 0; t < 3; t++) {
            const int s = (y + t) & 3;
            const unsigned short* rp = &ring[((s * 4 + cg) * 66 + x) * 8];
            us8 L = *(const us8*)(rp);
            us8 C = *(const us8*)(rp + 8);
            us8 R = *(const us8*)(rp + 16);
            #pragma unroll
            for (int i = 0; i < 8; i++) {
                a[i] += wr[t * 3 + 0][i] * b2f(L[i]);
                a[i] += wr[t * 3 + 1][i] * b2f(C[i]);
                a[i] += wr[t * 3 + 2][i] * b2f(R[i]);
            }
        }
        us8 ov;
        #pragma unroll
        for (int i = 0; i < 8; i++) ov[i] = f2b(gelu_t(a[i]));
        *(us8*)(h2t + (bbase + (y0 + y) * 256 + x0 + x) * 384 + c0) = ov;

        __syncthreads();
    }
}

// ---------------------------------------------------------------------------
extern "C" void kernel_launch(void* const* d_in, const int* in_sizes, int n_in,
                              void* d_out, int out_size, void* d_ws, size_t ws_size,
                              hipStream_t stream)
{
    const float* x    = (const float*)d_in[0];
    const float* ln1g = (const float*)d_in[1];
    const float* ln1b = (const float*)d_in[2];
    const float* qkvw = (const float*)d_in[3];
    const float* qkvb = (const float*)d_in[4];
    const float* outw = (const float*)d_in[5];
    const float* outb = (const float*)d_in[6];
    const float* ln2g = (const float*)d_in[7];
    const float* ln2b = (const float*)d_in[8];
    const float* w1   = (const float*)d_in[9];
    const float* b1   = (const float*)d_in[10];
    const float* dww  = (const float*)d_in[11];
    const float* dwb  = (const float*)d_in[12];
    const float* w2   = (const float*)d_in[13];
    const float* b2   = (const float*)d_in[14];
    float* out = (float*)d_out;

    char* ws = (char*)d_ws;
    unsigned short* kv  = (unsigned short*)ws;
    unsigned short* h1t = (unsigned short*)ws;
    unsigned short* h2t = (unsigned short*)(ws + (size_t)201326592);
    unsigned short* qT  = (unsigned short*)(ws + (size_t)201326592);
    unsigned short* xnt = (unsigned short*)(ws + (size_t)301989888);
    size_t off = (size_t)402653184;
    float* koff = (float*)(ws + off); off += 4096;
    float* ctxT = (float*)(ws + off); off += 131072;
    unsigned short* ctxb = (unsigned short*)(ws + off); off += 65536;
    unsigned short* qkvwb = (unsigned short*)(ws + off); off += 221184;
    unsigned short* outwb = (unsigned short*)(ws + off); off += 73728 * 2;
    unsigned short* w1b   = (unsigned short*)(ws + off); off += 147456;
    unsigned short* w2b   = (unsigned short*)(ws + off); off += 147456;
    off = (off + 255) & ~(size_t)255;
    unsigned short* x2b = (unsigned short*)(ws + off);
    const bool bigws = ws_size >= off + (size_t)100663296;
    (void)koff;

    cvt_k<<<(110592 + 255) / 256, 256, 0, stream>>>(qkvw, qkvwb, 110592);
    cvt_k<<<(36864 + 255) / 256, 256, 0, stream>>>(outw, outwb, 36864);
    cvt_k<<<(73728 + 255) / 256, 256, 0, stream>>>(w1, w1b, 73728);
    cvt_k<<<(73728 + 255) / 256, 256, 0, stream>>>(w2, w2b, 73728);

    // 1) LN1 + transpose -> xnt
    lnt_k<<<1024, 256, 0, stream>>>(x, ln1g, ln1b, xnt);

    // 2) qkv GEMM: exp(q) -> qT, exp(k)/v -> kv
    gemm3_k<3, 3, 1, 4><<<1024, 256, 0, stream>>>(xnt, qkvwb, qkvb, nullptr, kv, 384, qT);

    // 3) context accumulation + denominator
    zero_k<<<128, 256, 0, stream>>>(ctxT, 32768);
    context_k<<<512, 256, 0, stream>>>(kv, ctxT);

    // 4) normalize ctx -> bf16 copy ctxb
    ctxnorm_k<<<4, 256, 0, stream>>>(ctxT, ctxb);

    // 5) qctx fused (+LN2 +w1+gelu_t -> h1t)
    if (bigws)
        qctx_proj_k<true><<<4096, 256, 0, stream>>>(qT, ctxb, outwb, outb, x, out,
                                                    x2b, ln2g, ln2b, w1b, b1, h1t);
    else
        qctx_proj_k<false><<<4096, 256, 0, stream>>>(qT, ctxb, outwb, outb, x, out,
                                                     x2b, ln2g, ln2b, w1b, b1, h1t);

    // 6) depthwise 3x3 + gelu -> h2t
    dwconv_t2_k<<<dim3(4, 16, 48), 256, 0, stream>>>(h1t, dww, dwb, h2t);

    // 7) w2 GEMM + bias + x2 residual -> d_out f32
    if (bigws)
        gemm3_k<4, 1, 2, 4><<<1024, 256, 0, stream>>>(h2t, w2b, b2, x2b, out, 192, nullptr);
    else
        gemm3_k<2, 1, 2, 4><<<1024, 256, 0, stream>>>(h2t, w2b, b2, out, out, 192, nullptr);
}

// Round 20
// 838.454 us; speedup vs baseline: 1.0776x; 1.0006x over previous
//
#include <hip/hip_runtime.h>
#include <hip/hip_bf16.h>
#include <math.h>

typedef __attribute__((ext_vector_type(8))) short s8;
typedef __attribute__((ext_vector_type(8))) unsigned short us8;
typedef __attribute__((ext_vector_type(4))) float f4;
typedef __attribute__((ext_vector_type(4))) unsigned short us4;
typedef __attribute__((ext_vector_type(4))) unsigned int u32x4;

#define DEVI __device__ __forceinline__

static const int NPIX = 65536;   // 256*256

DEVI float b2f(unsigned short u) {
    unsigned int v = ((unsigned int)u) << 16;
    float f; __builtin_memcpy(&f, &v, 4); return f;
}
// native conversion -> compiler can pack pairs into v_cvt_pk_bf16_f32
DEVI unsigned short f2b(float f) {
    __hip_bfloat16 h = __float2bfloat16(f);
    unsigned short r; __builtin_memcpy(&r, &h, 2); return r;
}
DEVI float geluf(float x) { return 0.5f * x * (1.0f + erff(x * 0.70710678118f)); }
DEVI float gelu_t(float x) {
    float z = 1.595769122f * (x + 0.044715f * x * x * x);
    return x * __builtin_amdgcn_rcpf(1.0f + __expf(-z));
}
DEVI float rfl(float v) {
    int i; __builtin_memcpy(&i, &v, 4);
    i = __builtin_amdgcn_readfirstlane(i);
    float o; __builtin_memcpy(&o, &i, 4); return o;
}

DEVI void gload_lds16(const unsigned short* g, unsigned short* l) {
    __builtin_amdgcn_global_load_lds(
        (const __attribute__((address_space(1))) unsigned int*)g,
        (__attribute__((address_space(3))) unsigned int*)l,
        16, 0, 0);
}

// ---------------------------------------------------------------------------
// LayerNorm + transpose: x f32 [b][192][px] -> xnt bf16 [b*px][192]
// ---------------------------------------------------------------------------
__global__ __launch_bounds__(256) void lnt_k(const float* __restrict__ X,
                                             const float* __restrict__ gw,
                                             const float* __restrict__ gb,
                                             unsigned short* __restrict__ Out)
{
    const int i = blockIdx.x * 256 + threadIdx.x;
    const int b = i >> 16, px = i & 65535;
    const float* xp = X + (size_t)b * 192 * NPIX + px;

    unsigned int pk[96];
    float sum = 0.f, ssq = 0.f;
    #pragma unroll
    for (int c = 0; c < 192; c++) {
        float v = xp[(size_t)c * NPIX];
        sum += v; ssq += v * v;
        unsigned int h = f2b(v);
        if (c & 1) pk[c >> 1] |= h << 16;
        else       pk[c >> 1] = h;
    }
    float mu = sum * (1.0f / 192.0f);
    float var = ssq * (1.0f / 192.0f) - mu * mu;
    float rs = rsqrtf(var + 1e-5f);

    #pragma unroll
    for (int c2 = 0; c2 < 96; c2++) {
        int c = c2 * 2;
        float lo = b2f((unsigned short)(pk[c2] & 0xFFFF));
        float hi = b2f((unsigned short)(pk[c2] >> 16));
        lo = (lo - mu) * rs * gw[c] + gb[c];
        hi = (hi - mu) * rs * gw[c + 1] + gb[c + 1];
        pk[c2] = (unsigned int)f2b(lo) | ((unsigned int)f2b(hi) << 16);
    }
    u32x4* dst = (u32x4*)(Out + (size_t)i * 192);
    #pragma unroll
    for (int j = 0; j < 6; j++) {
        u32x4 v = { pk[4 * j], pk[4 * j + 1], pk[4 * j + 2], pk[4 * j + 3] };
        dst[j] = v;
    }
}

// ---------------------------------------------------------------------------
// Pipelined staged GEMM.
// MODE 2: out f32  [b][192][px], bias + f32 resid    (w2, small-ws)
// MODE 3: qkv: cn==0 -> exp(q) -> qT[gp][192]; cn==1 -> exp(k); cn==2 -> v
// MODE 4: out f32  [b][192][px], bias + bf16 resid   (w2, big-ws)
// ---------------------------------------------------------------------------
template<int MODE, int NCHUNK, int UNITS, int NTILE>
__global__ __launch_bounds__(256) void gemm3_k(
    const unsigned short* __restrict__ X, const unsigned short* __restrict__ Wb,
    const float* __restrict__ bias, const void* __restrict__ resid,
    void* __restrict__ Out, int OCTOT, unsigned short* __restrict__ qT)
{
    constexpr int KTOT = UNITS * 192;
    __shared__ unsigned short tile[2][64 * 192];

    const int tid = threadIdx.x;
    const int wave = tid >> 6, lane = tid & 63;
    const int lr = lane & 15, lg = lane >> 4;
    const int xr = lr & 7;

    auto stage = [&](int s, int buf) {
        const int t = s / UNITS, u = s - t * UNITS;
        const int gp0s = (blockIdx.x * NTILE + t) * 64;
        const unsigned short* Xb = X + (size_t)gp0s * KTOT + u * 192;
        #pragma unroll
        for (int j = 0; j < 6; j++) {
            int ci = (wave * 6 + j) * 64 + lane;
            int row = ci / 24;
            int c = ci - row * 24;
            int csw = (c & ~7) | ((c ^ row) & 7);
            gload_lds16(Xb + (size_t)row * KTOT + csw * 8, &tile[buf][ci * 8]);
        }
    };

    stage(0, 0);

    for (int t = 0; t < NTILE; t++) {
        const int gp0 = (blockIdx.x * NTILE + t) * 64;
        const int b = gp0 >> 16;
        const int pxb = gp0 & 65535;

        if constexpr (UNITS == 1) {
            __syncthreads();
            if (t + 1 < NTILE) stage(t + 1, (t + 1) & 1);
            const unsigned short* tb = tile[t & 1];

            #pragma unroll
            for (int cn = 0; cn < NCHUNK; cn++) {
                const int ocb = cn * 192 + wave * 48;
                const unsigned short* wrow = Wb + (size_t)(ocb + lr) * KTOT + lg * 8;
                const bool swapped = (MODE == 3 && cn == 0);

                s8 wf[3][6];
                #pragma unroll
                for (int ot = 0; ot < 3; ot++)
                    #pragma unroll
                    for (int kk = 0; kk < 6; kk++)
                        wf[ot][kk] = *(const s8*)(wrow + (size_t)ot * 16 * KTOT + kk * 32);

                f4 acc[4][3];
                #pragma unroll
                for (int i = 0; i < 4; i++)
                    #pragma unroll
                    for (int j = 0; j < 3; j++) acc[i][j] = (f4)0.0f;

                #pragma unroll
                for (int kk = 0; kk < 6; kk++) {
                    const int kc = kk * 4 + lg;
                    const int kcs = (kc & ~7) | ((kc ^ xr) & 7);
                    s8 a[4];
                    #pragma unroll
                    for (int pt = 0; pt < 4; pt++)
                        a[pt] = *(const s8*)&tb[((pt * 16 + lr) * 24 + kcs) * 8];
                    #pragma unroll
                    for (int ot = 0; ot < 3; ot++)
                        #pragma unroll
                        for (int pt = 0; pt < 4; pt++)
                            acc[pt][ot] = swapped
                                ? __builtin_amdgcn_mfma_f32_16x16x32_bf16(wf[ot][kk], a[pt], acc[pt][ot], 0, 0, 0)
                                : __builtin_amdgcn_mfma_f32_16x16x32_bf16(a[pt], wf[ot][kk], acc[pt][ot], 0, 0, 0);
                }

                if (MODE == 3 && cn == 0) {
                    #pragma unroll
                    for (int pt = 0; pt < 4; pt++) {
                        const int gp = gp0 + pt * 16 + lr;
                        unsigned short* orow = qT + (size_t)gp * 192 + wave * 48 + lg * 4;
                        #pragma unroll
                        for (int ot = 0; ot < 3; ot++) {
                            f4 bi4 = *(const f4*)&bias[wave * 48 + ot * 16 + lg * 4];
                            us4 o;
                            #pragma unroll
                            for (int r = 0; r < 4; r++) o[r] = f2b(__expf(acc[pt][ot][r] + bi4[r]));
                            *(us4*)(orow + ot * 16) = o;
                        }
                    }
                } else if (MODE == 3) {
                    #pragma unroll
                    for (int ot = 0; ot < 3; ot++) {
                        const int oc = ocb + ot * 16 + lr;
                        const float bi = bias[oc];
                        const size_t rowoff = ((size_t)b * 384 + (oc - 192)) * NPIX + pxb + lg * 4;
                        #pragma unroll
                        for (int pt = 0; pt < 4; pt++) {
                            us4 o;
                            #pragma unroll
                            for (int r = 0; r < 4; r++) {
                                float v = acc[pt][ot][r] + bi;
                                if (cn == 1) v = __expf(v);
                                o[r] = f2b(v);
                            }
                            *(us4*)((unsigned short*)Out + rowoff + pt * 16) = o;
                        }
                    }
                }
            }
        } else {
            // UNITS == 2, NCHUNK == 1 (w2)
            const int ocb = wave * 48;
            const unsigned short* wrow = Wb + (size_t)(ocb + lr) * KTOT + lg * 8;

            f4 acc[4][3];
            #pragma unroll
            for (int i = 0; i < 4; i++)
                #pragma unroll
                for (int j = 0; j < 3; j++) acc[i][j] = (f4)0.0f;

            #pragma unroll
            for (int u = 0; u < 2; u++) {
                const int s = t * 2 + u;
                __syncthreads();
                if (s + 1 < NTILE * 2) stage(s + 1, (s + 1) & 1);
                const unsigned short* tb = tile[s & 1];

                s8 wf[3][6];
                #pragma unroll
                for (int ot = 0; ot < 3; ot++)
                    #pragma unroll
                    for (int kk = 0; kk < 6; kk++)
                        wf[ot][kk] = *(const s8*)(wrow + (size_t)ot * 16 * KTOT + u * 192 + kk * 32);

                #pragma unroll
                for (int kk = 0; kk < 6; kk++) {
                    const int kc = kk * 4 + lg;
                    const int kcs = (kc & ~7) | ((kc ^ xr) & 7);
                    s8 a[4];
                    #pragma unroll
                    for (int pt = 0; pt < 4; pt++)
                        a[pt] = *(const s8*)&tb[((pt * 16 + lr) * 24 + kcs) * 8];
                    #pragma unroll
                    for (int ot = 0; ot < 3; ot++)
                        #pragma unroll
                        for (int pt = 0; pt < 4; pt++)
                            acc[pt][ot] = __builtin_amdgcn_mfma_f32_16x16x32_bf16(a[pt], wf[ot][kk], acc[pt][ot], 0, 0, 0);
                }
            }

            #pragma unroll
            for (int ot = 0; ot < 3; ot++) {
                const int oc = ocb + ot * 16 + lr;
                const float bi = bias[oc];
                const size_t rowoff = ((size_t)b * 192 + oc) * NPIX + pxb + lg * 4;
                #pragma unroll
                for (int pt = 0; pt < 4; pt++) {
                    if (MODE == 2) {
                        f4 rv = *(const f4*)((const float*)resid + rowoff + pt * 16);
                        f4 o;
                        #pragma unroll
                        for (int r = 0; r < 4; r++) o[r] = acc[pt][ot][r] + bi + rv[r];
                        *(f4*)((float*)Out + rowoff + pt * 16) = o;
                    } else {  // MODE 4
                        us4 rv = *(const us4*)((const unsigned short*)resid + rowoff + pt * 16);
                        f4 o;
                        #pragma unroll
                        for (int r = 0; r < 4; r++) o[r] = acc[pt][ot][r] + bi + b2f(rv[r]);
                        *(f4*)((float*)Out + rowoff + pt * 16) = o;
                    }
                }
            }
        }
    }
}

__global__ void zero_k(float* __restrict__ p, int n)
{
    int i = blockIdx.x * 256 + threadIdx.x;
    if (i < n) p[i] = 0.f;
}

__global__ void cvt_k(const float* __restrict__ src, unsigned short* __restrict__ dst, int n)
{
    int i = blockIdx.x * 256 + threadIdx.x;
    if (i < n) dst[i] = f2b(src[i]);
}

// ---------------------------------------------------------------------------
// context (exp-free) + denominator row d=24 via all-ones v fragment.
// ---------------------------------------------------------------------------
__global__ __launch_bounds__(256) void context_k(const unsigned short* __restrict__ kv,
                                                 float* __restrict__ ctxT)
{
    __shared__ float red[4][64][16];
    int bid = blockIdx.x;
    int bh = bid >> 4, cgrp = bid & 15;
    int b = bh >> 3, h = bh & 7;
    int tid = threadIdx.x;
    int wave = tid >> 6, lane = tid & 63, lr = lane & 15, lg = lane >> 4;
    int chunk = cgrp * 4 + wave;
    size_t nbase = (size_t)chunk * 1024 + lg * 8;

    int c0 = h * 24 + lr;
    int c1 = h * 24 + 16 + lr;
    bool val1 = lr < 8;

    const unsigned short* k0p = kv + ((size_t)b * 384 + c0) * NPIX + nbase;
    const unsigned short* k1p = kv + ((size_t)b * 384 + (c1 > 191 ? 191 : c1)) * NPIX + nbase;
    const unsigned short* v0p = kv + ((size_t)b * 384 + 192 + h * 24 + lr) * NPIX + nbase;
    const unsigned short* v1p = kv + ((size_t)b * 384 + 192 + ((h * 24 + 16 + lr > 191) ? 191 : h * 24 + 16 + lr)) * NPIX + nbase;

    const short one_bf = (short)0x3F80;
    s8 ones8 = { one_bf, one_bf, one_bf, one_bf, one_bf, one_bf, one_bf, one_bf };
    s8 zero8 = (s8)0;

    f4 acc[2][2];
    #pragma unroll
    for (int i = 0; i < 2; i++) for (int j = 0; j < 2; j++) acc[i][j] = (f4)0.0f;

    for (int s = 0; s < 32; s++) {
        int off = s * 32;
        s8 p0 = *(const s8*)(k0p + off);
        s8 p1 = *(const s8*)(k1p + off);
        s8 vr0 = *(const s8*)(v0p + off);
        s8 vr1 = *(const s8*)(v1p + off);
        if (!val1) p1 = zero8;
        if (lr == 8) vr1 = ones8;
        acc[0][0] = __builtin_amdgcn_mfma_f32_16x16x32_bf16(p0, vr0, acc[0][0], 0, 0, 0);
        acc[0][1] = __builtin_amdgcn_mfma_f32_16x16x32_bf16(p0, vr1, acc[0][1], 0, 0, 0);
        acc[1][0] = __builtin_amdgcn_mfma_f32_16x16x32_bf16(p1, vr0, acc[1][0], 0, 0, 0);
        acc[1][1] = __builtin_amdgcn_mfma_f32_16x16x32_bf16(p1, vr1, acc[1][1], 0, 0, 0);
    }
    #pragma unroll
    for (int mt = 0; mt < 2; mt++)
        #pragma unroll
        for (int ct = 0; ct < 2; ct++)
            #pragma unroll
            for (int r = 0; r < 4; r++)
                red[wave][lane][mt * 8 + ct * 4 + r] = acc[mt][ct][r];
    __syncthreads();

    if (wave == 0) {
        float* base = ctxT + (size_t)(b * 8 + h) * 1024;
        #pragma unroll
        for (int j = 0; j < 16; j++) {
            float sum = red[0][lane][j] + red[1][lane][j] + red[2][lane][j] + red[3][lane][j];
            int mt = j >> 3, ct = (j >> 2) & 1, r = j & 3;
            int c = mt * 16 + lg * 4 + r;
            int d = ct * 16 + lr;
            atomicAdd(base + d * 32 + c, sum);
        }
    }
}

// ---------------------------------------------------------------------------
// normalize ctx rows 0..23 by denominator; emit bf16 copy ctxb[bh][32][32]
// ---------------------------------------------------------------------------
__global__ void ctxnorm_k(float* __restrict__ ctxT, unsigned short* __restrict__ ctxb)
{
    int i = blockIdx.x * 256 + threadIdx.x;
    if (i >= 1024) return;
    int bh = i >> 5, c = i & 31;
    float* base = ctxT + (size_t)bh * 1024;
    unsigned short* bb = ctxb + (size_t)bh * 1024;
    float den = base[24 * 32 + c];
    float r = den > 0.f ? 1.0f / den : 0.0f;
    #pragma unroll
    for (int d = 0; d < 24; d++) {
        float v = base[d * 32 + c] * r;
        bb[d * 32 + c] = f2b(v);
    }
    #pragma unroll
    for (int d = 24; d < 32; d++) bb[d * 32 + c] = 0;
}

// ---------------------------------------------------------------------------
// fused qctx+w1
// ---------------------------------------------------------------------------
template<bool BIGWS>
__global__ __launch_bounds__(256) void qctx_proj_k(
    const unsigned short* __restrict__ qT, const unsigned short* __restrict__ ctxb,
    const unsigned short* __restrict__ outWb, const float* __restrict__ outBias,
    const float* __restrict__ xres, float* __restrict__ Out,
    unsigned short* __restrict__ x2b,
    const float* __restrict__ ln2g, const float* __restrict__ ln2b,
    const unsigned short* __restrict__ w1b, const float* __restrict__ b1,
    unsigned short* __restrict__ h1t)
{
    __shared__ unsigned short outp[64][200];
    __shared__ float lnS[4][64], lnQ[4][64];

    int tid = threadIdx.x, bid = blockIdx.x;
    int b = bid >> 10, n0 = (bid & 1023) * 64;
    int wave = tid >> 6, lane = tid & 63, lr = lane & 15, lg = lane >> 4;
    const size_t bpx = (size_t)b << 16;

    #pragma unroll
    for (int hh = 0; hh < 2; hh++) {
        int h = wave * 2 + hh;
        const unsigned short* cb = ctxb + (size_t)(b * 8 + h) * 1024;
        s8 cf[2];
        #pragma unroll
        for (int mt = 0; mt < 2; mt++)
            cf[mt] = *(const s8*)(cb + (mt * 16 + lr) * 32 + lg * 8);
        #pragma unroll
        for (int nt = 0; nt < 4; nt++) {
            int n = nt * 16 + lr;
            s8 bfq = (s8)0;
            float sown = 0.f;
            if (lg < 3) {
                bfq = *(const s8*)(qT + (bpx + n0 + n) * 192 + h * 24 + lg * 8);
                #pragma unroll
                for (int j = 0; j < 8; j++) sown += b2f((unsigned short)bfq[j]);
            }
            float den = sown;
            den += __shfl_xor(den, 16);
            den += __shfl_xor(den, 32);
            f4 z = (f4)0.0f;
            f4 d0 = __builtin_amdgcn_mfma_f32_16x16x32_bf16(cf[0], bfq, z, 0, 0, 0);
            f4 d1 = __builtin_amdgcn_mfma_f32_16x16x32_bf16(cf[1], bfq, z, 0, 0, 0);
            float sinv = __builtin_amdgcn_rcpf(den);
            us4 w0;
            #pragma unroll
            for (int r = 0; r < 4; r++) w0[r] = f2b(d0[r] * sinv);
            *(us4*)&outp[n][h * 24 + lg * 4] = w0;
            if (lg < 2) {
                us4 w1;
                #pragma unroll
                for (int r = 0; r < 4; r++) w1[r] = f2b(d1[r] * sinv);
                *(us4*)&outp[n][h * 24 + 16 + lg * 4] = w1;
            }
        }
    }
    __syncthreads();

    f4 acc[4][3];
    #pragma unroll
    for (int i = 0; i < 4; i++) for (int j = 0; j < 3; j++) acc[i][j] = (f4)0.0f;
    #pragma unroll
    for (int k0 = 0; k0 < 192; k0 += 32) {
        s8 bf[4];
        #pragma unroll
        for (int pt = 0; pt < 4; pt++)
            bf[pt] = *(const s8*)&outp[pt * 16 + lr][k0 + lg * 8];
        #pragma unroll
        for (int ot = 0; ot < 3; ot++) {
            s8 af = *(const s8*)&outWb[(size_t)(wave * 48 + ot * 16 + lr) * 192 + k0 + lg * 8];
            #pragma unroll
            for (int pt = 0; pt < 4; pt++)
                acc[pt][ot] = __builtin_amdgcn_mfma_f32_16x16x32_bf16(bf[pt], af, acc[pt][ot], 0, 0, 0);
        }
    }

    float sP[4][4], qP[4][4];
    #pragma unroll
    for (int pt = 0; pt < 4; pt++)
        #pragma unroll
        for (int r = 0; r < 4; r++) { sP[pt][r] = 0.f; qP[pt][r] = 0.f; }

    #pragma unroll
    for (int ot = 0; ot < 3; ot++) {
        const int oc = wave * 48 + ot * 16 + lr;
        const float bi = outBias[oc];
        const size_t rowbase = ((size_t)b * 192 + oc) * NPIX + n0 + lg * 4;
        #pragma unroll
        for (int pt = 0; pt < 4; pt++) {
            f4 rv = *(const f4*)(xres + rowbase + pt * 16);
            f4 v;
            #pragma unroll
            for (int r = 0; r < 4; r++) {
                v[r] = acc[pt][ot][r] + bi + rv[r];
                sP[pt][r] += v[r]; qP[pt][r] += v[r] * v[r];
            }
            acc[pt][ot] = v;
            if (BIGWS) {
                us4 o;
                #pragma unroll
                for (int r = 0; r < 4; r++) o[r] = f2b(v[r]);
                *(us4*)(x2b + rowbase + pt * 16) = o;
            } else {
                *(f4*)(Out + rowbase + pt * 16) = v;
            }
        }
    }
    #pragma unroll
    for (int pt = 0; pt < 4; pt++)
        #pragma unroll
        for (int r = 0; r < 4; r++) {
            float s = sP[pt][r], q = qP[pt][r];
            s += __shfl_xor(s, 1); s += __shfl_xor(s, 2);
            s += __shfl_xor(s, 4); s += __shfl_xor(s, 8);
            q += __shfl_xor(q, 1); q += __shfl_xor(q, 2);
            q += __shfl_xor(q, 4); q += __shfl_xor(q, 8);
            sP[pt][r] = s; qP[pt][r] = q;
        }
    if (lr == 0) {
        #pragma unroll
        for (int pt = 0; pt < 4; pt++)
            #pragma unroll
            for (int r = 0; r < 4; r++) {
                lnS[wave][pt * 16 + lg * 4 + r] = sP[pt][r];
                lnQ[wave][pt * 16 + lg * 4 + r] = qP[pt][r];
            }
    }
    __syncthreads();

    // LN2 apply -> xn into outp
    float lgv[3], lbv[3];
    #pragma unroll
    for (int ot = 0; ot < 3; ot++) {
        int oc = wave * 48 + ot * 16 + lr;
        lgv[ot] = ln2g[oc]; lbv[ot] = ln2b[oc];
    }
    #pragma unroll
    for (int pt = 0; pt < 4; pt++) {
        float mu4[4], rs4[4];
        #pragma unroll
        for (int r = 0; r < 4; r++) {
            int px = pt * 16 + lg * 4 + r;
            float S = lnS[0][px] + lnS[1][px] + lnS[2][px] + lnS[3][px];
            float Qq = lnQ[0][px] + lnQ[1][px] + lnQ[2][px] + lnQ[3][px];
            float mu = S * (1.0f / 192.0f);
            float var = Qq * (1.0f / 192.0f) - mu * mu;
            mu4[r] = mu; rs4[r] = rsqrtf(var + 1e-5f);
        }
        #pragma unroll
        for (int ot = 0; ot < 3; ot++) {
            int oc = wave * 48 + ot * 16 + lr;
            #pragma unroll
            for (int r = 0; r < 4; r++) {
                int px = pt * 16 + lg * 4 + r;
                float xn = (acc[pt][ot][r] - mu4[r]) * rs4[r] * lgv[ot] + lbv[ot];
                outp[px][oc] = f2b(xn);
            }
        }
    }
    __syncthreads();

    // w1 GEMM in place -> h1t[px][384] + gelu_t
    #pragma unroll
    for (int cn = 0; cn < 2; cn++) {
        const int ocb = cn * 192 + wave * 48;
        const unsigned short* wrow = w1b + (size_t)(ocb + lr) * 192 + lg * 8;

        s8 wf[3][6];
        #pragma unroll
        for (int ot = 0; ot < 3; ot++)
            #pragma unroll
            for (int kk = 0; kk < 6; kk++)
                wf[ot][kk] = *(const s8*)(wrow + (size_t)ot * 16 * 192 + kk * 32);

        f4 acc2[4][3];
        #pragma unroll
        for (int i = 0; i < 4; i++)
            #pragma unroll
            for (int j = 0; j < 3; j++) acc2[i][j] = (f4)0.0f;

        #pragma unroll
        for (int kk = 0; kk < 6; kk++) {
            s8 bf[4];
            #pragma unroll
            for (int pt = 0; pt < 4; pt++)
                bf[pt] = *(const s8*)&outp[pt * 16 + lr][kk * 32 + lg * 8];
            #pragma unroll
            for (int ot = 0; ot < 3; ot++)
                #pragma unroll
                for (int pt = 0; pt < 4; pt++)
                    acc2[pt][ot] = __builtin_amdgcn_mfma_f32_16x16x32_bf16(wf[ot][kk], bf[pt], acc2[pt][ot], 0, 0, 0);
        }

        #pragma unroll
        for (int pt = 0; pt < 4; pt++) {
            const int gp = n0 + pt * 16 + lr;
            unsigned short* orow = h1t + (bpx + gp) * 384 + ocb + lg * 4;
            #pragma unroll
            for (int ot = 0; ot < 3; ot++) {
                f4 bi4 = *(const f4*)&b1[ocb + ot * 16 + lg * 4];
                us4 o;
                #pragma unroll
                for (int r = 0; r < 4; r++) o[r] = f2b(gelu_t(acc2[pt][ot][r] + bi4[r]));
                *(us4*)(orow + ot * 16) = o;
            }
        }
    }
}

// ---------------------------------------------------------------------------
// depthwise 3x3 + gelu on [px][384], row-streamed LDS ring; 16 rows/block.
// ---------------------------------------------------------------------------
__global__ __launch_bounds__(256) void dwconv_t2_k(
    const unsigned short* __restrict__ h1t, const float* __restrict__ w,
    const float* __restrict__ bias, unsigned short* __restrict__ h2t)
{
    __shared__ unsigned short ring[4 * 4 * 66 * 8];
    const int bz = blockIdx.z;
    const int b = bz / 12, cb = (bz % 12) * 32;
    const int y0 = blockIdx.y * 16, x0 = blockIdx.x * 64;
    const int tid = threadIdx.x;
    const int x = tid & 63, cg = tid >> 6;
    const int c0 = cb + cg * 8;
    const size_t bbase = (size_t)b << 16;

    float wr[9][8], bi[8];
    #pragma unroll
    for (int i = 0; i < 8; i++) {
        #pragma unroll
        for (int j = 0; j < 9; j++) wr[j][i] = rfl(w[(c0 + i) * 9 + j]);
        bi[i] = rfl(bias[c0 + i]);
    }

    const us8 zz = {0, 0, 0, 0, 0, 0, 0, 0};

    auto stage_row = [&](int gy, int s) {
        unsigned short* ldsrow = &ring[((s * 4 + cg) * 66) * 8];
        if (gy >= 0 && gy <= 255) {
            us8 ev = zz;
            if (x == 0 && x0 > 0)
                ev = *(const us8*)(h1t + (bbase + gy * 256 + x0 - 1) * 384 + c0);
            if (x == 63 && x0 + 64 < 256)
                ev = *(const us8*)(h1t + (bbase + gy * 256 + x0 + 64) * 384 + c0);
            gload_lds16(h1t + (bbase + gy * 256 + x0 + x) * 384 + c0,
                        ldsrow + (1 + x) * 8);
            if (x == 0)  *(us8*)&ldsrow[0]      = ev;
            if (x == 63) *(us8*)&ldsrow[65 * 8] = ev;
        } else {
            *(us8*)&ldsrow[(1 + x) * 8] = zz;
            if (x == 0)  *(us8*)&ldsrow[0]      = zz;
            if (x == 63) *(us8*)&ldsrow[65 * 8] = zz;
        }
    };

    stage_row(y0 - 1, 0);
    stage_row(y0,     1);
    stage_row(y0 + 1, 2);
    __syncthreads();

    #pragma unroll
    for (int y = 0; y < 16; y++) {
        if (y < 15) stage_row(y0 + y + 2, (y + 3) & 3);

        float a[8];
        #pragma unroll
        for (int i = 0; i < 8; i++) a[i] = bi[i];
        #pragma unroll
        for (int t = 0; t < 3; t++) {
            const int s = (y + t) & 3;
            const unsigned short* rp = &ring[((s * 4 + cg) * 66 + x) * 8];
            us8 L = *(const us8*)(rp);
            us8 C = *(const us8*)(rp + 8);
            us8 R = *(const us8*)(rp + 16);
            #pragma unroll
            for (int i = 0; i < 8; i++) {
                a[i] += wr[t * 3 + 0][i] * b2f(L[i]);
                a[i] += wr[t * 3 + 1][i] * b2f(C[i]);
                a[i] += wr[t * 3 + 2][i] * b2f(R[i]);
            }
        }
        us8 ov;
        #pragma unroll
        for (int i = 0; i < 8; i++) ov[i] = f2b(gelu_t(a[i]));
        *(us8*)(h2t + (bbase + (y0 + y) * 256 + x0 + x) * 384 + c0) = ov;

        __syncthreads();
    }
}

// ---------------------------------------------------------------------------
extern "C" void kernel_launch(void* const* d_in, const int* in_sizes, int n_in,
                              void* d_out, int out_size, void* d_ws, size_t ws_size,
                              hipStream_t stream)
{
    const float* x    = (const float*)d_in[0];
    const float* ln1g = (const float*)d_in[1];
    const float* ln1b = (const float*)d_in[2];
    const float* qkvw = (const float*)d_in[3];
    const float* qkvb = (const float*)d_in[4];
    const float* outw = (const float*)d_in[5];
    const float* outb = (const float*)d_in[6];
    const float* ln2g = (const float*)d_in[7];
    const float* ln2b = (const float*)d_in[8];
    const float* w1   = (const float*)d_in[9];
    const float* b1   = (const float*)d_in[10];
    const float* dww  = (const float*)d_in[11];
    const float* dwb  = (const float*)d_in[12];
    const float* w2   = (const float*)d_in[13];
    const float* b2   = (const float*)d_in[14];
    float* out = (float*)d_out;

    char* ws = (char*)d_ws;
    unsigned short* kv  = (unsigned short*)ws;
    unsigned short* h1t = (unsigned short*)ws;
    unsigned short* h2t = (unsigned short*)(ws + (size_t)201326592);
    unsigned short* qT  = (unsigned short*)(ws + (size_t)201326592);
    unsigned short* xnt = (unsigned short*)(ws + (size_t)301989888);
    size_t off = (size_t)402653184;
    float* koff = (float*)(ws + off); off += 4096;
    float* ctxT = (float*)(ws + off); off += 131072;
    unsigned short* ctxb = (unsigned short*)(ws + off); off += 65536;
    unsigned short* qkvwb = (unsigned short*)(ws + off); off += 221184;
    unsigned short* outwb = (unsigned short*)(ws + off); off += 73728 * 2;
    unsigned short* w1b   = (unsigned short*)(ws + off); off += 147456;
    unsigned short* w2b   = (unsigned short*)(ws + off); off += 147456;
    off = (off + 255) & ~(size_t)255;
    unsigned short* x2b = (unsigned short*)(ws + off);
    const bool bigws = ws_size >= off + (size_t)100663296;
    (void)koff;

    cvt_k<<<(110592 + 255) / 256, 256, 0, stream>>>(qkvw, qkvwb, 110592);
    cvt_k<<<(36864 + 255) / 256, 256, 0, stream>>>(outw, outwb, 36864);
    cvt_k<<<(73728 + 255) / 256, 256, 0, stream>>>(w1, w1b, 73728);
    cvt_k<<<(73728 + 255) / 256, 256, 0, stream>>>(w2, w2b, 73728);

    // 1) LN1 + transpose -> xnt
    lnt_k<<<1024, 256, 0, stream>>>(x, ln1g, ln1b, xnt);

    // 2) qkv GEMM: exp(q) -> qT, exp(k)/v -> kv
    gemm3_k<3, 3, 1, 4><<<1024, 256, 0, stream>>>(xnt, qkvwb, qkvb, nullptr, kv, 384, qT);

    // 3) context accumulation + denominator
    zero_k<<<128, 256, 0, stream>>>(ctxT, 32768);
    context_k<<<512, 256, 0, stream>>>(kv, ctxT);

    // 4) normalize ctx -> bf16 copy ctxb
    ctxnorm_k<<<4, 256, 0, stream>>>(ctxT, ctxb);

    // 5) qctx fused (+LN2 +w1+gelu_t -> h1t)
    if (bigws)
        qctx_proj_k<true><<<4096, 256, 0, stream>>>(qT, ctxb, outwb, outb, x, out,
                                                    x2b, ln2g, ln2b, w1b, b1, h1t);
    else
        qctx_proj_k<false><<<4096, 256, 0, stream>>>(qT, ctxb, outwb, outb, x, out,
                                                     x2b, ln2g, ln2b, w1b, b1, h1t);

    // 6) depthwise 3x3 + gelu -> h2t
    dwconv_t2_k<<<dim3(4, 16, 48), 256, 0, stream>>>(h1t, dww, dwb, h2t);

    // 7) w2 GEMM + bias + x2 residual -> d_out f32
    if (bigws)
        gemm3_k<4, 1, 2, 4><<<1024, 256, 0, stream>>>(h2t, w2b, b2, x2b, out, 192, nullptr);
    else
        gemm3_k<2, 1, 2, 4><<<1024, 256, 0, stream>>>(h2t, w2b, b2, out, out, 192, nullptr);
}

// Round 21
// 828.676 us; speedup vs baseline: 1.0903x; 1.0118x over previous
//
#include <hip/hip_runtime.h>
#include <hip/hip_bf16.h>
#include <math.h>

typedef __attribute__((ext_vector_type(8))) short s8;
typedef __attribute__((ext_vector_type(8))) unsigned short us8;
typedef __attribute__((ext_vector_type(4))) float f4;
typedef __attribute__((ext_vector_type(4))) unsigned short us4;
typedef __attribute__((ext_vector_type(4))) unsigned int u32x4;

#define DEVI __device__ __forceinline__

static const int NPIX = 65536;   // 256*256

DEVI float b2f(unsigned short u) {
    unsigned int v = ((unsigned int)u) << 16;
    float f; __builtin_memcpy(&f, &v, 4); return f;
}
// native conversion -> compiler packs pairs into v_cvt_pk_bf16_f32
DEVI unsigned short f2b(float f) {
    __hip_bfloat16 h = __float2bfloat16(f);
    unsigned short r; __builtin_memcpy(&r, &h, 2); return r;
}
DEVI float gelu_t(float x) {
    float z = 1.595769122f * (x + 0.044715f * x * x * x);
    return x * __builtin_amdgcn_rcpf(1.0f + __expf(-z));
}
DEVI float rfl(float v) {
    int i; __builtin_memcpy(&i, &v, 4);
    i = __builtin_amdgcn_readfirstlane(i);
    float o; __builtin_memcpy(&o, &i, 4); return o;
}

DEVI void gload_lds16(const unsigned short* g, unsigned short* l) {
    __builtin_amdgcn_global_load_lds(
        (const __attribute__((address_space(1))) unsigned int*)g,
        (__attribute__((address_space(3))) unsigned int*)l,
        16, 0, 0);
}

// ---------------------------------------------------------------------------
// merged prologue: 4 weight f32->bf16 conversions + ctxT zeroing (1 launch)
// ---------------------------------------------------------------------------
__global__ __launch_bounds__(256) void prep_k(
    const float* __restrict__ qkvw, const float* __restrict__ outw,
    const float* __restrict__ w1,   const float* __restrict__ w2,
    unsigned short* __restrict__ qkvwb, unsigned short* __restrict__ outwb,
    unsigned short* __restrict__ w1b,   unsigned short* __restrict__ w2b,
    float* __restrict__ ctxT)
{
    int i = blockIdx.x * 256 + threadIdx.x;
    if (i < 110592) { qkvwb[i] = f2b(qkvw[i]); return; }
    i -= 110592;
    if (i < 36864) { outwb[i] = f2b(outw[i]); return; }
    i -= 36864;
    if (i < 73728) { w1b[i] = f2b(w1[i]); return; }
    i -= 73728;
    if (i < 73728) { w2b[i] = f2b(w2[i]); return; }
    i -= 73728;
    if (i < 32768) ctxT[i] = 0.f;
}

// ---------------------------------------------------------------------------
// LayerNorm + transpose: x f32 [b][192][px] -> xnt bf16 [b*px][192]
// ---------------------------------------------------------------------------
__global__ __launch_bounds__(256) void lnt_k(const float* __restrict__ X,
                                             const float* __restrict__ gw,
                                             const float* __restrict__ gb,
                                             unsigned short* __restrict__ Out)
{
    const int i = blockIdx.x * 256 + threadIdx.x;
    const int b = i >> 16, px = i & 65535;
    const float* xp = X + (size_t)b * 192 * NPIX + px;

    unsigned int pk[96];
    float sum = 0.f, ssq = 0.f;
    #pragma unroll
    for (int c = 0; c < 192; c++) {
        float v = xp[(size_t)c * NPIX];
        sum += v; ssq += v * v;
        unsigned int h = f2b(v);
        if (c & 1) pk[c >> 1] |= h << 16;
        else       pk[c >> 1] = h;
    }
    float mu = sum * (1.0f / 192.0f);
    float var = ssq * (1.0f / 192.0f) - mu * mu;
    float rs = rsqrtf(var + 1e-5f);

    #pragma unroll
    for (int c2 = 0; c2 < 96; c2++) {
        int c = c2 * 2;
        float lo = b2f((unsigned short)(pk[c2] & 0xFFFF));
        float hi = b2f((unsigned short)(pk[c2] >> 16));
        lo = (lo - mu) * rs * gw[c] + gb[c];
        hi = (hi - mu) * rs * gw[c + 1] + gb[c + 1];
        pk[c2] = (unsigned int)f2b(lo) | ((unsigned int)f2b(hi) << 16);
    }
    u32x4* dst = (u32x4*)(Out + (size_t)i * 192);
    #pragma unroll
    for (int j = 0; j < 6; j++) {
        u32x4 v = { pk[4 * j], pk[4 * j + 1], pk[4 * j + 2], pk[4 * j + 3] };
        dst[j] = v;
    }
}

// ---------------------------------------------------------------------------
// Pipelined staged GEMM.
// MODE 2: out f32  [b][192][px], bias + f32 resid    (w2, small-ws)
// MODE 3: qkv: cn==0 -> exp(q) -> qT[gp][192]; cn==1 -> exp(k); cn==2 -> v
// MODE 4: out f32  [b][192][px], bias + bf16 resid   (w2, big-ws)
// ---------------------------------------------------------------------------
template<int MODE, int NCHUNK, int UNITS, int NTILE>
__global__ __launch_bounds__(256) void gemm3_k(
    const unsigned short* __restrict__ X, const unsigned short* __restrict__ Wb,
    const float* __restrict__ bias, const void* __restrict__ resid,
    void* __restrict__ Out, int OCTOT, unsigned short* __restrict__ qT)
{
    constexpr int KTOT = UNITS * 192;
    __shared__ unsigned short tile[2][64 * 192];

    const int tid = threadIdx.x;
    const int wave = tid >> 6, lane = tid & 63;
    const int lr = lane & 15, lg = lane >> 4;
    const int xr = lr & 7;

    auto stage = [&](int s, int buf) {
        const int t = s / UNITS, u = s - t * UNITS;
        const int gp0s = (blockIdx.x * NTILE + t) * 64;
        const unsigned short* Xb = X + (size_t)gp0s * KTOT + u * 192;
        #pragma unroll
        for (int j = 0; j < 6; j++) {
            int ci = (wave * 6 + j) * 64 + lane;
            int row = ci / 24;
            int c = ci - row * 24;
            int csw = (c & ~7) | ((c ^ row) & 7);
            gload_lds16(Xb + (size_t)row * KTOT + csw * 8, &tile[buf][ci * 8]);
        }
    };

    stage(0, 0);

    for (int t = 0; t < NTILE; t++) {
        const int gp0 = (blockIdx.x * NTILE + t) * 64;
        const int b = gp0 >> 16;
        const int pxb = gp0 & 65535;

        if constexpr (UNITS == 1) {
            __syncthreads();
            if (t + 1 < NTILE) stage(t + 1, (t + 1) & 1);
            const unsigned short* tb = tile[t & 1];

            #pragma unroll
            for (int cn = 0; cn < NCHUNK; cn++) {
                const int ocb = cn * 192 + wave * 48;
                const unsigned short* wrow = Wb + (size_t)(ocb + lr) * KTOT + lg * 8;
                const bool swapped = (MODE == 3 && cn == 0);

                s8 wf[3][6];
                #pragma unroll
                for (int ot = 0; ot < 3; ot++)
                    #pragma unroll
                    for (int kk = 0; kk < 6; kk++)
                        wf[ot][kk] = *(const s8*)(wrow + (size_t)ot * 16 * KTOT + kk * 32);

                f4 acc[4][3];
                #pragma unroll
                for (int i = 0; i < 4; i++)
                    #pragma unroll
                    for (int j = 0; j < 3; j++) acc[i][j] = (f4)0.0f;

                #pragma unroll
                for (int kk = 0; kk < 6; kk++) {
                    const int kc = kk * 4 + lg;
                    const int kcs = (kc & ~7) | ((kc ^ xr) & 7);
                    s8 a[4];
                    #pragma unroll
                    for (int pt = 0; pt < 4; pt++)
                        a[pt] = *(const s8*)&tb[((pt * 16 + lr) * 24 + kcs) * 8];
                    #pragma unroll
                    for (int ot = 0; ot < 3; ot++)
                        #pragma unroll
                        for (int pt = 0; pt < 4; pt++)
                            acc[pt][ot] = swapped
                                ? __builtin_amdgcn_mfma_f32_16x16x32_bf16(wf[ot][kk], a[pt], acc[pt][ot], 0, 0, 0)
                                : __builtin_amdgcn_mfma_f32_16x16x32_bf16(a[pt], wf[ot][kk], acc[pt][ot], 0, 0, 0);
                }

                if (MODE == 3 && cn == 0) {
                    #pragma unroll
                    for (int pt = 0; pt < 4; pt++) {
                        const int gp = gp0 + pt * 16 + lr;
                        unsigned short* orow = qT + (size_t)gp * 192 + wave * 48 + lg * 4;
                        #pragma unroll
                        for (int ot = 0; ot < 3; ot++) {
                            f4 bi4 = *(const f4*)&bias[wave * 48 + ot * 16 + lg * 4];
                            us4 o;
                            #pragma unroll
                            for (int r = 0; r < 4; r++) o[r] = f2b(__expf(acc[pt][ot][r] + bi4[r]));
                            *(us4*)(orow + ot * 16) = o;
                        }
                    }
                } else if (MODE == 3) {
                    #pragma unroll
                    for (int ot = 0; ot < 3; ot++) {
                        const int oc = ocb + ot * 16 + lr;
                        const float bi = bias[oc];
                        const size_t rowoff = ((size_t)b * 384 + (oc - 192)) * NPIX + pxb + lg * 4;
                        #pragma unroll
                        for (int pt = 0; pt < 4; pt++) {
                            us4 o;
                            #pragma unroll
                            for (int r = 0; r < 4; r++) {
                                float v = acc[pt][ot][r] + bi;
                                if (cn == 1) v = __expf(v);
                                o[r] = f2b(v);
                            }
                            *(us4*)((unsigned short*)Out + rowoff + pt * 16) = o;
                        }
                    }
                }
            }
        } else {
            // UNITS == 2, NCHUNK == 1 (w2)
            const int ocb = wave * 48;
            const unsigned short* wrow = Wb + (size_t)(ocb + lr) * KTOT + lg * 8;

            f4 acc[4][3];
            #pragma unroll
            for (int i = 0; i < 4; i++)
                #pragma unroll
                for (int j = 0; j < 3; j++) acc[i][j] = (f4)0.0f;

            #pragma unroll
            for (int u = 0; u < 2; u++) {
                const int s = t * 2 + u;
                __syncthreads();
                if (s + 1 < NTILE * 2) stage(s + 1, (s + 1) & 1);
                const unsigned short* tb = tile[s & 1];

                s8 wf[3][6];
                #pragma unroll
                for (int ot = 0; ot < 3; ot++)
                    #pragma unroll
                    for (int kk = 0; kk < 6; kk++)
                        wf[ot][kk] = *(const s8*)(wrow + (size_t)ot * 16 * KTOT + u * 192 + kk * 32);

                #pragma unroll
                for (int kk = 0; kk < 6; kk++) {
                    const int kc = kk * 4 + lg;
                    const int kcs = (kc & ~7) | ((kc ^ xr) & 7);
                    s8 a[4];
                    #pragma unroll
                    for (int pt = 0; pt < 4; pt++)
                        a[pt] = *(const s8*)&tb[((pt * 16 + lr) * 24 + kcs) * 8];
                    #pragma unroll
                    for (int ot = 0; ot < 3; ot++)
                        #pragma unroll
                        for (int pt = 0; pt < 4; pt++)
                            acc[pt][ot] = __builtin_amdgcn_mfma_f32_16x16x32_bf16(a[pt], wf[ot][kk], acc[pt][ot], 0, 0, 0);
                }
            }

            #pragma unroll
            for (int ot = 0; ot < 3; ot++) {
                const int oc = ocb + ot * 16 + lr;
                const float bi = bias[oc];
                const size_t rowoff = ((size_t)b * 192 + oc) * NPIX + pxb + lg * 4;
                #pragma unroll
                for (int pt = 0; pt < 4; pt++) {
                    if (MODE == 2) {
                        f4 rv = *(const f4*)((const float*)resid + rowoff + pt * 16);
                        f4 o;
                        #pragma unroll
                        for (int r = 0; r < 4; r++) o[r] = acc[pt][ot][r] + bi + rv[r];
                        *(f4*)((float*)Out + rowoff + pt * 16) = o;
                    } else {  // MODE 4
                        us4 rv = *(const us4*)((const unsigned short*)resid + rowoff + pt * 16);
                        f4 o;
                        #pragma unroll
                        for (int r = 0; r < 4; r++) o[r] = acc[pt][ot][r] + bi + b2f(rv[r]);
                        *(f4*)((float*)Out + rowoff + pt * 16) = o;
                    }
                }
            }
        }
    }
}

// ---------------------------------------------------------------------------
// context (exp-free) + denominator row d=24 via all-ones v fragment.
// ---------------------------------------------------------------------------
__global__ __launch_bounds__(256) void context_k(const unsigned short* __restrict__ kv,
                                                 float* __restrict__ ctxT)
{
    __shared__ float red[4][64][16];
    int bid = blockIdx.x;
    int bh = bid >> 4, cgrp = bid & 15;
    int b = bh >> 3, h = bh & 7;
    int tid = threadIdx.x;
    int wave = tid >> 6, lane = tid & 63, lr = lane & 15, lg = lane >> 4;
    int chunk = cgrp * 4 + wave;
    size_t nbase = (size_t)chunk * 1024 + lg * 8;

    int c0 = h * 24 + lr;
    int c1 = h * 24 + 16 + lr;
    bool val1 = lr < 8;

    const unsigned short* k0p = kv + ((size_t)b * 384 + c0) * NPIX + nbase;
    const unsigned short* k1p = kv + ((size_t)b * 384 + (c1 > 191 ? 191 : c1)) * NPIX + nbase;
    const unsigned short* v0p = kv + ((size_t)b * 384 + 192 + h * 24 + lr) * NPIX + nbase;
    const unsigned short* v1p = kv + ((size_t)b * 384 + 192 + ((h * 24 + 16 + lr > 191) ? 191 : h * 24 + 16 + lr)) * NPIX + nbase;

    const short one_bf = (short)0x3F80;
    s8 ones8 = { one_bf, one_bf, one_bf, one_bf, one_bf, one_bf, one_bf, one_bf };
    s8 zero8 = (s8)0;

    f4 acc[2][2];
    #pragma unroll
    for (int i = 0; i < 2; i++) for (int j = 0; j < 2; j++) acc[i][j] = (f4)0.0f;

    for (int s = 0; s < 32; s++) {
        int off = s * 32;
        s8 p0 = *(const s8*)(k0p + off);
        s8 p1 = *(const s8*)(k1p + off);
        s8 vr0 = *(const s8*)(v0p + off);
        s8 vr1 = *(const s8*)(v1p + off);
        if (!val1) p1 = zero8;
        if (lr == 8) vr1 = ones8;
        acc[0][0] = __builtin_amdgcn_mfma_f32_16x16x32_bf16(p0, vr0, acc[0][0], 0, 0, 0);
        acc[0][1] = __builtin_amdgcn_mfma_f32_16x16x32_bf16(p0, vr1, acc[0][1], 0, 0, 0);
        acc[1][0] = __builtin_amdgcn_mfma_f32_16x16x32_bf16(p1, vr0, acc[1][0], 0, 0, 0);
        acc[1][1] = __builtin_amdgcn_mfma_f32_16x16x32_bf16(p1, vr1, acc[1][1], 0, 0, 0);
    }
    #pragma unroll
    for (int mt = 0; mt < 2; mt++)
        #pragma unroll
        for (int ct = 0; ct < 2; ct++)
            #pragma unroll
            for (int r = 0; r < 4; r++)
                red[wave][lane][mt * 8 + ct * 4 + r] = acc[mt][ct][r];
    __syncthreads();

    if (wave == 0) {
        float* base = ctxT + (size_t)(b * 8 + h) * 1024;
        #pragma unroll
        for (int j = 0; j < 16; j++) {
            float sum = red[0][lane][j] + red[1][lane][j] + red[2][lane][j] + red[3][lane][j];
            int mt = j >> 3, ct = (j >> 2) & 1, r = j & 3;
            int c = mt * 16 + lg * 4 + r;
            int d = ct * 16 + lr;
            atomicAdd(base + d * 32 + c, sum);
        }
    }
}

// ---------------------------------------------------------------------------
// normalize ctx rows 0..23 by denominator; emit bf16 copy ctxb[bh][32][32]
// ---------------------------------------------------------------------------
__global__ void ctxnorm_k(float* __restrict__ ctxT, unsigned short* __restrict__ ctxb)
{
    int i = blockIdx.x * 256 + threadIdx.x;
    if (i >= 1024) return;
    int bh = i >> 5, c = i & 31;
    float* base = ctxT + (size_t)bh * 1024;
    unsigned short* bb = ctxb + (size_t)bh * 1024;
    float den = base[24 * 32 + c];
    float r = den > 0.f ? 1.0f / den : 0.0f;
    #pragma unroll
    for (int d = 0; d < 24; d++) {
        float v = base[d * 32 + c] * r;
        bb[d * 32 + c] = f2b(v);
    }
    #pragma unroll
    for (int d = 24; d < 32; d++) bb[d * 32 + c] = 0;
}

// ---------------------------------------------------------------------------
// fused qctx+w1
// ---------------------------------------------------------------------------
template<bool BIGWS>
__global__ __launch_bounds__(256) void qctx_proj_k(
    const unsigned short* __restrict__ qT, const unsigned short* __restrict__ ctxb,
    const unsigned short* __restrict__ outWb, const float* __restrict__ outBias,
    const float* __restrict__ xres, float* __restrict__ Out,
    unsigned short* __restrict__ x2b,
    const float* __restrict__ ln2g, const float* __restrict__ ln2b,
    const unsigned short* __restrict__ w1b, const float* __restrict__ b1,
    unsigned short* __restrict__ h1t)
{
    __shared__ unsigned short outp[64][200];
    __shared__ float lnS[4][64], lnQ[4][64];

    int tid = threadIdx.x, bid = blockIdx.x;
    int b = bid >> 10, n0 = (bid & 1023) * 64;
    int wave = tid >> 6, lane = tid & 63, lr = lane & 15, lg = lane >> 4;
    const size_t bpx = (size_t)b << 16;

    #pragma unroll
    for (int hh = 0; hh < 2; hh++) {
        int h = wave * 2 + hh;
        const unsigned short* cb = ctxb + (size_t)(b * 8 + h) * 1024;
        s8 cf[2];
        #pragma unroll
        for (int mt = 0; mt < 2; mt++)
            cf[mt] = *(const s8*)(cb + (mt * 16 + lr) * 32 + lg * 8);
        #pragma unroll
        for (int nt = 0; nt < 4; nt++) {
            int n = nt * 16 + lr;
            s8 bfq = (s8)0;
            float sown = 0.f;
            if (lg < 3) {
                bfq = *(const s8*)(qT + (bpx + n0 + n) * 192 + h * 24 + lg * 8);
                #pragma unroll
                for (int j = 0; j < 8; j++) sown += b2f((unsigned short)bfq[j]);
            }
            float den = sown;
            den += __shfl_xor(den, 16);
            den += __shfl_xor(den, 32);
            f4 z = (f4)0.0f;
            f4 d0 = __builtin_amdgcn_mfma_f32_16x16x32_bf16(cf[0], bfq, z, 0, 0, 0);
            f4 d1 = __builtin_amdgcn_mfma_f32_16x16x32_bf16(cf[1], bfq, z, 0, 0, 0);
            float sinv = __builtin_amdgcn_rcpf(den);
            us4 w0;
            #pragma unroll
            for (int r = 0; r < 4; r++) w0[r] = f2b(d0[r] * sinv);
            *(us4*)&outp[n][h * 24 + lg * 4] = w0;
            if (lg < 2) {
                us4 w1;
                #pragma unroll
                for (int r = 0; r < 4; r++) w1[r] = f2b(d1[r] * sinv);
                *(us4*)&outp[n][h * 24 + 16 + lg * 4] = w1;
            }
        }
    }
    __syncthreads();

    f4 acc[4][3];
    #pragma unroll
    for (int i = 0; i < 4; i++) for (int j = 0; j < 3; j++) acc[i][j] = (f4)0.0f;
    #pragma unroll
    for (int k0 = 0; k0 < 192; k0 += 32) {
        s8 bf[4];
        #pragma unroll
        for (int pt = 0; pt < 4; pt++)
            bf[pt] = *(const s8*)&outp[pt * 16 + lr][k0 + lg * 8];
        #pragma unroll
        for (int ot = 0; ot < 3; ot++) {
            s8 af = *(const s8*)&outWb[(size_t)(wave * 48 + ot * 16 + lr) * 192 + k0 + lg * 8];
            #pragma unroll
            for (int pt = 0; pt < 4; pt++)
                acc[pt][ot] = __builtin_amdgcn_mfma_f32_16x16x32_bf16(bf[pt], af, acc[pt][ot], 0, 0, 0);
        }
    }

    float sP[4][4], qP[4][4];
    #pragma unroll
    for (int pt = 0; pt < 4; pt++)
        #pragma unroll
        for (int r = 0; r < 4; r++) { sP[pt][r] = 0.f; qP[pt][r] = 0.f; }

    #pragma unroll
    for (int ot = 0; ot < 3; ot++) {
        const int oc = wave * 48 + ot * 16 + lr;
        const float bi = outBias[oc];
        const size_t rowbase = ((size_t)b * 192 + oc) * NPIX + n0 + lg * 4;
        #pragma unroll
        for (int pt = 0; pt < 4; pt++) {
            f4 rv = *(const f4*)(xres + rowbase + pt * 16);
            f4 v;
            #pragma unroll
            for (int r = 0; r < 4; r++) {
                v[r] = acc[pt][ot][r] + bi + rv[r];
                sP[pt][r] += v[r]; qP[pt][r] += v[r] * v[r];
            }
            acc[pt][ot] = v;
            if (BIGWS) {
                us4 o;
                #pragma unroll
                for (int r = 0; r < 4; r++) o[r] = f2b(v[r]);
                *(us4*)(x2b + rowbase + pt * 16) = o;
            } else {
                *(f4*)(Out + rowbase + pt * 16) = v;
            }
        }
    }
    #pragma unroll
    for (int pt = 0; pt < 4; pt++)
        #pragma unroll
        for (int r = 0; r < 4; r++) {
            float s = sP[pt][r], q = qP[pt][r];
            s += __shfl_xor(s, 1); s += __shfl_xor(s, 2);
            s += __shfl_xor(s, 4); s += __shfl_xor(s, 8);
            q += __shfl_xor(q, 1); q += __shfl_xor(q, 2);
            q += __shfl_xor(q, 4); q += __shfl_xor(q, 8);
            sP[pt][r] = s; qP[pt][r] = q;
        }
    if (lr == 0) {
        #pragma unroll
        for (int pt = 0; pt < 4; pt++)
            #pragma unroll
            for (int r = 0; r < 4; r++) {
                lnS[wave][pt * 16 + lg * 4 + r] = sP[pt][r];
                lnQ[wave][pt * 16 + lg * 4 + r] = qP[pt][r];
            }
    }
    __syncthreads();

    // LN2 apply -> xn into outp
    float lgv[3], lbv[3];
    #pragma unroll
    for (int ot = 0; ot < 3; ot++) {
        int oc = wave * 48 + ot * 16 + lr;
        lgv[ot] = ln2g[oc]; lbv[ot] = ln2b[oc];
    }
    #pragma unroll
    for (int pt = 0; pt < 4; pt++) {
        float mu4[4], rs4[4];
        #pragma unroll
        for (int r = 0; r < 4; r++) {
            int px = pt * 16 + lg * 4 + r;
            float S = lnS[0][px] + lnS[1][px] + lnS[2][px] + lnS[3][px];
            float Qq = lnQ[0][px] + lnQ[1][px] + lnQ[2][px] + lnQ[3][px];
            float mu = S * (1.0f / 192.0f);
            float var = Qq * (1.0f / 192.0f) - mu * mu;
            mu4[r] = mu; rs4[r] = rsqrtf(var + 1e-5f);
        }
        #pragma unroll
        for (int ot = 0; ot < 3; ot++) {
            int oc = wave * 48 + ot * 16 + lr;
            #pragma unroll
            for (int r = 0; r < 4; r++) {
                int px = pt * 16 + lg * 4 + r;
                float xn = (acc[pt][ot][r] - mu4[r]) * rs4[r] * lgv[ot] + lbv[ot];
                outp[px][oc] = f2b(xn);
            }
        }
    }
    __syncthreads();

    // w1 GEMM in place -> h1t[px][384] + gelu_t
    #pragma unroll
    for (int cn = 0; cn < 2; cn++) {
        const int ocb = cn * 192 + wave * 48;
        const unsigned short* wrow = w1b + (size_t)(ocb + lr) * 192 + lg * 8;

        s8 wf[3][6];
        #pragma unroll
        for (int ot = 0; ot < 3; ot++)
            #pragma unroll
            for (int kk = 0; kk < 6; kk++)
                wf[ot][kk] = *(const s8*)(wrow + (size_t)ot * 16 * 192 + kk * 32);

        f4 acc2[4][3];
        #pragma unroll
        for (int i = 0; i < 4; i++)
            #pragma unroll
            for (int j = 0; j < 3; j++) acc2[i][j] = (f4)0.0f;

        #pragma unroll
        for (int kk = 0; kk < 6; kk++) {
            s8 bf[4];
            #pragma unroll
            for (int pt = 0; pt < 4; pt++)
                bf[pt] = *(const s8*)&outp[pt * 16 + lr][kk * 32 + lg * 8];
            #pragma unroll
            for (int ot = 0; ot < 3; ot++)
                #pragma unroll
                for (int pt = 0; pt < 4; pt++)
                    acc2[pt][ot] = __builtin_amdgcn_mfma_f32_16x16x32_bf16(wf[ot][kk], bf[pt], acc2[pt][ot], 0, 0, 0);
        }

        #pragma unroll
        for (int pt = 0; pt < 4; pt++) {
            const int gp = n0 + pt * 16 + lr;
            unsigned short* orow = h1t + (bpx + gp) * 384 + ocb + lg * 4;
            #pragma unroll
            for (int ot = 0; ot < 3; ot++) {
                f4 bi4 = *(const f4*)&b1[ocb + ot * 16 + lg * 4];
                us4 o;
                #pragma unroll
                for (int r = 0; r < 4; r++) o[r] = f2b(gelu_t(acc2[pt][ot][r] + bi4[r]));
                *(us4*)(orow + ot * 16) = o;
            }
        }
    }
}

// ---------------------------------------------------------------------------
// depthwise 3x3 + gelu on [px][384], row-streamed LDS ring; 16 rows/block.
// ---------------------------------------------------------------------------
__global__ __launch_bounds__(256) void dwconv_t2_k(
    const unsigned short* __restrict__ h1t, const float* __restrict__ w,
    const float* __restrict__ bias, unsigned short* __restrict__ h2t)
{
    __shared__ unsigned short ring[4 * 4 * 66 * 8];
    const int bz = blockIdx.z;
    const int b = bz / 12, cb = (bz % 12) * 32;
    const int y0 = blockIdx.y * 16, x0 = blockIdx.x * 64;
    const int tid = threadIdx.x;
    const int x = tid & 63, cg = tid >> 6;
    const int c0 = cb + cg * 8;
    const size_t bbase = (size_t)b << 16;

    float wr[9][8], bi[8];
    #pragma unroll
    for (int i = 0; i < 8; i++) {
        #pragma unroll
        for (int j = 0; j < 9; j++) wr[j][i] = rfl(w[(c0 + i) * 9 + j]);
        bi[i] = rfl(bias[c0 + i]);
    }

    const us8 zz = {0, 0, 0, 0, 0, 0, 0, 0};

    auto stage_row = [&](int gy, int s) {
        unsigned short* ldsrow = &ring[((s * 4 + cg) * 66) * 8];
        if (gy >= 0 && gy <= 255) {
            us8 ev = zz;
            if (x == 0 && x0 > 0)
                ev = *(const us8*)(h1t + (bbase + gy * 256 + x0 - 1) * 384 + c0);
            if (x == 63 && x0 + 64 < 256)
                ev = *(const us8*)(h1t + (bbase + gy * 256 + x0 + 64) * 384 + c0);
            gload_lds16(h1t + (bbase + gy * 256 + x0 + x) * 384 + c0,
                        ldsrow + (1 + x) * 8);
            if (x == 0)  *(us8*)&ldsrow[0]      = ev;
            if (x == 63) *(us8*)&ldsrow[65 * 8] = ev;
        } else {
            *(us8*)&ldsrow[(1 + x) * 8] = zz;
            if (x == 0)  *(us8*)&ldsrow[0]      = zz;
            if (x == 63) *(us8*)&ldsrow[65 * 8] = zz;
        }
    };

    stage_row(y0 - 1, 0);
    stage_row(y0,     1);
    stage_row(y0 + 1, 2);
    __syncthreads();

    #pragma unroll
    for (int y = 0; y < 16; y++) {
        if (y < 15) stage_row(y0 + y + 2, (y + 3) & 3);

        float a[8];
        #pragma unroll
        for (int i = 0; i < 8; i++) a[i] = bi[i];
        #pragma unroll
        for (int t = 0; t < 3; t++) {
            const int s = (y + t) & 3;
            const unsigned short* rp = &ring[((s * 4 + cg) * 66 + x) * 8];
            us8 L = *(const us8*)(rp);
            us8 C = *(const us8*)(rp + 8);
            us8 R = *(const us8*)(rp + 16);
            #pragma unroll
            for (int i = 0; i < 8; i++) {
                a[i] += wr[t * 3 + 0][i] * b2f(L[i]);
                a[i] += wr[t * 3 + 1][i] * b2f(C[i]);
                a[i] += wr[t * 3 + 2][i] * b2f(R[i]);
            }
        }
        us8 ov;
        #pragma unroll
        for (int i = 0; i < 8; i++) ov[i] = f2b(gelu_t(a[i]));
        *(us8*)(h2t + (bbase + (y0 + y) * 256 + x0 + x) * 384 + c0) = ov;

        __syncthreads();
    }
}

// ---------------------------------------------------------------------------
extern "C" void kernel_launch(void* const* d_in, const int* in_sizes, int n_in,
                              void* d_out, int out_size, void* d_ws, size_t ws_size,
                              hipStream_t stream)
{
    const float* x    = (const float*)d_in[0];
    const float* ln1g = (const float*)d_in[1];
    const float* ln1b = (const float*)d_in[2];
    const float* qkvw = (const float*)d_in[3];
    const float* qkvb = (const float*)d_in[4];
    const float* outw = (const float*)d_in[5];
    const float* outb = (const float*)d_in[6];
    const float* ln2g = (const float*)d_in[7];
    const float* ln2b = (const float*)d_in[8];
    const float* w1   = (const float*)d_in[9];
    const float* b1   = (const float*)d_in[10];
    const float* dww  = (const float*)d_in[11];
    const float* dwb  = (const float*)d_in[12];
    const float* w2   = (const float*)d_in[13];
    const float* b2   = (const float*)d_in[14];
    float* out = (float*)d_out;

    char* ws = (char*)d_ws;
    unsigned short* kv  = (unsigned short*)ws;
    unsigned short* h1t = (unsigned short*)ws;
    unsigned short* h2t = (unsigned short*)(ws + (size_t)201326592);
    unsigned short* qT  = (unsigned short*)(ws + (size_t)201326592);
    unsigned short* xnt = (unsigned short*)(ws + (size_t)301989888);
    size_t off = (size_t)402653184;
    float* koff = (float*)(ws + off); off += 4096;
    float* ctxT = (float*)(ws + off); off += 131072;
    unsigned short* ctxb = (unsigned short*)(ws + off); off += 65536;
    unsigned short* qkvwb = (unsigned short*)(ws + off); off += 221184;
    unsigned short* outwb = (unsigned short*)(ws + off); off += 73728 * 2;
    unsigned short* w1b   = (unsigned short*)(ws + off); off += 147456;
    unsigned short* w2b   = (unsigned short*)(ws + off); off += 147456;
    off = (off + 255) & ~(size_t)255;
    unsigned short* x2b = (unsigned short*)(ws + off);
    const bool bigws = ws_size >= off + (size_t)100663296;
    (void)koff;

    // 0) merged prologue: weight conversions + ctxT zeroing (1 launch)
    prep_k<<<1280, 256, 0, stream>>>(qkvw, outw, w1, w2,
                                     qkvwb, outwb, w1b, w2b, ctxT);

    // 1) LN1 + transpose -> xnt
    lnt_k<<<1024, 256, 0, stream>>>(x, ln1g, ln1b, xnt);

    // 2) qkv GEMM: exp(q) -> qT, exp(k)/v -> kv
    gemm3_k<3, 3, 1, 4><<<1024, 256, 0, stream>>>(xnt, qkvwb, qkvb, nullptr, kv, 384, qT);

    // 3) context accumulation + denominator
    context_k<<<512, 256, 0, stream>>>(kv, ctxT);

    // 4) normalize ctx -> bf16 copy ctxb
    ctxnorm_k<<<4, 256, 0, stream>>>(ctxT, ctxb);

    // 5) qctx fused (+LN2 +w1+gelu_t -> h1t)
    if (bigws)
        qctx_proj_k<true><<<4096, 256, 0, stream>>>(qT, ctxb, outwb, outb, x, out,
                                                    x2b, ln2g, ln2b, w1b, b1, h1t);
    else
        qctx_proj_k<false><<<4096, 256, 0, stream>>>(qT, ctxb, outwb, outb, x, out,
                                                     x2b, ln2g, ln2b, w1b, b1, h1t);

    // 6) depthwise 3x3 + gelu -> h2t
    dwconv_t2_k<<<dim3(4, 16, 48), 256, 0, stream>>>(h1t, dww, dwb, h2t);

    // 7) w2 GEMM + bias + x2 residual -> d_out f32
    if (bigws)
        gemm3_k<4, 1, 2, 4><<<1024, 256, 0, stream>>>(h2t, w2b, b2, x2b, out, 192, nullptr);
    else
        gemm3_k<2, 1, 2, 4><<<1024, 256, 0, stream>>>(h2t, w2b, b2, out, out, 192, nullptr);
}

// Round 22
// 822.426 us; speedup vs baseline: 1.0986x; 1.0076x over previous
//
#include <hip/hip_runtime.h>
#include <hip/hip_bf16.h>
#include <math.h>

typedef __attribute__((ext_vector_type(8))) short s8;
typedef __attribute__((ext_vector_type(8))) unsigned short us8;
typedef __attribute__((ext_vector_type(4))) float f4;
typedef __attribute__((ext_vector_type(4))) unsigned short us4;
typedef __attribute__((ext_vector_type(4))) unsigned int u32x4;

#define DEVI __device__ __forceinline__

static const int NPIX = 65536;   // 256*256

DEVI float b2f(unsigned short u) {
    unsigned int v = ((unsigned int)u) << 16;
    float f; __builtin_memcpy(&f, &v, 4); return f;
}
// native conversion -> compiler packs pairs into v_cvt_pk_bf16_f32
DEVI unsigned short f2b(float f) {
    __hip_bfloat16 h = __float2bfloat16(f);
    unsigned short r; __builtin_memcpy(&r, &h, 2); return r;
}
DEVI float gelu_t(float x) {
    float z = 1.595769122f * (x + 0.044715f * x * x * x);
    return x * __builtin_amdgcn_rcpf(1.0f + __expf(-z));
}
DEVI float rfl(float v) {
    int i; __builtin_memcpy(&i, &v, 4);
    i = __builtin_amdgcn_readfirstlane(i);
    float o; __builtin_memcpy(&o, &i, 4); return o;
}

DEVI void gload_lds16(const unsigned short* g, unsigned short* l) {
    __builtin_amdgcn_global_load_lds(
        (const __attribute__((address_space(1))) unsigned int*)g,
        (__attribute__((address_space(3))) unsigned int*)l,
        16, 0, 0);
}

// ---------------------------------------------------------------------------
// merged prologue: LN1+transpose (blocks 0..1023) and weight conversions +
// ctxT zeroing (blocks 1024..2303). Single launch.
// ---------------------------------------------------------------------------
__global__ __launch_bounds__(256) void prelnt_k(
    const float* __restrict__ X, const float* __restrict__ gw,
    const float* __restrict__ gb, unsigned short* __restrict__ Out,
    const float* __restrict__ qkvw, const float* __restrict__ outw,
    const float* __restrict__ w1,   const float* __restrict__ w2,
    unsigned short* __restrict__ qkvwb, unsigned short* __restrict__ outwb,
    unsigned short* __restrict__ w1b,   unsigned short* __restrict__ w2b,
    float* __restrict__ ctxT)
{
    const int bid = blockIdx.x;
    if (bid >= 1024) {
        int i = (bid - 1024) * 256 + threadIdx.x;
        if (i < 110592) { qkvwb[i] = f2b(qkvw[i]); return; }
        i -= 110592;
        if (i < 36864) { outwb[i] = f2b(outw[i]); return; }
        i -= 36864;
        if (i < 73728) { w1b[i] = f2b(w1[i]); return; }
        i -= 73728;
        if (i < 73728) { w2b[i] = f2b(w2[i]); return; }
        i -= 73728;
        if (i < 32768) ctxT[i] = 0.f;
        return;
    }

    const int i = bid * 256 + threadIdx.x;
    const int b = i >> 16, px = i & 65535;
    const float* xp = X + (size_t)b * 192 * NPIX + px;

    unsigned int pk[96];
    float sum = 0.f, ssq = 0.f;
    #pragma unroll
    for (int c = 0; c < 192; c++) {
        float v = xp[(size_t)c * NPIX];
        sum += v; ssq += v * v;
        unsigned int h = f2b(v);
        if (c & 1) pk[c >> 1] |= h << 16;
        else       pk[c >> 1] = h;
    }
    float mu = sum * (1.0f / 192.0f);
    float var = ssq * (1.0f / 192.0f) - mu * mu;
    float rs = rsqrtf(var + 1e-5f);

    #pragma unroll
    for (int c2 = 0; c2 < 96; c2++) {
        int c = c2 * 2;
        float lo = b2f((unsigned short)(pk[c2] & 0xFFFF));
        float hi = b2f((unsigned short)(pk[c2] >> 16));
        lo = (lo - mu) * rs * gw[c] + gb[c];
        hi = (hi - mu) * rs * gw[c + 1] + gb[c + 1];
        pk[c2] = (unsigned int)f2b(lo) | ((unsigned int)f2b(hi) << 16);
    }
    u32x4* dst = (u32x4*)(Out + (size_t)i * 192);
    #pragma unroll
    for (int j = 0; j < 6; j++) {
        u32x4 v = { pk[4 * j], pk[4 * j + 1], pk[4 * j + 2], pk[4 * j + 3] };
        dst[j] = v;
    }
}

// ---------------------------------------------------------------------------
// Pipelined staged GEMM.
// MODE 2: out f32  [b][192][px], bias + f32 resid    (w2, small-ws)
// MODE 3: qkv: cn==0 -> exp(q) -> qT[gp][192]; cn==1 -> exp(k); cn==2 -> v
// MODE 4: out f32  [b][192][px], bias + bf16 resid   (w2, big-ws)
// ---------------------------------------------------------------------------
template<int MODE, int NCHUNK, int UNITS, int NTILE>
__global__ __launch_bounds__(256) void gemm3_k(
    const unsigned short* __restrict__ X, const unsigned short* __restrict__ Wb,
    const float* __restrict__ bias, const void* __restrict__ resid,
    void* __restrict__ Out, int OCTOT, unsigned short* __restrict__ qT)
{
    constexpr int KTOT = UNITS * 192;
    __shared__ unsigned short tile[2][64 * 192];

    const int tid = threadIdx.x;
    const int wave = tid >> 6, lane = tid & 63;
    const int lr = lane & 15, lg = lane >> 4;
    const int xr = lr & 7;

    auto stage = [&](int s, int buf) {
        const int t = s / UNITS, u = s - t * UNITS;
        const int gp0s = (blockIdx.x * NTILE + t) * 64;
        const unsigned short* Xb = X + (size_t)gp0s * KTOT + u * 192;
        #pragma unroll
        for (int j = 0; j < 6; j++) {
            int ci = (wave * 6 + j) * 64 + lane;
            int row = ci / 24;
            int c = ci - row * 24;
            int csw = (c & ~7) | ((c ^ row) & 7);
            gload_lds16(Xb + (size_t)row * KTOT + csw * 8, &tile[buf][ci * 8]);
        }
    };

    stage(0, 0);

    for (int t = 0; t < NTILE; t++) {
        const int gp0 = (blockIdx.x * NTILE + t) * 64;
        const int b = gp0 >> 16;
        const int pxb = gp0 & 65535;

        if constexpr (UNITS == 1) {
            __syncthreads();
            if (t + 1 < NTILE) stage(t + 1, (t + 1) & 1);
            const unsigned short* tb = tile[t & 1];

            #pragma unroll
            for (int cn = 0; cn < NCHUNK; cn++) {
                const int ocb = cn * 192 + wave * 48;
                const unsigned short* wrow = Wb + (size_t)(ocb + lr) * KTOT + lg * 8;
                const bool swapped = (MODE == 3 && cn == 0);

                s8 wf[3][6];
                #pragma unroll
                for (int ot = 0; ot < 3; ot++)
                    #pragma unroll
                    for (int kk = 0; kk < 6; kk++)
                        wf[ot][kk] = *(const s8*)(wrow + (size_t)ot * 16 * KTOT + kk * 32);

                f4 acc[4][3];
                #pragma unroll
                for (int i = 0; i < 4; i++)
                    #pragma unroll
                    for (int j = 0; j < 3; j++) acc[i][j] = (f4)0.0f;

                #pragma unroll
                for (int kk = 0; kk < 6; kk++) {
                    const int kc = kk * 4 + lg;
                    const int kcs = (kc & ~7) | ((kc ^ xr) & 7);
                    s8 a[4];
                    #pragma unroll
                    for (int pt = 0; pt < 4; pt++)
                        a[pt] = *(const s8*)&tb[((pt * 16 + lr) * 24 + kcs) * 8];
                    #pragma unroll
                    for (int ot = 0; ot < 3; ot++)
                        #pragma unroll
                        for (int pt = 0; pt < 4; pt++)
                            acc[pt][ot] = swapped
                                ? __builtin_amdgcn_mfma_f32_16x16x32_bf16(wf[ot][kk], a[pt], acc[pt][ot], 0, 0, 0)
                                : __builtin_amdgcn_mfma_f32_16x16x32_bf16(a[pt], wf[ot][kk], acc[pt][ot], 0, 0, 0);
                }

                if (MODE == 3 && cn == 0) {
                    #pragma unroll
                    for (int pt = 0; pt < 4; pt++) {
                        const int gp = gp0 + pt * 16 + lr;
                        unsigned short* orow = qT + (size_t)gp * 192 + wave * 48 + lg * 4;
                        #pragma unroll
                        for (int ot = 0; ot < 3; ot++) {
                            f4 bi4 = *(const f4*)&bias[wave * 48 + ot * 16 + lg * 4];
                            us4 o;
                            #pragma unroll
                            for (int r = 0; r < 4; r++) o[r] = f2b(__expf(acc[pt][ot][r] + bi4[r]));
                            *(us4*)(orow + ot * 16) = o;
                        }
                    }
                } else if (MODE == 3) {
                    #pragma unroll
                    for (int ot = 0; ot < 3; ot++) {
                        const int oc = ocb + ot * 16 + lr;
                        const float bi = bias[oc];
                        const size_t rowoff = ((size_t)b * 384 + (oc - 192)) * NPIX + pxb + lg * 4;
                        #pragma unroll
                        for (int pt = 0; pt < 4; pt++) {
                            us4 o;
                            #pragma unroll
                            for (int r = 0; r < 4; r++) {
                                float v = acc[pt][ot][r] + bi;
                                if (cn == 1) v = __expf(v);
                                o[r] = f2b(v);
                            }
                            *(us4*)((unsigned short*)Out + rowoff + pt * 16) = o;
                        }
                    }
                }
            }
        } else {
            // UNITS == 2, NCHUNK == 1 (w2)
            const int ocb = wave * 48;
            const unsigned short* wrow = Wb + (size_t)(ocb + lr) * KTOT + lg * 8;

            f4 acc[4][3];
            #pragma unroll
            for (int i = 0; i < 4; i++)
                #pragma unroll
                for (int j = 0; j < 3; j++) acc[i][j] = (f4)0.0f;

            #pragma unroll
            for (int u = 0; u < 2; u++) {
                const int s = t * 2 + u;
                __syncthreads();
                if (s + 1 < NTILE * 2) stage(s + 1, (s + 1) & 1);
                const unsigned short* tb = tile[s & 1];

                s8 wf[3][6];
                #pragma unroll
                for (int ot = 0; ot < 3; ot++)
                    #pragma unroll
                    for (int kk = 0; kk < 6; kk++)
                        wf[ot][kk] = *(const s8*)(wrow + (size_t)ot * 16 * KTOT + u * 192 + kk * 32);

                #pragma unroll
                for (int kk = 0; kk < 6; kk++) {
                    const int kc = kk * 4 + lg;
                    const int kcs = (kc & ~7) | ((kc ^ xr) & 7);
                    s8 a[4];
                    #pragma unroll
                    for (int pt = 0; pt < 4; pt++)
                        a[pt] = *(const s8*)&tb[((pt * 16 + lr) * 24 + kcs) * 8];
                    #pragma unroll
                    for (int ot = 0; ot < 3; ot++)
                        #pragma unroll
                        for (int pt = 0; pt < 4; pt++)
                            acc[pt][ot] = __builtin_amdgcn_mfma_f32_16x16x32_bf16(a[pt], wf[ot][kk], acc[pt][ot], 0, 0, 0);
                }
            }

            #pragma unroll
            for (int ot = 0; ot < 3; ot++) {
                const int oc = ocb + ot * 16 + lr;
                const float bi = bias[oc];
                const size_t rowoff = ((size_t)b * 192 + oc) * NPIX + pxb + lg * 4;
                #pragma unroll
                for (int pt = 0; pt < 4; pt++) {
                    if (MODE == 2) {
                        f4 rv = *(const f4*)((const float*)resid + rowoff + pt * 16);
                        f4 o;
                        #pragma unroll
                        for (int r = 0; r < 4; r++) o[r] = acc[pt][ot][r] + bi + rv[r];
                        *(f4*)((float*)Out + rowoff + pt * 16) = o;
                    } else {  // MODE 4
                        us4 rv = *(const us4*)((const unsigned short*)resid + rowoff + pt * 16);
                        f4 o;
                        #pragma unroll
                        for (int r = 0; r < 4; r++) o[r] = acc[pt][ot][r] + bi + b2f(rv[r]);
                        *(f4*)((float*)Out + rowoff + pt * 16) = o;
                    }
                }
            }
        }
    }
}

// ---------------------------------------------------------------------------
// context (exp-free) + denominator row d=24; 1024 blocks (512-px chunks)
// for 4 blocks/CU latency hiding.
// ---------------------------------------------------------------------------
__global__ __launch_bounds__(256) void context_k(const unsigned short* __restrict__ kv,
                                                 float* __restrict__ ctxT)
{
    __shared__ float red[4][64][16];
    int bid = blockIdx.x;                  // 1024 blocks
    int bh = bid >> 5, cgrp = bid & 31;
    int b = bh >> 3, h = bh & 7;
    int tid = threadIdx.x;
    int wave = tid >> 6, lane = tid & 63, lr = lane & 15, lg = lane >> 4;
    int chunk = cgrp * 4 + wave;           // 0..127, 512 px each
    size_t nbase = (size_t)chunk * 512 + lg * 8;

    int c0 = h * 24 + lr;
    int c1 = h * 24 + 16 + lr;
    bool val1 = lr < 8;

    const unsigned short* k0p = kv + ((size_t)b * 384 + c0) * NPIX + nbase;
    const unsigned short* k1p = kv + ((size_t)b * 384 + (c1 > 191 ? 191 : c1)) * NPIX + nbase;
    const unsigned short* v0p = kv + ((size_t)b * 384 + 192 + h * 24 + lr) * NPIX + nbase;
    const unsigned short* v1p = kv + ((size_t)b * 384 + 192 + ((h * 24 + 16 + lr > 191) ? 191 : h * 24 + 16 + lr)) * NPIX + nbase;

    const short one_bf = (short)0x3F80;
    s8 ones8 = { one_bf, one_bf, one_bf, one_bf, one_bf, one_bf, one_bf, one_bf };
    s8 zero8 = (s8)0;

    f4 acc[2][2];
    #pragma unroll
    for (int i = 0; i < 2; i++) for (int j = 0; j < 2; j++) acc[i][j] = (f4)0.0f;

    for (int s = 0; s < 16; s++) {
        int off = s * 32;
        s8 p0 = *(const s8*)(k0p + off);
        s8 p1 = *(const s8*)(k1p + off);
        s8 vr0 = *(const s8*)(v0p + off);
        s8 vr1 = *(const s8*)(v1p + off);
        if (!val1) p1 = zero8;
        if (lr == 8) vr1 = ones8;
        acc[0][0] = __builtin_amdgcn_mfma_f32_16x16x32_bf16(p0, vr0, acc[0][0], 0, 0, 0);
        acc[0][1] = __builtin_amdgcn_mfma_f32_16x16x32_bf16(p0, vr1, acc[0][1], 0, 0, 0);
        acc[1][0] = __builtin_amdgcn_mfma_f32_16x16x32_bf16(p1, vr0, acc[1][0], 0, 0, 0);
        acc[1][1] = __builtin_amdgcn_mfma_f32_16x16x32_bf16(p1, vr1, acc[1][1], 0, 0, 0);
    }
    #pragma unroll
    for (int mt = 0; mt < 2; mt++)
        #pragma unroll
        for (int ct = 0; ct < 2; ct++)
            #pragma unroll
            for (int r = 0; r < 4; r++)
                red[wave][lane][mt * 8 + ct * 4 + r] = acc[mt][ct][r];
    __syncthreads();

    if (wave == 0) {
        float* base = ctxT + (size_t)(b * 8 + h) * 1024;
        #pragma unroll
        for (int j = 0; j < 16; j++) {
            float sum = red[0][lane][j] + red[1][lane][j] + red[2][lane][j] + red[3][lane][j];
            int mt = j >> 3, ct = (j >> 2) & 1, r = j & 3;
            int c = mt * 16 + lg * 4 + r;
            int d = ct * 16 + lr;
            atomicAdd(base + d * 32 + c, sum);
        }
    }
}

// ---------------------------------------------------------------------------
// normalize ctx rows 0..23 by denominator; emit bf16 copy ctxb[bh][32][32]
// ---------------------------------------------------------------------------
__global__ void ctxnorm_k(float* __restrict__ ctxT, unsigned short* __restrict__ ctxb)
{
    int i = blockIdx.x * 256 + threadIdx.x;
    if (i >= 1024) return;
    int bh = i >> 5, c = i & 31;
    float* base = ctxT + (size_t)bh * 1024;
    unsigned short* bb = ctxb + (size_t)bh * 1024;
    float den = base[24 * 32 + c];
    float r = den > 0.f ? 1.0f / den : 0.0f;
    #pragma unroll
    for (int d = 0; d < 24; d++) {
        float v = base[d * 32 + c] * r;
        bb[d * 32 + c] = f2b(v);
    }
    #pragma unroll
    for (int d = 24; d < 32; d++) bb[d * 32 + c] = 0;
}

// ---------------------------------------------------------------------------
// fused qctx+w1
// ---------------------------------------------------------------------------
template<bool BIGWS>
__global__ __launch_bounds__(256) void qctx_proj_k(
    const unsigned short* __restrict__ qT, const unsigned short* __restrict__ ctxb,
    const unsigned short* __restrict__ outWb, const float* __restrict__ outBias,
    const float* __restrict__ xres, float* __restrict__ Out,
    unsigned short* __restrict__ x2b,
    const float* __restrict__ ln2g, const float* __restrict__ ln2b,
    const unsigned short* __restrict__ w1b, const float* __restrict__ b1,
    unsigned short* __restrict__ h1t)
{
    __shared__ unsigned short outp[64][200];
    __shared__ float lnS[4][64], lnQ[4][64];

    int tid = threadIdx.x, bid = blockIdx.x;
    int b = bid >> 10, n0 = (bid & 1023) * 64;
    int wave = tid >> 6, lane = tid & 63, lr = lane & 15, lg = lane >> 4;
    const size_t bpx = (size_t)b << 16;

    #pragma unroll
    for (int hh = 0; hh < 2; hh++) {
        int h = wave * 2 + hh;
        const unsigned short* cb = ctxb + (size_t)(b * 8 + h) * 1024;
        s8 cf[2];
        #pragma unroll
        for (int mt = 0; mt < 2; mt++)
            cf[mt] = *(const s8*)(cb + (mt * 16 + lr) * 32 + lg * 8);
        #pragma unroll
        for (int nt = 0; nt < 4; nt++) {
            int n = nt * 16 + lr;
            s8 bfq = (s8)0;
            float sown = 0.f;
            if (lg < 3) {
                bfq = *(const s8*)(qT + (bpx + n0 + n) * 192 + h * 24 + lg * 8);
                #pragma unroll
                for (int j = 0; j < 8; j++) sown += b2f((unsigned short)bfq[j]);
            }
            float den = sown;
            den += __shfl_xor(den, 16);
            den += __shfl_xor(den, 32);
            f4 z = (f4)0.0f;
            f4 d0 = __builtin_amdgcn_mfma_f32_16x16x32_bf16(cf[0], bfq, z, 0, 0, 0);
            f4 d1 = __builtin_amdgcn_mfma_f32_16x16x32_bf16(cf[1], bfq, z, 0, 0, 0);
            float sinv = __builtin_amdgcn_rcpf(den);
            us4 w0;
            #pragma unroll
            for (int r = 0; r < 4; r++) w0[r] = f2b(d0[r] * sinv);
            *(us4*)&outp[n][h * 24 + lg * 4] = w0;
            if (lg < 2) {
                us4 w1;
                #pragma unroll
                for (int r = 0; r < 4; r++) w1[r] = f2b(d1[r] * sinv);
                *(us4*)&outp[n][h * 24 + 16 + lg * 4] = w1;
            }
        }
    }
    __syncthreads();

    f4 acc[4][3];
    #pragma unroll
    for (int i = 0; i < 4; i++) for (int j = 0; j < 3; j++) acc[i][j] = (f4)0.0f;
    #pragma unroll
    for (int k0 = 0; k0 < 192; k0 += 32) {
        s8 bf[4];
        #pragma unroll
        for (int pt = 0; pt < 4; pt++)
            bf[pt] = *(const s8*)&outp[pt * 16 + lr][k0 + lg * 8];
        #pragma unroll
        for (int ot = 0; ot < 3; ot++) {
            s8 af = *(const s8*)&outWb[(size_t)(wave * 48 + ot * 16 + lr) * 192 + k0 + lg * 8];
            #pragma unroll
            for (int pt = 0; pt < 4; pt++)
                acc[pt][ot] = __builtin_amdgcn_mfma_f32_16x16x32_bf16(bf[pt], af, acc[pt][ot], 0, 0, 0);
        }
    }

    float sP[4][4], qP[4][4];
    #pragma unroll
    for (int pt = 0; pt < 4; pt++)
        #pragma unroll
        for (int r = 0; r < 4; r++) { sP[pt][r] = 0.f; qP[pt][r] = 0.f; }

    #pragma unroll
    for (int ot = 0; ot < 3; ot++) {
        const int oc = wave * 48 + ot * 16 + lr;
        const float bi = outBias[oc];
        const size_t rowbase = ((size_t)b * 192 + oc) * NPIX + n0 + lg * 4;
        #pragma unroll
        for (int pt = 0; pt < 4; pt++) {
            f4 rv = *(const f4*)(xres + rowbase + pt * 16);
            f4 v;
            #pragma unroll
            for (int r = 0; r < 4; r++) {
                v[r] = acc[pt][ot][r] + bi + rv[r];
                sP[pt][r] += v[r]; qP[pt][r] += v[r] * v[r];
            }
            acc[pt][ot] = v;
            if (BIGWS) {
                us4 o;
                #pragma unroll
                for (int r = 0; r < 4; r++) o[r] = f2b(v[r]);
                *(us4*)(x2b + rowbase + pt * 16) = o;
            } else {
                *(f4*)(Out + rowbase + pt * 16) = v;
            }
        }
    }
    #pragma unroll
    for (int pt = 0; pt < 4; pt++)
        #pragma unroll
        for (int r = 0; r < 4; r++) {
            float s = sP[pt][r], q = qP[pt][r];
            s += __shfl_xor(s, 1); s += __shfl_xor(s, 2);
            s += __shfl_xor(s, 4); s += __shfl_xor(s, 8);
            q += __shfl_xor(q, 1); q += __shfl_xor(q, 2);
            q += __shfl_xor(q, 4); q += __shfl_xor(q, 8);
            sP[pt][r] = s; qP[pt][r] = q;
        }
    if (lr == 0) {
        #pragma unroll
        for (int pt = 0; pt < 4; pt++)
            #pragma unroll
            for (int r = 0; r < 4; r++) {
                lnS[wave][pt * 16 + lg * 4 + r] = sP[pt][r];
                lnQ[wave][pt * 16 + lg * 4 + r] = qP[pt][r];
            }
    }
    __syncthreads();

    // LN2 apply -> xn into outp
    float lgv[3], lbv[3];
    #pragma unroll
    for (int ot = 0; ot < 3; ot++) {
        int oc = wave * 48 + ot * 16 + lr;
        lgv[ot] = ln2g[oc]; lbv[ot] = ln2b[oc];
    }
    #pragma unroll
    for (int pt = 0; pt < 4; pt++) {
        float mu4[4], rs4[4];
        #pragma unroll
        for (int r = 0; r < 4; r++) {
            int px = pt * 16 + lg * 4 + r;
            float S = lnS[0][px] + lnS[1][px] + lnS[2][px] + lnS[3][px];
            float Qq = lnQ[0][px] + lnQ[1][px] + lnQ[2][px] + lnQ[3][px];
            float mu = S * (1.0f / 192.0f);
            float var = Qq * (1.0f / 192.0f) - mu * mu;
            mu4[r] = mu; rs4[r] = rsqrtf(var + 1e-5f);
        }
        #pragma unroll
        for (int ot = 0; ot < 3; ot++) {
            int oc = wave * 48 + ot * 16 + lr;
            #pragma unroll
            for (int r = 0; r < 4; r++) {
                int px = pt * 16 + lg * 4 + r;
                float xn = (acc[pt][ot][r] - mu4[r]) * rs4[r] * lgv[ot] + lbv[ot];
                outp[px][oc] = f2b(xn);
            }
        }
    }
    __syncthreads();

    // w1 GEMM in place -> h1t[px][384] + gelu_t
    #pragma unroll
    for (int cn = 0; cn < 2; cn++) {
        const int ocb = cn * 192 + wave * 48;
        const unsigned short* wrow = w1b + (size_t)(ocb + lr) * 192 + lg * 8;

        s8 wf[3][6];
        #pragma unroll
        for (int ot = 0; ot < 3; ot++)
            #pragma unroll
            for (int kk = 0; kk < 6; kk++)
                wf[ot][kk] = *(const s8*)(wrow + (size_t)ot * 16 * 192 + kk * 32);

        f4 acc2[4][3];
        #pragma unroll
        for (int i = 0; i < 4; i++)
            #pragma unroll
            for (int j = 0; j < 3; j++) acc2[i][j] = (f4)0.0f;

        #pragma unroll
        for (int kk = 0; kk < 6; kk++) {
            s8 bf[4];
            #pragma unroll
            for (int pt = 0; pt < 4; pt++)
                bf[pt] = *(const s8*)&outp[pt * 16 + lr][kk * 32 + lg * 8];
            #pragma unroll
            for (int ot = 0; ot < 3; ot++)
                #pragma unroll
                for (int pt = 0; pt < 4; pt++)
                    acc2[pt][ot] = __builtin_amdgcn_mfma_f32_16x16x32_bf16(wf[ot][kk], bf[pt], acc2[pt][ot], 0, 0, 0);
        }

        #pragma unroll
        for (int pt = 0; pt < 4; pt++) {
            const int gp = n0 + pt * 16 + lr;
            unsigned short* orow = h1t + (bpx + gp) * 384 + ocb + lg * 4;
            #pragma unroll
            for (int ot = 0; ot < 3; ot++) {
                f4 bi4 = *(const f4*)&b1[ocb + ot * 16 + lg * 4];
                us4 o;
                #pragma unroll
                for (int r = 0; r < 4; r++) o[r] = f2b(gelu_t(acc2[pt][ot][r] + bi4[r]));
                *(us4*)(orow + ot * 16) = o;
            }
        }
    }
}

// ---------------------------------------------------------------------------
// depthwise 3x3 + gelu on [px][384], row-streamed LDS ring; 32 rows/block.
// ---------------------------------------------------------------------------
__global__ __launch_bounds__(256) void dwconv_t2_k(
    const unsigned short* __restrict__ h1t, const float* __restrict__ w,
    const float* __restrict__ bias, unsigned short* __restrict__ h2t)
{
    __shared__ unsigned short ring[4 * 4 * 66 * 8];
    const int bz = blockIdx.z;
    const int b = bz / 12, cb = (bz % 12) * 32;
    const int y0 = blockIdx.y * 32, x0 = blockIdx.x * 64;
    const int tid = threadIdx.x;
    const int x = tid & 63, cg = tid >> 6;
    const int c0 = cb + cg * 8;
    const size_t bbase = (size_t)b << 16;

    float wr[9][8], bi[8];
    #pragma unroll
    for (int i = 0; i < 8; i++) {
        #pragma unroll
        for (int j = 0; j < 9; j++) wr[j][i] = rfl(w[(c0 + i) * 9 + j]);
        bi[i] = rfl(bias[c0 + i]);
    }

    const us8 zz = {0, 0, 0, 0, 0, 0, 0, 0};

    auto stage_row = [&](int gy, int s) {
        unsigned short* ldsrow = &ring[((s * 4 + cg) * 66) * 8];
        if (gy >= 0 && gy <= 255) {
            us8 ev = zz;
            if (x == 0 && x0 > 0)
                ev = *(const us8*)(h1t + (bbase + gy * 256 + x0 - 1) * 384 + c0);
            if (x == 63 && x0 + 64 < 256)
                ev = *(const us8*)(h1t + (bbase + gy * 256 + x0 + 64) * 384 + c0);
            gload_lds16(h1t + (bbase + gy * 256 + x0 + x) * 384 + c0,
                        ldsrow + (1 + x) * 8);
            if (x == 0)  *(us8*)&ldsrow[0]      = ev;
            if (x == 63) *(us8*)&ldsrow[65 * 8] = ev;
        } else {
            *(us8*)&ldsrow[(1 + x) * 8] = zz;
            if (x == 0)  *(us8*)&ldsrow[0]      = zz;
            if (x == 63) *(us8*)&ldsrow[65 * 8] = zz;
        }
    };

    stage_row(y0 - 1, 0);
    stage_row(y0,     1);
    stage_row(y0 + 1, 2);
    __syncthreads();

    #pragma unroll 4
    for (int y = 0; y < 32; y++) {
        if (y < 31) stage_row(y0 + y + 2, (y + 3) & 3);

        float a[8];
        #pragma unroll
        for (int i = 0; i < 8; i++) a[i] = bi[i];
        #pragma unroll
        for (int t = 0; t < 3; t++) {
            const int s = (y + t) & 3;
            const unsigned short* rp = &ring[((s * 4 + cg) * 66 + x) * 8];
            us8 L = *(const us8*)(rp);
            us8 C = *(const us8*)(rp + 8);
            us8 R = *(const us8*)(rp + 16);
            #pragma unroll
            for (int i = 0; i < 8; i++) {
                a[i] += wr[t * 3 + 0][i] * b2f(L[i]);
                a[i] += wr[t * 3 + 1][i] * b2f(C[i]);
                a[i] += wr[t * 3 + 2][i] * b2f(R[i]);
            }
        }
        us8 ov;
        #pragma unroll
        for (int i = 0; i < 8; i++) ov[i] = f2b(gelu_t(a[i]));
        *(us8*)(h2t + (bbase + (y0 + y) * 256 + x0 + x) * 384 + c0) = ov;

        __syncthreads();
    }
}

// ---------------------------------------------------------------------------
extern "C" void kernel_launch(void* const* d_in, const int* in_sizes, int n_in,
                              void* d_out, int out_size, void* d_ws, size_t ws_size,
                              hipStream_t stream)
{
    const float* x    = (const float*)d_in[0];
    const float* ln1g = (const float*)d_in[1];
    const float* ln1b = (const float*)d_in[2];
    const float* qkvw = (const float*)d_in[3];
    const float* qkvb = (const float*)d_in[4];
    const float* outw = (const float*)d_in[5];
    const float* outb = (const float*)d_in[6];
    const float* ln2g = (const float*)d_in[7];
    const float* ln2b = (const float*)d_in[8];
    const float* w1   = (const float*)d_in[9];
    const float* b1   = (const float*)d_in[10];
    const float* dww  = (const float*)d_in[11];
    const float* dwb  = (const float*)d_in[12];
    const float* w2   = (const float*)d_in[13];
    const float* b2   = (const float*)d_in[14];
    float* out = (float*)d_out;

    char* ws = (char*)d_ws;
    unsigned short* kv  = (unsigned short*)ws;
    unsigned short* h1t = (unsigned short*)ws;
    unsigned short* h2t = (unsigned short*)(ws + (size_t)201326592);
    unsigned short* qT  = (unsigned short*)(ws + (size_t)201326592);
    unsigned short* xnt = (unsigned short*)(ws + (size_t)301989888);
    size_t off = (size_t)402653184;
    float* koff = (float*)(ws + off); off += 4096;
    float* ctxT = (float*)(ws + off); off += 131072;
    unsigned short* ctxb = (unsigned short*)(ws + off); off += 65536;
    unsigned short* qkvwb = (unsigned short*)(ws + off); off += 221184;
    unsigned short* outwb = (unsigned short*)(ws + off); off += 73728 * 2;
    unsigned short* w1b   = (unsigned short*)(ws + off); off += 147456;
    unsigned short* w2b   = (unsigned short*)(ws + off); off += 147456;
    off = (off + 255) & ~(size_t)255;
    unsigned short* x2b = (unsigned short*)(ws + off);
    const bool bigws = ws_size >= off + (size_t)100663296;
    (void)koff;

    // 0) merged prologue: LN1+transpose + weight conversions + ctxT zeroing
    prelnt_k<<<2304, 256, 0, stream>>>(x, ln1g, ln1b, xnt,
                                       qkvw, outw, w1, w2,
                                       qkvwb, outwb, w1b, w2b, ctxT);

    // 1) qkv GEMM: exp(q) -> qT, exp(k)/v -> kv
    gemm3_k<3, 3, 1, 4><<<1024, 256, 0, stream>>>(xnt, qkvwb, qkvb, nullptr, kv, 384, qT);

    // 2) context accumulation + denominator (1024 blocks)
    context_k<<<1024, 256, 0, stream>>>(kv, ctxT);

    // 3) normalize ctx -> bf16 copy ctxb
    ctxnorm_k<<<4, 256, 0, stream>>>(ctxT, ctxb);

    // 4) qctx fused (+LN2 +w1+gelu_t -> h1t)
    if (bigws)
        qctx_proj_k<true><<<4096, 256, 0, stream>>>(qT, ctxb, outwb, outb, x, out,
                                                    x2b, ln2g, ln2b, w1b, b1, h1t);
    else
        qctx_proj_k<false><<<4096, 256, 0, stream>>>(qT, ctxb, outwb, outb, x, out,
                                                     x2b, ln2g, ln2b, w1b, b1, h1t);

    // 5) depthwise 3x3 + gelu -> h2t (32 rows/block)
    dwconv_t2_k<<<dim3(4, 8, 48), 256, 0, stream>>>(h1t, dww, dwb, h2t);

    // 6) w2 GEMM + bias + x2 residual -> d_out f32
    if (bigws)
        gemm3_k<4, 1, 2, 4><<<1024, 256, 0, stream>>>(h2t, w2b, b2, x2b, out, 192, nullptr);
    else
        gemm3_k<2, 1, 2, 4><<<1024, 256, 0, stream>>>(h2t, w2b, b2, out, out, 192, nullptr);
}